// Round 5
// baseline (326.096 us; speedup 1.0000x reference)
//
#include <hip/hip_runtime.h>

#define PC_ 60

typedef unsigned short u16;
typedef __attribute__((ext_vector_type(8))) short short8v;   // 8 bf16 (4 VGPR)
typedef __attribute__((ext_vector_type(4))) float f32x4;

__device__ inline float bf2f(u16 u) {
    union { unsigned int i; float f; } x; x.i = ((unsigned)u) << 16; return x.f;
}
__device__ inline u16 f2bf(float f) {
    union { float f; unsigned int i; } x; x.f = f;
    unsigned int r = x.i + 0x7fff + ((x.i >> 16) & 1);   // RNE
    return (u16)(r >> 16);
}
__device__ inline unsigned pk2(float a, float b) {
    return (unsigned)f2bf(a) | ((unsigned)f2bf(b) << 16);
}

// ---------------- prep: query f32 -> bf16
__global__ __launch_bounds__(256) void k_prepx(const float* __restrict__ X, u16* __restrict__ Xb)
{
    const int i = (blockIdx.x * 256 + threadIdx.x) * 8;
    float4 a = *reinterpret_cast<const float4*>(X + i);
    float4 b = *reinterpret_cast<const float4*>(X + i + 4);
    *reinterpret_cast<uint4*>(Xb + i) =
        make_uint4(pk2(a.x, a.y), pk2(a.z, a.w), pk2(b.x, b.y), pk2(b.z, b.w));
}

// ---------------- prep: W transposes (z<4) + conv-frag/pos prep (z==4)
__global__ __launch_bounds__(256) void k_prept(
    const float* __restrict__ W0, const float* __restrict__ W1,
    const float* __restrict__ W2, const float* __restrict__ W3,
    u16* __restrict__ T0, u16* __restrict__ T1, u16* __restrict__ T2, u16* __restrict__ T3,
    const float* __restrict__ c1w, const float* __restrict__ c2w,
    const float* __restrict__ pos_k,
    u16* __restrict__ Wf1, u16* __restrict__ Wf2, u16* __restrict__ pos_kb)
{
    const int z = blockIdx.z;
    const int t = threadIdx.x;
    if (z == 4) {
        if (blockIdx.x != 0 || blockIdx.y != 0) return;
        for (int s = t; s < 448; s += 256) {
            const int q = s >> 6, l = s & 63, lg = l >> 4, n = l & 15;
            const int G = q * 4 + lg;
            unsigned o[4];
#pragma unroll
            for (int u2 = 0; u2 < 4; ++u2) {
                float v0 = 0.f, v1 = 0.f;
                if (G < 25) {
                    const int dn = G / 5, dm = G - dn * 5;
                    v0 = c1w[((dn * 5 + dm) * 8 + u2 * 2 + 0) * 16 + n];
                    v1 = c1w[((dn * 5 + dm) * 8 + u2 * 2 + 1) * 16 + n];
                }
                o[u2] = pk2(v0, v1);
            }
            *reinterpret_cast<uint4*>(&Wf1[s * 8]) = make_uint4(o[0], o[1], o[2], o[3]);
        }
        for (int s = t; s < 832; s += 256) {
            const int q = s >> 6, l = s & 63, lg = l >> 4, n = l & 15;
            const int G = q * 4 + lg;
            unsigned o[4];
#pragma unroll
            for (int u2 = 0; u2 < 4; ++u2) {
                float v0 = 0.f, v1 = 0.f;
                if (G < 50 && n < 8) {
                    const int pos = G >> 1, h = G & 1;
                    const int dn = pos / 5, dm = pos - dn * 5;
                    v0 = c2w[((dn * 5 + dm) * 16 + h * 8 + u2 * 2 + 0) * 8 + n];
                    v1 = c2w[((dn * 5 + dm) * 16 + h * 8 + u2 * 2 + 1) * 8 + n];
                }
                o[u2] = pk2(v0, v1);
            }
            *reinterpret_cast<uint4*>(&Wf2[s * 8]) = make_uint4(o[0], o[1], o[2], o[3]);
        }
        for (int s = t; s < 128 * 64; s += 256) {
            const int r = s >> 6;
            pos_kb[s] = (r < 121) ? f2bf(pos_k[s]) : (u16)0;
        }
        return;
    }
    const float* W = (z == 0) ? W0 : (z == 1) ? W1 : (z == 2) ? W2 : W3;
    u16* T        = (z == 0) ? T0 : (z == 1) ? T1 : (z == 2) ? T2 : T3;
    __shared__ float ls[64 * 65];
    const int k0 = blockIdx.x * 64, n0 = blockIdx.y * 64;
#pragma unroll
    for (int i = 0; i < 16; ++i) {
        const int idx = t + i * 256, r = idx >> 6, c = idx & 63;
        ls[c * 65 + r] = W[(size_t)(k0 + r) * 512 + n0 + c];
    }
    __syncthreads();
#pragma unroll
    for (int i = 0; i < 16; ++i) {
        const int idx = t + i * 256, r = idx >> 6, c = idx & 63;
        T[(size_t)(n0 + r) * 512 + k0 + c] = f2bf(ls[r * 65 + c]);
    }
}

// ---------------- QKV (MFMA): Xb @ WT -> Q/K bf16 (B,H,N,DH), V^T bf16 (B,H,DH,N)
__global__ __launch_bounds__(256) void k_qkvm(
    const u16* __restrict__ Xb,
    const u16* __restrict__ WT0, const u16* __restrict__ WT1, const u16* __restrict__ WT2,
    const float* __restrict__ b0, const float* __restrict__ b1, const float* __restrict__ b2,
    u16* __restrict__ Qb, u16* __restrict__ Kb, u16* __restrict__ Vt)
{
    const int z = blockIdx.z;
    const u16* WT    = (z == 0) ? WT0 : (z == 1) ? WT1 : WT2;
    const float* bias = (z == 0) ? b0 : (z == 1) ? b1 : b2;
    __shared__ __align__(16) u16 sh[18432];          // As 128x72, Bs 128x72
    u16* As = sh; u16* Bs = sh + 9216;
    const int t = threadIdx.x, lane = t & 63, wave = t >> 6;
    const int wm = wave >> 1, wn = wave & 1;
    const int lg = lane >> 4, ln16 = lane & 15;
    const int m0 = blockIdx.x * 128, n0 = blockIdx.y * 128;
    f32x4 acc[4][4] = {};
    for (int k0 = 0; k0 < 512; k0 += 64) {
#pragma unroll
        for (int u = 0; u < 4; ++u) {
            const int chunk = u * 256 + t, row = chunk >> 3, ko = (chunk & 7) * 8;
            *reinterpret_cast<uint4*>(As + row * 72 + ko) =
                *reinterpret_cast<const uint4*>(Xb + (size_t)(m0 + row) * 512 + k0 + ko);
            *reinterpret_cast<uint4*>(Bs + row * 72 + ko) =
                *reinterpret_cast<const uint4*>(WT + (size_t)(n0 + row) * 512 + k0 + ko);
        }
        __syncthreads();
#pragma unroll
        for (int kk = 0; kk < 64; kk += 32) {
            short8v a[4], bfr[4];
#pragma unroll
            for (int mi = 0; mi < 4; ++mi)
                a[mi] = *reinterpret_cast<const short8v*>(As + (wm * 64 + mi * 16 + ln16) * 72 + kk + lg * 8);
#pragma unroll
            for (int ni = 0; ni < 4; ++ni)
                bfr[ni] = *reinterpret_cast<const short8v*>(Bs + (wn * 64 + ni * 16 + ln16) * 72 + kk + lg * 8);
#pragma unroll
            for (int mi = 0; mi < 4; ++mi)
#pragma unroll
                for (int ni = 0; ni < 4; ++ni)
                    acc[mi][ni] = __builtin_amdgcn_mfma_f32_16x16x32_bf16(a[mi], bfr[ni], acc[mi][ni], 0, 0, 0);
        }
        __syncthreads();
    }
    u16* Cs = sh + wave * 4608;                       // 64x72 per wave
#pragma unroll
    for (int ni = 0; ni < 4; ++ni) {
        const float bv = bias[n0 + wn * 64 + ni * 16 + ln16];
#pragma unroll
        for (int mi = 0; mi < 4; ++mi)
#pragma unroll
            for (int r = 0; r < 4; ++r)
                Cs[(mi * 16 + lg * 4 + r) * 72 + ni * 16 + ln16] = f2bf(acc[mi][ni][r] + bv);
    }
    if (z < 2) {
        u16* O = (z == 0) ? Qb : Kb;
#pragma unroll
        for (int j = 0; j < 8; ++j) {
            const int chunk = j * 64 + lane, row = chunk >> 3, co = (chunk & 7) * 8;
            const int tok = m0 + wm * 64 + row;
            const int b = tok >> 9, n = tok & 511;
            const int cg = n0 + wn * 64 + co;
            const int h = cg >> 6, dh = cg & 63;
            *reinterpret_cast<uint4*>(O + ((size_t)((b * 8 + h) * 512 + n)) * 64 + dh) =
                *reinterpret_cast<const uint4*>(Cs + row * 72 + co);
        }
    } else {
#pragma unroll
        for (int j = 0; j < 8; ++j) {
            const int chunk = j * 64 + lane, dr = chunk >> 3, no8 = (chunk & 7) * 8;
            const int cg = n0 + wn * 64 + dr;
            const int h = cg >> 6, dh = cg & 63;
            const int tok = m0 + wm * 64 + no8;
            const int b = tok >> 9, n = tok & 511;
            u16 v[8];
#pragma unroll
            for (int e = 0; e < 8; ++e) v[e] = Cs[(no8 + e) * 72 + dr];
            uint4 o = make_uint4((unsigned)v[0] | ((unsigned)v[1] << 16),
                                 (unsigned)v[2] | ((unsigned)v[3] << 16),
                                 (unsigned)v[4] | ((unsigned)v[5] << 16),
                                 (unsigned)v[6] | ((unsigned)v[7] << 16));
            *reinterpret_cast<uint4*>(Vt + ((size_t)((b * 8 + h) * 64 + dh)) * 512 + n) = o;
        }
    }
}

// ---------------- qp (MFMA): Q(bh,n,64) @ pos_k^T -> QP bf16 (bh,n,128pad)
__global__ __launch_bounds__(256) void k_qposm(
    const u16* __restrict__ Qb, const u16* __restrict__ pos_kb, u16* __restrict__ QP)
{
    __shared__ __align__(16) u16 sh[18432];
    u16* As = sh; u16* Bs = sh + 9216;
    const int t = threadIdx.x, lane = t & 63, wave = t >> 6;
    const int lg = lane >> 4, ln16 = lane & 15;
    const int n0 = blockIdx.x * 128, bh = blockIdx.y;
#pragma unroll
    for (int u = 0; u < 4; ++u) {
        const int chunk = u * 256 + t, row = chunk >> 3, ko = (chunk & 7) * 8;
        *reinterpret_cast<uint4*>(As + row * 72 + ko) =
            *reinterpret_cast<const uint4*>(Qb + ((size_t)(bh * 512 + n0 + row)) * 64 + ko);
        *reinterpret_cast<uint4*>(Bs + row * 72 + ko) =
            *reinterpret_cast<const uint4*>(pos_kb + (size_t)row * 64 + ko);
    }
    __syncthreads();
    f32x4 acc[2][8] = {};
#pragma unroll
    for (int kk = 0; kk < 64; kk += 32) {
        short8v a[2], bfr[8];
#pragma unroll
        for (int mi = 0; mi < 2; ++mi)
            a[mi] = *reinterpret_cast<const short8v*>(As + (wave * 32 + mi * 16 + ln16) * 72 + kk + lg * 8);
#pragma unroll
        for (int ni = 0; ni < 8; ++ni)
            bfr[ni] = *reinterpret_cast<const short8v*>(Bs + (ni * 16 + ln16) * 72 + kk + lg * 8);
#pragma unroll
        for (int mi = 0; mi < 2; ++mi)
#pragma unroll
            for (int ni = 0; ni < 8; ++ni)
                acc[mi][ni] = __builtin_amdgcn_mfma_f32_16x16x32_bf16(a[mi], bfr[ni], acc[mi][ni], 0, 0, 0);
    }
    __syncthreads();
    u16* Cs = sh + wave * 4352;                      // 32x136 per wave
#pragma unroll
    for (int mi = 0; mi < 2; ++mi)
#pragma unroll
        for (int ni = 0; ni < 8; ++ni)
#pragma unroll
            for (int r = 0; r < 4; ++r)
                Cs[(mi * 16 + lg * 4 + r) * 136 + ni * 16 + ln16] = f2bf(acc[mi][ni][r]);
#pragma unroll
    for (int j = 0; j < 8; ++j) {
        const int chunk = j * 64 + lane, row = chunk >> 4, co = (chunk & 15) * 8;
        *reinterpret_cast<uint4*>(QP + ((size_t)(bh * 512 + n0 + wave * 32 + row)) * 128 + co) =
            *reinterpret_cast<const uint4*>(Cs + row * 136 + co);
    }
}

// ---------------- scores (MFMA): (Q@K^T + QP[rel]) / 8 -> S bf16 (bh,n,m)
__global__ __launch_bounds__(256) void k_scoresm(
    const u16* __restrict__ Qb, const u16* __restrict__ Kb, const u16* __restrict__ QP,
    u16* __restrict__ S)
{
    __shared__ __align__(16) u16 sh[18432];
    u16* As = sh; u16* Bs = sh + 9216;
    const int t = threadIdx.x, lane = t & 63, wave = t >> 6;
    const int wm = wave >> 1, wn = wave & 1;
    const int lg = lane >> 4, ln16 = lane & 15;
    const int m0 = blockIdx.x * 128, n0 = blockIdx.y * 128, bh = blockIdx.z;
#pragma unroll
    for (int u = 0; u < 4; ++u) {
        const int chunk = u * 256 + t, row = chunk >> 3, ko = (chunk & 7) * 8;
        *reinterpret_cast<uint4*>(As + row * 72 + ko) =
            *reinterpret_cast<const uint4*>(Qb + ((size_t)(bh * 512 + n0 + row)) * 64 + ko);
        *reinterpret_cast<uint4*>(Bs + row * 72 + ko) =
            *reinterpret_cast<const uint4*>(Kb + ((size_t)(bh * 512 + m0 + row)) * 64 + ko);
    }
    __syncthreads();
    f32x4 acc[4][4] = {};
#pragma unroll
    for (int kk = 0; kk < 64; kk += 32) {
        short8v a[4], bfr[4];
#pragma unroll
        for (int mi = 0; mi < 4; ++mi)
            a[mi] = *reinterpret_cast<const short8v*>(As + (wm * 64 + mi * 16 + ln16) * 72 + kk + lg * 8);
#pragma unroll
        for (int ni = 0; ni < 4; ++ni)
            bfr[ni] = *reinterpret_cast<const short8v*>(Bs + (wn * 64 + ni * 16 + ln16) * 72 + kk + lg * 8);
#pragma unroll
        for (int mi = 0; mi < 4; ++mi)
#pragma unroll
            for (int ni = 0; ni < 4; ++ni)
                acc[mi][ni] = __builtin_amdgcn_mfma_f32_16x16x32_bf16(a[mi], bfr[ni], acc[mi][ni], 0, 0, 0);
    }
    __syncthreads();
    u16* QPs = sh;                                   // 128x128 bf16
#pragma unroll
    for (int u = 0; u < 8; ++u) {
        const int chunk = u * 256 + t, row = chunk >> 4, co = (chunk & 15) * 8;
        *reinterpret_cast<uint4*>(QPs + row * 128 + co) =
            *reinterpret_cast<const uint4*>(QP + ((size_t)(bh * 512 + n0 + row)) * 128 + co);
    }
    __syncthreads();
#pragma unroll
    for (int mi = 0; mi < 4; ++mi)
#pragma unroll
        for (int ni = 0; ni < 4; ++ni) {
            const int m_g = m0 + wn * 64 + ni * 16 + ln16;
#pragma unroll
            for (int r = 0; r < 4; ++r) {
                const int n_loc = wm * 64 + mi * 16 + lg * 4 + r;
                const int n_g = n0 + n_loc;
                int rel = m_g - n_g;
                rel = rel < -PC_ ? -PC_ : (rel > PC_ ? PC_ : rel);
                const float v = (acc[mi][ni][r] + bf2f(QPs[n_loc * 128 + rel + PC_])) * 0.125f;
                S[(size_t)bh * 262144 + (size_t)n_g * 512 + m_g] = f2bf(v);
            }
        }
}

// ---------------- conv1-stats (MFMA, no Y write): masked sum/sumsq of conv1 output
__global__ __launch_bounds__(256) void k_stats1(
    const u16* __restrict__ S, const u16* __restrict__ Wf,
    const float* __restrict__ bias, const int* __restrict__ VL,
    float* __restrict__ ST)
{
    __shared__ __align__(16) u16 xs[10368];
    __shared__ float wred[4][16][2];
    const int t = threadIdx.x;
    const int b = blockIdx.z;
    const int n0 = blockIdx.y * 32;
    const int m0 = blockIdx.x * 32;
    const int vl = VL[b];
    if (n0 >= vl) return;
    const u16* sp0 = S + (size_t)(b * 8) * 262144;
    for (int idx = t; idx < 1296; idx += 256) {
        const int r = idx / 36; const int c = idx - r * 36;
        const int gn = n0 - 2 + r, gm = m0 - 2 + c;
        uint4 pk = make_uint4(0, 0, 0, 0);
        if ((unsigned)gn < 512u && (unsigned)gm < 512u) {
            const u16* p = sp0 + (size_t)gn * 512 + gm;
            u16 v[8];
#pragma unroll
            for (int e = 0; e < 8; ++e) v[e] = p[(size_t)e * 262144];
            pk.x = (unsigned)v[0] | ((unsigned)v[1] << 16);
            pk.y = (unsigned)v[2] | ((unsigned)v[3] << 16);
            pk.z = (unsigned)v[4] | ((unsigned)v[5] << 16);
            pk.w = (unsigned)v[6] | ((unsigned)v[7] << 16);
        }
        *reinterpret_cast<uint4*>(&xs[idx * 8]) = pk;
    }
    const int lane = t & 63, wave = t >> 6;
    const int lg = lane >> 4, ln16 = lane & 15;
    short8v bq[7];
#pragma unroll
    for (int q = 0; q < 7; ++q)
        bq[q] = *reinterpret_cast<const short8v*>(&Wf[(q * 64 + lane) * 8]);
    int aoff[7];
#pragma unroll
    for (int q = 0; q < 7; ++q) {
        const int G = q * 4 + lg; const int p = (G < 25) ? G : 0;
        const int dn = p / 5, dm = p - dn * 5;
        aoff[q] = (dn * 36 + dm) * 8;
    }
    const float bs = bias[ln16];
    float sst = 0.f, sst2 = 0.f;
    __syncthreads();
    for (int i = 0; i < 16; ++i) {
        const int j = wave * 16 + i;
        const int tr = j >> 1, c0 = (j & 1) << 4;
        const int pb = (tr * 36 + c0 + ln16) * 8;
        f32x4 acc = {bs, bs, bs, bs};
#pragma unroll
        for (int q = 0; q < 7; ++q) {
            short8v a = *reinterpret_cast<const short8v*>(&xs[pb + aoff[q]]);
            acc = __builtin_amdgcn_mfma_f32_16x16x32_bf16(a, bq[q], acc, 0, 0, 0);
        }
        if (n0 + tr < vl) {
            sst  += acc[0] + acc[1] + acc[2] + acc[3];
            sst2 += acc[0]*acc[0] + acc[1]*acc[1] + acc[2]*acc[2] + acc[3]*acc[3];
        }
    }
    sst  += __shfl_xor(sst, 16);  sst  += __shfl_xor(sst, 32);
    sst2 += __shfl_xor(sst2, 16); sst2 += __shfl_xor(sst2, 32);
    if (lane < 16) { wred[wave][lane][0] = sst; wred[wave][lane][1] = sst2; }
    __syncthreads();
    if (t < 16) {
        const float a  = wred[0][t][0] + wred[1][t][0] + wred[2][t][0] + wred[3][t][0];
        const float b2 = wred[0][t][1] + wred[1][t][1] + wred[2][t][1] + wred[3][t][1];
        atomicAdd(&ST[(b * 16 + t) * 2 + 0], a);
        atomicAdd(&ST[(b * 16 + t) * 2 + 1], b2);
    }
}

__global__ void k_statfin(const float* __restrict__ ST, const int* __restrict__ VL,
                          const float* __restrict__ g, const float* __restrict__ be,
                          float* __restrict__ ST2)
{
    const int i = threadIdx.x;
    if (i < 128) {
        const int b = i >> 4, c = i & 15;
        const float sw = (float)VL[b] * 512.f;
        const float mean = ST[i * 2] / sw;
        const float var = ST[i * 2 + 1] / sw - mean * mean;
        const float scale = g[c] * rsqrtf(var + 1e-7f);
        ST2[i * 2] = scale;
        ST2[i * 2 + 1] = be[c] - mean * scale;
    }
}

// ---------------- fused conv1 -> norm+relu (regs) -> conv2, all in LDS; no Y in HBM
__global__ __launch_bounds__(256) void k_fused12(
    const u16* __restrict__ S, const float* __restrict__ ST2,
    const u16* __restrict__ Wf1, const float* __restrict__ c1b,
    const u16* __restrict__ Wf2, const float* __restrict__ c2b,
    u16* __restrict__ S2)
{
    extern __shared__ __align__(16) u16 dsm[];
    u16* xs = dsm;            // 40x40 px * 8ch   = 12800 u16
    u16* ys = dsm + 12800;    // 2 halves of [1296][8], half stride 10368 u16
    const int t = threadIdx.x;
    const int b = blockIdx.z;
    const int n0 = blockIdx.y * 32, m0 = blockIdx.x * 32;
    const u16* sp0 = S + (size_t)(b * 8) * 262144;
    for (int idx = t; idx < 1600; idx += 256) {
        const int r = idx / 40; const int c = idx - r * 40;
        const int gn = n0 - 4 + r, gm = m0 - 4 + c;
        uint4 pk = make_uint4(0, 0, 0, 0);
        if ((unsigned)gn < 512u && (unsigned)gm < 512u) {
            const u16* p = sp0 + (size_t)gn * 512 + gm;
            u16 v[8];
#pragma unroll
            for (int e = 0; e < 8; ++e) v[e] = p[(size_t)e * 262144];
            pk.x = (unsigned)v[0] | ((unsigned)v[1] << 16);
            pk.y = (unsigned)v[2] | ((unsigned)v[3] << 16);
            pk.z = (unsigned)v[4] | ((unsigned)v[5] << 16);
            pk.w = (unsigned)v[6] | ((unsigned)v[7] << 16);
        }
        *reinterpret_cast<uint4*>(&xs[idx * 8]) = pk;
    }
    const int lane = t & 63, wave = t >> 6;
    const int lg = lane >> 4, ln16 = lane & 15;
    short8v bq1[7];
#pragma unroll
    for (int q = 0; q < 7; ++q)
        bq1[q] = *reinterpret_cast<const short8v*>(&Wf1[(q * 64 + lane) * 8]);
    int aoff1[7];
#pragma unroll
    for (int q = 0; q < 7; ++q) {
        const int G = q * 4 + lg; const int p = (G < 25) ? G : 0;
        const int dn = p / 5, dm = p - dn * 5;
        aoff1[q] = (dn * 40 + dm) * 8;
    }
    const float bs1 = c1b[ln16];
    const float scn = ST2[(b * 16 + ln16) * 2 + 0];
    const float shn = ST2[(b * 16 + ln16) * 2 + 1];
    const int yhalf = (ln16 >> 3) * 10368;
    const int ych = ln16 & 7;
    __syncthreads();
    // conv1 over 36x36 y-grid (81 pixel-tiles of 16)
    for (int i = 0; i < 21; ++i) {
        const int j = i * 4 + wave;
        if (j >= 81) break;
        const int pa = j * 16 + ln16;
        const int arow = pa / 36, acol = pa - arow * 36;
        const int abase = (arow * 40 + acol) * 8;
        f32x4 acc = {bs1, bs1, bs1, bs1};
#pragma unroll
        for (int q = 0; q < 7; ++q) {
            short8v a = *reinterpret_cast<const short8v*>(&xs[abase + aoff1[q]]);
            acc = __builtin_amdgcn_mfma_f32_16x16x32_bf16(a, bq1[q], acc, 0, 0, 0);
        }
#pragma unroll
        for (int r = 0; r < 4; ++r) {
            const int pr = j * 16 + lg * 4 + r;
            const int prow = pr / 36, pcol = pr - prow * 36;
            const int gn = n0 - 2 + prow, gm = m0 - 2 + pcol;
            float v = 0.f;
            if ((unsigned)gn < 512u && (unsigned)gm < 512u) {
                v = fmaf(acc[r], scn, shn);
                v = v > 0.f ? v : 0.f;
            }
            ys[pr * 8 + ych + yhalf] = f2bf(v);
        }
    }
    short8v bq2[13];
#pragma unroll
    for (int q = 0; q < 13; ++q)
        bq2[q] = *reinterpret_cast<const short8v*>(&Wf2[(q * 64 + lane) * 8]);
    int aoff2[13];
#pragma unroll
    for (int q = 0; q < 13; ++q) {
        const int G = q * 4 + lg; const int p = (G < 50) ? G : 0;
        const int pos = p >> 1, h = p & 1;
        const int dn = pos / 5, dm = pos - dn * 5;
        aoff2[q] = h * 10368 + (dn * 36 + dm) * 8;
    }
    const float bs2 = (ln16 < 8) ? c2b[ln16] : 0.f;
    __syncthreads();
    for (int i = 0; i < 16; ++i) {
        const int j = wave * 16 + i;
        const int tr = j >> 1, c0 = (j & 1) << 4;
        const int pb = (tr * 36 + c0 + ln16) * 8;
        f32x4 acc = {bs2, bs2, bs2, bs2};
#pragma unroll
        for (int q = 0; q < 13; ++q) {
            short8v a = *reinterpret_cast<const short8v*>(&ys[pb + aoff2[q]]);
            acc = __builtin_amdgcn_mfma_f32_16x16x32_bf16(a, bq2[q], acc, 0, 0, 0);
        }
        if (ln16 < 8) {
            uint2 o = make_uint2(pk2(acc[0], acc[1]), pk2(acc[2], acc[3]));
            *reinterpret_cast<uint2*>(
                &S2[(((size_t)(b * 8 + ln16)) * 512 + n0 + tr) * 512 + m0 + c0 + lg * 4]) = o;
        }
    }
}

// ---------------- fused masked softmax + A@V: logits bf16 -> X2(B,N,512) bf16
__global__ __launch_bounds__(256) void k_softav(
    const u16* __restrict__ SL, const u16* __restrict__ Vt,
    const int* __restrict__ VL, u16* __restrict__ X2)
{
    __shared__ __align__(16) u16 As[9216];   // 128x72
    __shared__ __align__(16) u16 Bs[4608];   // 64x72
    __shared__ float smx[128], siv[128];
    const int t = threadIdx.x, lane = t & 63, wave = t >> 6;
    const int lg = lane >> 4, ln16 = lane & 15;
    const int n0 = blockIdx.x * 128, bh = blockIdx.y;
    const int b = bh >> 3, h = bh & 7;
    const int vl = VL[b];
    const u16* Sp = SL + (size_t)bh * 262144;
    for (int rr = 0; rr < 32; ++rr) {
        const int row = wave * 32 + rr;
        uint4 v = *reinterpret_cast<const uint4*>(Sp + (size_t)(n0 + row) * 512 + lane * 8);
        const unsigned w[4] = {v.x, v.y, v.z, v.w};
        float x[8];
#pragma unroll
        for (int j = 0; j < 4; ++j) {
            x[2 * j]     = bf2f((u16)(w[j] & 0xffff));
            x[2 * j + 1] = bf2f((u16)(w[j] >> 16));
        }
        const int mb = lane * 8;
        float mx = -3.0e38f;
#pragma unroll
        for (int j = 0; j < 8; ++j) {
            if (mb + j >= vl) x[j] = -3.0e38f;
            mx = fmaxf(mx, x[j]);
        }
#pragma unroll
        for (int o = 32; o; o >>= 1) mx = fmaxf(mx, __shfl_xor(mx, o));
        float sm = 0.f;
#pragma unroll
        for (int j = 0; j < 8; ++j) sm += __expf(x[j] - mx);
#pragma unroll
        for (int o = 32; o; o >>= 1) sm += __shfl_xor(sm, o);
        if (lane == 0) { smx[row] = mx; siv[row] = 1.0f / sm; }
    }
    __syncthreads();
    f32x4 acc[2][4] = {};
    for (int k0 = 0; k0 < 512; k0 += 64) {
#pragma unroll
        for (int u = 0; u < 4; ++u) {
            const int chunk = u * 256 + t, row = chunk >> 3, ko = (chunk & 7) * 8;
            uint4 raw = *reinterpret_cast<const uint4*>(Sp + (size_t)(n0 + row) * 512 + k0 + ko);
            const unsigned w[4] = {raw.x, raw.y, raw.z, raw.w};
            const float mxr = smx[row], ivr = siv[row];
            unsigned o[4];
#pragma unroll
            for (int jj = 0; jj < 4; ++jj) {
                const int m0i = k0 + ko + 2 * jj;
                float a0 = (m0i     < vl) ? __expf(bf2f((u16)(w[jj] & 0xffff)) - mxr) * ivr : 0.f;
                float a1 = (m0i + 1 < vl) ? __expf(bf2f((u16)(w[jj] >> 16))   - mxr) * ivr : 0.f;
                o[jj] = pk2(a0, a1);
            }
            *reinterpret_cast<uint4*>(As + row * 72 + ko) = make_uint4(o[0], o[1], o[2], o[3]);
        }
#pragma unroll
        for (int u = 0; u < 2; ++u) {
            const int chunk = u * 256 + t, row = chunk >> 3, ko = (chunk & 7) * 8;
            *reinterpret_cast<uint4*>(Bs + row * 72 + ko) =
                *reinterpret_cast<const uint4*>(Vt + ((size_t)(bh * 64 + row)) * 512 + k0 + ko);
        }
        __syncthreads();
#pragma unroll
        for (int kk = 0; kk < 64; kk += 32) {
            short8v a[2], bfr[4];
#pragma unroll
            for (int mi = 0; mi < 2; ++mi)
                a[mi] = *reinterpret_cast<const short8v*>(As + (wave * 32 + mi * 16 + ln16) * 72 + kk + lg * 8);
#pragma unroll
            for (int ni = 0; ni < 4; ++ni)
                bfr[ni] = *reinterpret_cast<const short8v*>(Bs + (ni * 16 + ln16) * 72 + kk + lg * 8);
#pragma unroll
            for (int mi = 0; mi < 2; ++mi)
#pragma unroll
                for (int ni = 0; ni < 4; ++ni)
                    acc[mi][ni] = __builtin_amdgcn_mfma_f32_16x16x32_bf16(a[mi], bfr[ni], acc[mi][ni], 0, 0, 0);
        }
        __syncthreads();
    }
    u16* Cs = As + wave * 2304;                      // 32x72 per wave
#pragma unroll
    for (int mi = 0; mi < 2; ++mi)
#pragma unroll
        for (int ni = 0; ni < 4; ++ni)
#pragma unroll
            for (int r = 0; r < 4; ++r)
                Cs[(mi * 16 + lg * 4 + r) * 72 + ni * 16 + ln16] = f2bf(acc[mi][ni][r]);
#pragma unroll
    for (int j = 0; j < 4; ++j) {
        const int chunk = j * 64 + lane, row = chunk >> 3, co = (chunk & 7) * 8;
        const int tn = n0 + wave * 32 + row;
        *reinterpret_cast<uint4*>(X2 + ((size_t)(b * 512 + tn)) * 512 + h * 64 + co) =
            *reinterpret_cast<const uint4*>(Cs + row * 72 + co);
    }
}

// ---------------- out-proj (MFMA): X2 @ WhT + bh + query -> P f32
__global__ __launch_bounds__(256) void k_outm(
    const u16* __restrict__ X2, const u16* __restrict__ WT, const float* __restrict__ bias,
    const float* __restrict__ Xq, float* __restrict__ Pout)
{
    __shared__ __align__(16) u16 sh[18432];
    u16* As = sh; u16* Bs = sh + 9216;
    const int t = threadIdx.x, lane = t & 63, wave = t >> 6;
    const int wm = wave >> 1, wn = wave & 1;
    const int lg = lane >> 4, ln16 = lane & 15;
    const int m0 = blockIdx.x * 128, n0 = blockIdx.y * 128;
    f32x4 acc[4][4] = {};
    for (int k0 = 0; k0 < 512; k0 += 64) {
#pragma unroll
        for (int u = 0; u < 4; ++u) {
            const int chunk = u * 256 + t, row = chunk >> 3, ko = (chunk & 7) * 8;
            *reinterpret_cast<uint4*>(As + row * 72 + ko) =
                *reinterpret_cast<const uint4*>(X2 + (size_t)(m0 + row) * 512 + k0 + ko);
            *reinterpret_cast<uint4*>(Bs + row * 72 + ko) =
                *reinterpret_cast<const uint4*>(WT + (size_t)(n0 + row) * 512 + k0 + ko);
        }
        __syncthreads();
#pragma unroll
        for (int kk = 0; kk < 64; kk += 32) {
            short8v a[4], bfr[4];
#pragma unroll
            for (int mi = 0; mi < 4; ++mi)
                a[mi] = *reinterpret_cast<const short8v*>(As + (wm * 64 + mi * 16 + ln16) * 72 + kk + lg * 8);
#pragma unroll
            for (int ni = 0; ni < 4; ++ni)
                bfr[ni] = *reinterpret_cast<const short8v*>(Bs + (wn * 64 + ni * 16 + ln16) * 72 + kk + lg * 8);
#pragma unroll
            for (int mi = 0; mi < 4; ++mi)
#pragma unroll
                for (int ni = 0; ni < 4; ++ni)
                    acc[mi][ni] = __builtin_amdgcn_mfma_f32_16x16x32_bf16(a[mi], bfr[ni], acc[mi][ni], 0, 0, 0);
        }
        __syncthreads();
    }
#pragma unroll
    for (int ni = 0; ni < 4; ++ni) {
        const int cg = n0 + wn * 64 + ni * 16 + ln16;
        const float bv = bias[cg];
#pragma unroll
        for (int mi = 0; mi < 4; ++mi)
#pragma unroll
            for (int r = 0; r < 4; ++r) {
                const int tok = m0 + wm * 64 + mi * 16 + lg * 4 + r;
                Pout[(size_t)tok * 512 + cg] = acc[mi][ni][r] + bv + Xq[(size_t)tok * 512 + cg];
            }
    }
}

// ---------------- final LayerNorm over D=512
__global__ __launch_bounds__(256) void k_ln(
    const float* __restrict__ P, const float* __restrict__ g,
    const float* __restrict__ be, float* __restrict__ out)
{
    const int row = blockIdx.x * 4 + (threadIdx.x >> 6);
    const int lane = threadIdx.x & 63;
    const float* p = P + (size_t)row * 512;
    float4 v0 = reinterpret_cast<const float4*>(p)[lane];
    float4 v1 = reinterpret_cast<const float4*>(p)[64 + lane];
    float s = v0.x + v0.y + v0.z + v0.w + v1.x + v1.y + v1.z + v1.w;
#pragma unroll
    for (int o = 32; o; o >>= 1) s += __shfl_xor(s, o);
    const float mean = s * (1.0f / 512.0f);
    float d[8] = {v0.x - mean, v0.y - mean, v0.z - mean, v0.w - mean,
                  v1.x - mean, v1.y - mean, v1.z - mean, v1.w - mean};
    float s2 = 0.f;
#pragma unroll
    for (int j = 0; j < 8; ++j) s2 += d[j] * d[j];
#pragma unroll
    for (int o = 32; o; o >>= 1) s2 += __shfl_xor(s2, o);
    const float rstd = rsqrtf(s2 * (1.0f / 512.0f) + 1e-7f);
    float4 g0 = reinterpret_cast<const float4*>(g)[lane];
    float4 g1 = reinterpret_cast<const float4*>(g)[64 + lane];
    float4 b0 = reinterpret_cast<const float4*>(be)[lane];
    float4 b1 = reinterpret_cast<const float4*>(be)[64 + lane];
    float* op = out + (size_t)row * 512;
    reinterpret_cast<float4*>(op)[lane] =
        make_float4(d[0] * rstd * g0.x + b0.x, d[1] * rstd * g0.y + b0.y,
                    d[2] * rstd * g0.z + b0.z, d[3] * rstd * g0.w + b0.w);
    reinterpret_cast<float4*>(op)[64 + lane] =
        make_float4(d[4] * rstd * g1.x + b1.x, d[5] * rstd * g1.y + b1.y,
                    d[6] * rstd * g1.z + b1.z, d[7] * rstd * g1.w + b1.w);
}

extern "C" void kernel_launch(void* const* d_in, const int* in_sizes, int n_in,
                              void* d_out, int out_size, void* d_ws, size_t ws_size,
                              hipStream_t stream)
{
    const float* query = (const float*)d_in[0];
    const int*   VL    = (const int*)d_in[1];
    const float* Wq = (const float*)d_in[2];  const float* bq = (const float*)d_in[3];
    const float* Wk = (const float*)d_in[4];  const float* bk = (const float*)d_in[5];
    const float* Wv = (const float*)d_in[6];  const float* bv = (const float*)d_in[7];
    const float* Wh = (const float*)d_in[8];  const float* bh = (const float*)d_in[9];
    const float* pos_k = (const float*)d_in[10];
    const float* c1w = (const float*)d_in[11]; const float* c1b = (const float*)d_in[12];
    const float* n1g = (const float*)d_in[13]; const float* n1b = (const float*)d_in[14];
    const float* c2w = (const float*)d_in[15]; const float* c2b = (const float*)d_in[16];
    const float* lng = (const float*)d_in[17]; const float* lnb = (const float*)d_in[18];

    float* ws = (float*)d_ws;
    const size_t M1 = (size_t)1 << 20;
    // f32-unit layout (peak ~23M f32 = 92 MB):
    //  [0,8M)    S1  scores bf16 (16M u16)
    //  [8M,16M)  S2  conv2 logits bf16 (16M u16)
    //  [16M,17M) Xb bf16 -> later X2
    //  [17M,18M) Qb ; [18M,19M) Kb ; [19M,20M) Vt
    //  [20M,22M) QPb bf16 -> later Pout f32
    //  [22M,22.5M) WT x4 ; +pos_kb/Wf1/Wf2
    //  [23M,..)  ST/ST2
    u16* S1  = (u16*)ws;
    u16* S2  = (u16*)(ws + 8 * M1);
    u16* Xb  = (u16*)(ws + 16 * M1);
    u16* Qb  = (u16*)(ws + 17 * M1);
    u16* Kb  = (u16*)(ws + 18 * M1);
    u16* Vt  = (u16*)(ws + 19 * M1);
    u16* QPb = (u16*)(ws + 20 * M1);
    u16* WqT = (u16*)(ws + 22 * M1);
    u16* WkT = WqT + 262144;
    u16* WvT = WkT + 262144;
    u16* WhT = WvT + 262144;
    u16* pos_kb = (u16*)(ws + 22 * M1 + 524288);
    u16* Wf1 = pos_kb + 8192;
    u16* Wf2 = Wf1 + 3584;
    float* ST  = ws + 23 * M1;
    float* ST2 = ST + 256;
    u16* X2 = Xb;
    float* Pout = ws + 20 * M1;

    hipMemsetAsync(ST, 0, 256 * sizeof(float), stream);

    k_prepx<<<1024, 256, 0, stream>>>(query, Xb);
    k_prept<<<dim3(8, 8, 5), 256, 0, stream>>>(Wq, Wk, Wv, Wh, WqT, WkT, WvT, WhT,
                                               c1w, c2w, pos_k, Wf1, Wf2, pos_kb);
    k_qkvm<<<dim3(32, 4, 3), 256, 0, stream>>>(Xb, WqT, WkT, WvT, bq, bk, bv, Qb, Kb, Vt);
    k_qposm<<<dim3(4, 64), 256, 0, stream>>>(Qb, pos_kb, QPb);
    k_scoresm<<<dim3(4, 4, 64), 256, 0, stream>>>(Qb, Kb, QPb, S1);
    k_stats1<<<dim3(16, 16, 8), 256, 0, stream>>>(S1, Wf1, c1b, VL, ST);
    k_statfin<<<1, 128, 0, stream>>>(ST, VL, n1g, n1b, ST2);
    k_fused12<<<dim3(16, 16, 8), 256, 67072, stream>>>(S1, ST2, Wf1, c1b, Wf2, c2b, S2);
    k_softav<<<dim3(4, 64), 256, 0, stream>>>(S2, Vt, VL, X2);
    k_outm<<<dim3(32, 4), 256, 0, stream>>>(X2, WhT, bh, query, Pout);
    k_ln<<<1024, 256, 0, stream>>>(Pout, lng, lnb, (float*)d_out);
}

// Round 6
// 312.011 us; speedup vs baseline: 1.0451x; 1.0451x over previous
//
#include <hip/hip_runtime.h>

#define PC_ 60

typedef unsigned short u16;
typedef __attribute__((ext_vector_type(8))) short short8v;   // 8 bf16 (4 VGPR)
typedef __attribute__((ext_vector_type(4))) float f32x4;

__device__ inline float bf2f(u16 u) {
    union { unsigned int i; float f; } x; x.i = ((unsigned)u) << 16; return x.f;
}
__device__ inline u16 f2bf(float f) {
    union { float f; unsigned int i; } x; x.f = f;
    unsigned int r = x.i + 0x7fff + ((x.i >> 16) & 1);   // RNE
    return (u16)(r >> 16);
}
__device__ inline unsigned pk2(float a, float b) {
    return (unsigned)f2bf(a) | ((unsigned)f2bf(b) << 16);
}

// ---------------- prep: W transposes (z<4) + conv-frag/pos (z==4) + query->bf16 (z==5)
__global__ __launch_bounds__(256) void k_prept(
    const float* __restrict__ W0, const float* __restrict__ W1,
    const float* __restrict__ W2, const float* __restrict__ W3,
    u16* __restrict__ T0, u16* __restrict__ T1, u16* __restrict__ T2, u16* __restrict__ T3,
    const float* __restrict__ c1w, const float* __restrict__ c2w,
    const float* __restrict__ pos_k,
    u16* __restrict__ Wf1, u16* __restrict__ Wf2, u16* __restrict__ pos_kb,
    const float* __restrict__ X, u16* __restrict__ Xb)
{
    const int z = blockIdx.z;
    const int t = threadIdx.x;
    if (z == 5) {
        const int blk = blockIdx.y * 8 + blockIdx.x;
#pragma unroll
        for (int k2 = 0; k2 < 16; ++k2) {
            const int i = ((blk * 16 + k2) * 256 + t) * 8;
            float4 a = *reinterpret_cast<const float4*>(X + i);
            float4 b = *reinterpret_cast<const float4*>(X + i + 4);
            *reinterpret_cast<uint4*>(Xb + i) =
                make_uint4(pk2(a.x, a.y), pk2(a.z, a.w), pk2(b.x, b.y), pk2(b.z, b.w));
        }
        return;
    }
    if (z == 4) {
        if (blockIdx.x != 0 || blockIdx.y != 0) return;
        for (int s = t; s < 448; s += 256) {
            const int q = s >> 6, l = s & 63, lg = l >> 4, n = l & 15;
            const int G = q * 4 + lg;
            unsigned o[4];
#pragma unroll
            for (int u2 = 0; u2 < 4; ++u2) {
                float v0 = 0.f, v1 = 0.f;
                if (G < 25) {
                    const int dn = G / 5, dm = G - dn * 5;
                    v0 = c1w[((dn * 5 + dm) * 8 + u2 * 2 + 0) * 16 + n];
                    v1 = c1w[((dn * 5 + dm) * 8 + u2 * 2 + 1) * 16 + n];
                }
                o[u2] = pk2(v0, v1);
            }
            *reinterpret_cast<uint4*>(&Wf1[s * 8]) = make_uint4(o[0], o[1], o[2], o[3]);
        }
        for (int s = t; s < 832; s += 256) {
            const int q = s >> 6, l = s & 63, lg = l >> 4, n = l & 15;
            const int G = q * 4 + lg;
            unsigned o[4];
#pragma unroll
            for (int u2 = 0; u2 < 4; ++u2) {
                float v0 = 0.f, v1 = 0.f;
                if (G < 50 && n < 8) {
                    const int pos = G >> 1, h = G & 1;
                    const int dn = pos / 5, dm = pos - dn * 5;
                    v0 = c2w[((dn * 5 + dm) * 16 + h * 8 + u2 * 2 + 0) * 8 + n];
                    v1 = c2w[((dn * 5 + dm) * 16 + h * 8 + u2 * 2 + 1) * 8 + n];
                }
                o[u2] = pk2(v0, v1);
            }
            *reinterpret_cast<uint4*>(&Wf2[s * 8]) = make_uint4(o[0], o[1], o[2], o[3]);
        }
        for (int s = t; s < 128 * 64; s += 256) {
            const int r = s >> 6;
            pos_kb[s] = (r < 121) ? f2bf(pos_k[s]) : (u16)0;
        }
        return;
    }
    const float* W = (z == 0) ? W0 : (z == 1) ? W1 : (z == 2) ? W2 : W3;
    u16* T        = (z == 0) ? T0 : (z == 1) ? T1 : (z == 2) ? T2 : T3;
    __shared__ float ls[64 * 65];
    const int k0 = blockIdx.x * 64, n0 = blockIdx.y * 64;
#pragma unroll
    for (int i = 0; i < 16; ++i) {
        const int idx = t + i * 256, r = idx >> 6, c = idx & 63;
        ls[c * 65 + r] = W[(size_t)(k0 + r) * 512 + n0 + c];
    }
    __syncthreads();
#pragma unroll
    for (int i = 0; i < 16; ++i) {
        const int idx = t + i * 256, r = idx >> 6, c = idx & 63;
        T[(size_t)(n0 + r) * 512 + k0 + c] = f2bf(ls[r * 65 + c]);
    }
}

// ---------------- QKV (MFMA): Xb @ WT -> Q/K bf16 (B,H,N,DH), V^T bf16 (B,H,DH,N)
__global__ __launch_bounds__(256) void k_qkvm(
    const u16* __restrict__ Xb,
    const u16* __restrict__ WT0, const u16* __restrict__ WT1, const u16* __restrict__ WT2,
    const float* __restrict__ b0, const float* __restrict__ b1, const float* __restrict__ b2,
    u16* __restrict__ Qb, u16* __restrict__ Kb, u16* __restrict__ Vt)
{
    const int z = blockIdx.z;
    const u16* WT    = (z == 0) ? WT0 : (z == 1) ? WT1 : WT2;
    const float* bias = (z == 0) ? b0 : (z == 1) ? b1 : b2;
    __shared__ __align__(16) u16 sh[18432];          // As 128x72, Bs 128x72
    u16* As = sh; u16* Bs = sh + 9216;
    const int t = threadIdx.x, lane = t & 63, wave = t >> 6;
    const int wm = wave >> 1, wn = wave & 1;
    const int lg = lane >> 4, ln16 = lane & 15;
    const int m0 = blockIdx.x * 128, n0 = blockIdx.y * 128;
    f32x4 acc[4][4] = {};
    for (int k0 = 0; k0 < 512; k0 += 64) {
#pragma unroll
        for (int u = 0; u < 4; ++u) {
            const int chunk = u * 256 + t, row = chunk >> 3, ko = (chunk & 7) * 8;
            *reinterpret_cast<uint4*>(As + row * 72 + ko) =
                *reinterpret_cast<const uint4*>(Xb + (size_t)(m0 + row) * 512 + k0 + ko);
            *reinterpret_cast<uint4*>(Bs + row * 72 + ko) =
                *reinterpret_cast<const uint4*>(WT + (size_t)(n0 + row) * 512 + k0 + ko);
        }
        __syncthreads();
#pragma unroll
        for (int kk = 0; kk < 64; kk += 32) {
            short8v a[4], bfr[4];
#pragma unroll
            for (int mi = 0; mi < 4; ++mi)
                a[mi] = *reinterpret_cast<const short8v*>(As + (wm * 64 + mi * 16 + ln16) * 72 + kk + lg * 8);
#pragma unroll
            for (int ni = 0; ni < 4; ++ni)
                bfr[ni] = *reinterpret_cast<const short8v*>(Bs + (wn * 64 + ni * 16 + ln16) * 72 + kk + lg * 8);
#pragma unroll
            for (int mi = 0; mi < 4; ++mi)
#pragma unroll
                for (int ni = 0; ni < 4; ++ni)
                    acc[mi][ni] = __builtin_amdgcn_mfma_f32_16x16x32_bf16(a[mi], bfr[ni], acc[mi][ni], 0, 0, 0);
        }
        __syncthreads();
    }
    u16* Cs = sh + wave * 4608;                       // 64x72 per wave
#pragma unroll
    for (int ni = 0; ni < 4; ++ni) {
        const float bv = bias[n0 + wn * 64 + ni * 16 + ln16];
#pragma unroll
        for (int mi = 0; mi < 4; ++mi)
#pragma unroll
            for (int r = 0; r < 4; ++r)
                Cs[(mi * 16 + lg * 4 + r) * 72 + ni * 16 + ln16] = f2bf(acc[mi][ni][r] + bv);
    }
    if (z < 2) {
        u16* O = (z == 0) ? Qb : Kb;
#pragma unroll
        for (int j = 0; j < 8; ++j) {
            const int chunk = j * 64 + lane, row = chunk >> 3, co = (chunk & 7) * 8;
            const int tok = m0 + wm * 64 + row;
            const int b = tok >> 9, n = tok & 511;
            const int cg = n0 + wn * 64 + co;
            const int h = cg >> 6, dh = cg & 63;
            *reinterpret_cast<uint4*>(O + ((size_t)((b * 8 + h) * 512 + n)) * 64 + dh) =
                *reinterpret_cast<const uint4*>(Cs + row * 72 + co);
        }
    } else {
#pragma unroll
        for (int j = 0; j < 8; ++j) {
            const int chunk = j * 64 + lane, dr = chunk >> 3, no8 = (chunk & 7) * 8;
            const int cg = n0 + wn * 64 + dr;
            const int h = cg >> 6, dh = cg & 63;
            const int tok = m0 + wm * 64 + no8;
            const int b = tok >> 9, n = tok & 511;
            u16 v[8];
#pragma unroll
            for (int e = 0; e < 8; ++e) v[e] = Cs[(no8 + e) * 72 + dr];
            uint4 o = make_uint4((unsigned)v[0] | ((unsigned)v[1] << 16),
                                 (unsigned)v[2] | ((unsigned)v[3] << 16),
                                 (unsigned)v[4] | ((unsigned)v[5] << 16),
                                 (unsigned)v[6] | ((unsigned)v[7] << 16));
            *reinterpret_cast<uint4*>(Vt + ((size_t)((b * 8 + h) * 64 + dh)) * 512 + n) = o;
        }
    }
}

// ---------------- qp (MFMA): Q(bh,n,64) @ pos_k^T -> QP bf16 (bh,n,128pad)
__global__ __launch_bounds__(256) void k_qposm(
    const u16* __restrict__ Qb, const u16* __restrict__ pos_kb, u16* __restrict__ QP)
{
    __shared__ __align__(16) u16 sh[18432];
    u16* As = sh; u16* Bs = sh + 9216;
    const int t = threadIdx.x, lane = t & 63, wave = t >> 6;
    const int lg = lane >> 4, ln16 = lane & 15;
    const int n0 = blockIdx.x * 128, bh = blockIdx.y;
#pragma unroll
    for (int u = 0; u < 4; ++u) {
        const int chunk = u * 256 + t, row = chunk >> 3, ko = (chunk & 7) * 8;
        *reinterpret_cast<uint4*>(As + row * 72 + ko) =
            *reinterpret_cast<const uint4*>(Qb + ((size_t)(bh * 512 + n0 + row)) * 64 + ko);
        *reinterpret_cast<uint4*>(Bs + row * 72 + ko) =
            *reinterpret_cast<const uint4*>(pos_kb + (size_t)row * 64 + ko);
    }
    __syncthreads();
    f32x4 acc[2][8] = {};
#pragma unroll
    for (int kk = 0; kk < 64; kk += 32) {
        short8v a[2], bfr[8];
#pragma unroll
        for (int mi = 0; mi < 2; ++mi)
            a[mi] = *reinterpret_cast<const short8v*>(As + (wave * 32 + mi * 16 + ln16) * 72 + kk + lg * 8);
#pragma unroll
        for (int ni = 0; ni < 8; ++ni)
            bfr[ni] = *reinterpret_cast<const short8v*>(Bs + (ni * 16 + ln16) * 72 + kk + lg * 8);
#pragma unroll
        for (int mi = 0; mi < 2; ++mi)
#pragma unroll
            for (int ni = 0; ni < 8; ++ni)
                acc[mi][ni] = __builtin_amdgcn_mfma_f32_16x16x32_bf16(a[mi], bfr[ni], acc[mi][ni], 0, 0, 0);
    }
    __syncthreads();
    u16* Cs = sh + wave * 4352;                      // 32x136 per wave
#pragma unroll
    for (int mi = 0; mi < 2; ++mi)
#pragma unroll
        for (int ni = 0; ni < 8; ++ni)
#pragma unroll
            for (int r = 0; r < 4; ++r)
                Cs[(mi * 16 + lg * 4 + r) * 136 + ni * 16 + ln16] = f2bf(acc[mi][ni][r]);
#pragma unroll
    for (int j = 0; j < 8; ++j) {
        const int chunk = j * 64 + lane, row = chunk >> 4, co = (chunk & 15) * 8;
        *reinterpret_cast<uint4*>(QP + ((size_t)(bh * 512 + n0 + wave * 32 + row)) * 128 + co) =
            *reinterpret_cast<const uint4*>(Cs + row * 136 + co);
    }
}

// ---------------- scores (MFMA): (Q@K^T + QP[rel]) / 8 -> S bf16 (bh,n,m)
__global__ __launch_bounds__(256) void k_scoresm(
    const u16* __restrict__ Qb, const u16* __restrict__ Kb, const u16* __restrict__ QP,
    u16* __restrict__ S)
{
    __shared__ __align__(16) u16 sh[18432];
    u16* As = sh; u16* Bs = sh + 9216;
    const int t = threadIdx.x, lane = t & 63, wave = t >> 6;
    const int wm = wave >> 1, wn = wave & 1;
    const int lg = lane >> 4, ln16 = lane & 15;
    const int m0 = blockIdx.x * 128, n0 = blockIdx.y * 128, bh = blockIdx.z;
#pragma unroll
    for (int u = 0; u < 4; ++u) {
        const int chunk = u * 256 + t, row = chunk >> 3, ko = (chunk & 7) * 8;
        *reinterpret_cast<uint4*>(As + row * 72 + ko) =
            *reinterpret_cast<const uint4*>(Qb + ((size_t)(bh * 512 + n0 + row)) * 64 + ko);
        *reinterpret_cast<uint4*>(Bs + row * 72 + ko) =
            *reinterpret_cast<const uint4*>(Kb + ((size_t)(bh * 512 + m0 + row)) * 64 + ko);
    }
    __syncthreads();
    f32x4 acc[4][4] = {};
#pragma unroll
    for (int kk = 0; kk < 64; kk += 32) {
        short8v a[4], bfr[4];
#pragma unroll
        for (int mi = 0; mi < 4; ++mi)
            a[mi] = *reinterpret_cast<const short8v*>(As + (wm * 64 + mi * 16 + ln16) * 72 + kk + lg * 8);
#pragma unroll
        for (int ni = 0; ni < 4; ++ni)
            bfr[ni] = *reinterpret_cast<const short8v*>(Bs + (wn * 64 + ni * 16 + ln16) * 72 + kk + lg * 8);
#pragma unroll
        for (int mi = 0; mi < 4; ++mi)
#pragma unroll
            for (int ni = 0; ni < 4; ++ni)
                acc[mi][ni] = __builtin_amdgcn_mfma_f32_16x16x32_bf16(a[mi], bfr[ni], acc[mi][ni], 0, 0, 0);
    }
    __syncthreads();
    u16* QPs = sh;                                   // 128x128 bf16
#pragma unroll
    for (int u = 0; u < 8; ++u) {
        const int chunk = u * 256 + t, row = chunk >> 4, co = (chunk & 15) * 8;
        *reinterpret_cast<uint4*>(QPs + row * 128 + co) =
            *reinterpret_cast<const uint4*>(QP + ((size_t)(bh * 512 + n0 + row)) * 128 + co);
    }
    __syncthreads();
#pragma unroll
    for (int mi = 0; mi < 4; ++mi)
#pragma unroll
        for (int ni = 0; ni < 4; ++ni) {
            const int m_g = m0 + wn * 64 + ni * 16 + ln16;
#pragma unroll
            for (int r = 0; r < 4; ++r) {
                const int n_loc = wm * 64 + mi * 16 + lg * 4 + r;
                const int n_g = n0 + n_loc;
                int rel = m_g - n_g;
                rel = rel < -PC_ ? -PC_ : (rel > PC_ ? PC_ : rel);
                const float v = (acc[mi][ni][r] + bf2f(QPs[n_loc * 128 + rel + PC_])) * 0.125f;
                S[(size_t)bh * 262144 + (size_t)n_g * 512 + m_g] = f2bf(v);
            }
        }
}

// ---------------- conv1 (MFMA): S bf16 planar -> Y(B,512,512,16) bf16 ch-last + fused stats
__global__ __launch_bounds__(256) void k_conv1m(
    const u16* __restrict__ S, const u16* __restrict__ Wf,
    const float* __restrict__ bias, u16* __restrict__ Y,
    const int* __restrict__ VL, float* __restrict__ ST)
{
    __shared__ __align__(16) u16 xs[10368];
    __shared__ float wred[4][16][2];
    const int t = threadIdx.x;
    const int b = blockIdx.z;
    const int n0 = blockIdx.y * 32;
    const int m0 = blockIdx.x * 32;
    const u16* sp0 = S + (size_t)(b * 8) * 262144;
    for (int idx = t; idx < 1296; idx += 256) {
        const int r = idx / 36; const int c = idx - r * 36;
        const int gn = n0 - 2 + r, gm = m0 - 2 + c;
        uint4 pk = make_uint4(0, 0, 0, 0);
        if ((unsigned)gn < 512u && (unsigned)gm < 512u) {
            const u16* p = sp0 + (size_t)gn * 512 + gm;
            u16 v[8];
#pragma unroll
            for (int e = 0; e < 8; ++e) v[e] = p[(size_t)e * 262144];
            pk.x = (unsigned)v[0] | ((unsigned)v[1] << 16);
            pk.y = (unsigned)v[2] | ((unsigned)v[3] << 16);
            pk.z = (unsigned)v[4] | ((unsigned)v[5] << 16);
            pk.w = (unsigned)v[6] | ((unsigned)v[7] << 16);
        }
        *reinterpret_cast<uint4*>(&xs[idx * 8]) = pk;
    }
    const int lane = t & 63, wave = t >> 6;
    const int lg = lane >> 4, ln16 = lane & 15;
    short8v bq[7];
#pragma unroll
    for (int q = 0; q < 7; ++q)
        bq[q] = *reinterpret_cast<const short8v*>(&Wf[(q * 64 + lane) * 8]);
    int aoff[7];
#pragma unroll
    for (int q = 0; q < 7; ++q) {
        const int G = q * 4 + lg; const int p = (G < 25) ? G : 0;
        const int dn = p / 5, dm = p - dn * 5;
        aoff[q] = (dn * 36 + dm) * 8;
    }
    const float bs = bias[ln16];
    const int vl = VL[b];
    const int cb = ln16 & ~1;          // paired-channel base for u32 stores
    const bool evn = (ln16 & 1) == 0;
    float sst = 0.f, sst2 = 0.f;
    __syncthreads();
    for (int i = 0; i < 16; ++i) {
        const int j = wave * 16 + i;
        const int tr = j >> 1, c0 = (j & 1) << 4;
        const int pb = (tr * 36 + c0 + ln16) * 8;
        f32x4 acc = {bs, bs, bs, bs};
#pragma unroll
        for (int q = 0; q < 7; ++q) {
            short8v a = *reinterpret_cast<const short8v*>(&xs[pb + aoff[q]]);
            acc = __builtin_amdgcn_mfma_f32_16x16x32_bf16(a, bq[q], acc, 0, 0, 0);
        }
        // paired-channel u32 stores: even lane stores px r=0,1; odd lane px r=2,3
        unsigned wv_[4];
#pragma unroll
        for (int r = 0; r < 4; ++r) {
            const float ex = __shfl_xor(acc[r], 1);
            wv_[r] = evn ? pk2(acc[r], ex) : pk2(ex, acc[r]);
        }
        u16* yb = Y + (((size_t)(b * 512 + n0 + tr)) * 512 + (m0 + c0 + lg * 4)) * 16 + cb;
        if (evn) {
            *reinterpret_cast<unsigned*>(yb)      = wv_[0];
            *reinterpret_cast<unsigned*>(yb + 16) = wv_[1];
        } else {
            *reinterpret_cast<unsigned*>(yb + 32) = wv_[2];
            *reinterpret_cast<unsigned*>(yb + 48) = wv_[3];
        }
        if (n0 + tr < vl) {
            sst  += acc[0] + acc[1] + acc[2] + acc[3];
            sst2 += acc[0]*acc[0] + acc[1]*acc[1] + acc[2]*acc[2] + acc[3]*acc[3];
        }
    }
    sst  += __shfl_xor(sst, 16);  sst  += __shfl_xor(sst, 32);
    sst2 += __shfl_xor(sst2, 16); sst2 += __shfl_xor(sst2, 32);
    if (lane < 16) { wred[wave][lane][0] = sst; wred[wave][lane][1] = sst2; }
    __syncthreads();
    if (t < 16) {
        const float a  = wred[0][t][0] + wred[1][t][0] + wred[2][t][0] + wred[3][t][0];
        const float b2 = wred[0][t][1] + wred[1][t][1] + wred[2][t][1] + wred[3][t][1];
        atomicAdd(&ST[(b * 16 + t) * 2 + 0], a);
        atomicAdd(&ST[(b * 16 + t) * 2 + 1], b2);
    }
}

// ---------------- conv2 (MFMA): Y ch-last bf16, statfin + norm+relu fused -> S2 bf16 planar
__global__ __launch_bounds__(256) void k_conv2m(
    const u16* __restrict__ Y, const float* __restrict__ ST,
    const int* __restrict__ VL, const float* __restrict__ n1g, const float* __restrict__ n1b,
    const u16* __restrict__ Wf, const float* __restrict__ bias,
    u16* __restrict__ S2)
{
    __shared__ __align__(16) u16 xs[20736];
    __shared__ float ssh[16][2];
    const int t = threadIdx.x;
    const int b = blockIdx.z;
    const int n0 = blockIdx.y * 32, m0 = blockIdx.x * 32;
    if (t < 16) {                       // folded statfin (redundant per block, trivial)
        const float sw = (float)VL[b] * 512.f;
        const float mean = ST[(b * 16 + t) * 2 + 0] / sw;
        const float var  = ST[(b * 16 + t) * 2 + 1] / sw - mean * mean;
        const float sc = n1g[t] * rsqrtf(var + 1e-7f);
        ssh[t][0] = sc;
        ssh[t][1] = n1b[t] - mean * sc;
    }
    __syncthreads();
    float sc[16], shv[16];
#pragma unroll
    for (int ch = 0; ch < 16; ++ch) { sc[ch] = ssh[ch][0]; shv[ch] = ssh[ch][1]; }
    for (int idx = t; idx < 1296; idx += 256) {
        const int r = idx / 36; const int c = idx - r * 36;
        const int gn = n0 - 2 + r, gm = m0 - 2 + c;
        uint4 p0 = make_uint4(0, 0, 0, 0), p1 = p0;
        if ((unsigned)gn < 512u && (unsigned)gm < 512u) {
            const u16* yp = Y + (((size_t)(b * 512 + gn)) * 512 + gm) * 16;
            const uint4 r0 = *reinterpret_cast<const uint4*>(yp);
            const uint4 r1 = *reinterpret_cast<const uint4*>(yp + 8);
            const unsigned w0[4] = {r0.x, r0.y, r0.z, r0.w};
            const unsigned w1[4] = {r1.x, r1.y, r1.z, r1.w};
            unsigned o0[4], o1[4];
#pragma unroll
            for (int u2 = 0; u2 < 4; ++u2) {
                const int ch = u2 * 2;
                float a0 = bf2f((u16)(w0[u2] & 0xffff));
                float a1 = bf2f((u16)(w0[u2] >> 16));
                a0 = fmaf(a0, sc[ch], shv[ch]);          a0 = a0 > 0.f ? a0 : 0.f;
                a1 = fmaf(a1, sc[ch + 1], shv[ch + 1]);  a1 = a1 > 0.f ? a1 : 0.f;
                o0[u2] = pk2(a0, a1);
                const int ch2 = 8 + u2 * 2;
                float b0 = bf2f((u16)(w1[u2] & 0xffff));
                float b1 = bf2f((u16)(w1[u2] >> 16));
                b0 = fmaf(b0, sc[ch2], shv[ch2]);          b0 = b0 > 0.f ? b0 : 0.f;
                b1 = fmaf(b1, sc[ch2 + 1], shv[ch2 + 1]);  b1 = b1 > 0.f ? b1 : 0.f;
                o1[u2] = pk2(b0, b1);
            }
            p0 = make_uint4(o0[0], o0[1], o0[2], o0[3]);
            p1 = make_uint4(o1[0], o1[1], o1[2], o1[3]);
        }
        *reinterpret_cast<uint4*>(&xs[idx * 8]) = p0;
        *reinterpret_cast<uint4*>(&xs[10368 + idx * 8]) = p1;
    }
    const int lane = t & 63, wave = t >> 6;
    const int lg = lane >> 4, ln16 = lane & 15;
    short8v bq[13];
#pragma unroll
    for (int q = 0; q < 13; ++q)
        bq[q] = *reinterpret_cast<const short8v*>(&Wf[(q * 64 + lane) * 8]);
    int aoff[13];
#pragma unroll
    for (int q = 0; q < 13; ++q) {
        const int G = q * 4 + lg; const int p = (G < 50) ? G : 0;
        const int pos = p >> 1, h = p & 1;
        const int dn = pos / 5, dm = pos - dn * 5;
        aoff[q] = h * 10368 + (dn * 36 + dm) * 8;
    }
    const float bs = (ln16 < 8) ? bias[ln16] : 0.f;
    __syncthreads();
    for (int i = 0; i < 16; ++i) {
        const int j = wave * 16 + i;
        const int tr = j >> 1, c0 = (j & 1) << 4;
        const int pb = (tr * 36 + c0 + ln16) * 8;
        f32x4 acc = {bs, bs, bs, bs};
#pragma unroll
        for (int q = 0; q < 13; ++q) {
            short8v a = *reinterpret_cast<const short8v*>(&xs[pb + aoff[q]]);
            acc = __builtin_amdgcn_mfma_f32_16x16x32_bf16(a, bq[q], acc, 0, 0, 0);
        }
        if (ln16 < 8) {
            uint2 o = make_uint2(pk2(acc[0], acc[1]), pk2(acc[2], acc[3]));
            *reinterpret_cast<uint2*>(
                &S2[(((size_t)(b * 8 + ln16)) * 512 + n0 + tr) * 512 + m0 + c0 + lg * 4]) = o;
        }
    }
}

// ---------------- fused masked softmax + A@V: logits bf16 -> X2(B,N,512) bf16
__global__ __launch_bounds__(256) void k_softav(
    const u16* __restrict__ SL, const u16* __restrict__ Vt,
    const int* __restrict__ VL, u16* __restrict__ X2)
{
    __shared__ __align__(16) u16 As[9216];   // 128x72
    __shared__ __align__(16) u16 Bs[4608];   // 64x72
    __shared__ float smx[128], siv[128];
    const int t = threadIdx.x, lane = t & 63, wave = t >> 6;
    const int lg = lane >> 4, ln16 = lane & 15;
    const int n0 = blockIdx.x * 128, bh = blockIdx.y;
    const int b = bh >> 3, h = bh & 7;
    const int vl = VL[b];
    const u16* Sp = SL + (size_t)bh * 262144;
    for (int rr = 0; rr < 32; ++rr) {
        const int row = wave * 32 + rr;
        uint4 v = *reinterpret_cast<const uint4*>(Sp + (size_t)(n0 + row) * 512 + lane * 8);
        const unsigned w[4] = {v.x, v.y, v.z, v.w};
        float x[8];
#pragma unroll
        for (int j = 0; j < 4; ++j) {
            x[2 * j]     = bf2f((u16)(w[j] & 0xffff));
            x[2 * j + 1] = bf2f((u16)(w[j] >> 16));
        }
        const int mb = lane * 8;
        float mx = -3.0e38f;
#pragma unroll
        for (int j = 0; j < 8; ++j) {
            if (mb + j >= vl) x[j] = -3.0e38f;
            mx = fmaxf(mx, x[j]);
        }
#pragma unroll
        for (int o = 32; o; o >>= 1) mx = fmaxf(mx, __shfl_xor(mx, o));
        float sm = 0.f;
#pragma unroll
        for (int j = 0; j < 8; ++j) sm += __expf(x[j] - mx);
#pragma unroll
        for (int o = 32; o; o >>= 1) sm += __shfl_xor(sm, o);
        if (lane == 0) { smx[row] = mx; siv[row] = 1.0f / sm; }
    }
    __syncthreads();
    f32x4 acc[2][4] = {};
    for (int k0 = 0; k0 < 512; k0 += 64) {
#pragma unroll
        for (int u = 0; u < 4; ++u) {
            const int chunk = u * 256 + t, row = chunk >> 3, ko = (chunk & 7) * 8;
            uint4 raw = *reinterpret_cast<const uint4*>(Sp + (size_t)(n0 + row) * 512 + k0 + ko);
            const unsigned w[4] = {raw.x, raw.y, raw.z, raw.w};
            const float mxr = smx[row], ivr = siv[row];
            unsigned o[4];
#pragma unroll
            for (int jj = 0; jj < 4; ++jj) {
                const int m0i = k0 + ko + 2 * jj;
                float a0 = (m0i     < vl) ? __expf(bf2f((u16)(w[jj] & 0xffff)) - mxr) * ivr : 0.f;
                float a1 = (m0i + 1 < vl) ? __expf(bf2f((u16)(w[jj] >> 16))   - mxr) * ivr : 0.f;
                o[jj] = pk2(a0, a1);
            }
            *reinterpret_cast<uint4*>(As + row * 72 + ko) = make_uint4(o[0], o[1], o[2], o[3]);
        }
#pragma unroll
        for (int u = 0; u < 2; ++u) {
            const int chunk = u * 256 + t, row = chunk >> 3, ko = (chunk & 7) * 8;
            *reinterpret_cast<uint4*>(Bs + row * 72 + ko) =
                *reinterpret_cast<const uint4*>(Vt + ((size_t)(bh * 64 + row)) * 512 + k0 + ko);
        }
        __syncthreads();
#pragma unroll
        for (int kk = 0; kk < 64; kk += 32) {
            short8v a[2], bfr[4];
#pragma unroll
            for (int mi = 0; mi < 2; ++mi)
                a[mi] = *reinterpret_cast<const short8v*>(As + (wave * 32 + mi * 16 + ln16) * 72 + kk + lg * 8);
#pragma unroll
            for (int ni = 0; ni < 4; ++ni)
                bfr[ni] = *reinterpret_cast<const short8v*>(Bs + (ni * 16 + ln16) * 72 + kk + lg * 8);
#pragma unroll
            for (int mi = 0; mi < 2; ++mi)
#pragma unroll
                for (int ni = 0; ni < 4; ++ni)
                    acc[mi][ni] = __builtin_amdgcn_mfma_f32_16x16x32_bf16(a[mi], bfr[ni], acc[mi][ni], 0, 0, 0);
        }
        __syncthreads();
    }
    u16* Cs = As + wave * 2304;                      // 32x72 per wave
#pragma unroll
    for (int mi = 0; mi < 2; ++mi)
#pragma unroll
        for (int ni = 0; ni < 4; ++ni)
#pragma unroll
            for (int r = 0; r < 4; ++r)
                Cs[(mi * 16 + lg * 4 + r) * 72 + ni * 16 + ln16] = f2bf(acc[mi][ni][r]);
#pragma unroll
    for (int j = 0; j < 4; ++j) {
        const int chunk = j * 64 + lane, row = chunk >> 3, co = (chunk & 7) * 8;
        const int tn = n0 + wave * 32 + row;
        *reinterpret_cast<uint4*>(X2 + ((size_t)(b * 512 + tn)) * 512 + h * 64 + co) =
            *reinterpret_cast<const uint4*>(Cs + row * 72 + co);
    }
}

// ---------------- out-proj (MFMA): X2 @ WhT + bh + query -> P f32
__global__ __launch_bounds__(256) void k_outm(
    const u16* __restrict__ X2, const u16* __restrict__ WT, const float* __restrict__ bias,
    const float* __restrict__ Xq, float* __restrict__ Pout)
{
    __shared__ __align__(16) u16 sh[18432];
    u16* As = sh; u16* Bs = sh + 9216;
    const int t = threadIdx.x, lane = t & 63, wave = t >> 6;
    const int wm = wave >> 1, wn = wave & 1;
    const int lg = lane >> 4, ln16 = lane & 15;
    const int m0 = blockIdx.x * 128, n0 = blockIdx.y * 128;
    f32x4 acc[4][4] = {};
    for (int k0 = 0; k0 < 512; k0 += 64) {
#pragma unroll
        for (int u = 0; u < 4; ++u) {
            const int chunk = u * 256 + t, row = chunk >> 3, ko = (chunk & 7) * 8;
            *reinterpret_cast<uint4*>(As + row * 72 + ko) =
                *reinterpret_cast<const uint4*>(X2 + (size_t)(m0 + row) * 512 + k0 + ko);
            *reinterpret_cast<uint4*>(Bs + row * 72 + ko) =
                *reinterpret_cast<const uint4*>(WT + (size_t)(n0 + row) * 512 + k0 + ko);
        }
        __syncthreads();
#pragma unroll
        for (int kk = 0; kk < 64; kk += 32) {
            short8v a[4], bfr[4];
#pragma unroll
            for (int mi = 0; mi < 4; ++mi)
                a[mi] = *reinterpret_cast<const short8v*>(As + (wm * 64 + mi * 16 + ln16) * 72 + kk + lg * 8);
#pragma unroll
            for (int ni = 0; ni < 4; ++ni)
                bfr[ni] = *reinterpret_cast<const short8v*>(Bs + (wn * 64 + ni * 16 + ln16) * 72 + kk + lg * 8);
#pragma unroll
            for (int mi = 0; mi < 4; ++mi)
#pragma unroll
                for (int ni = 0; ni < 4; ++ni)
                    acc[mi][ni] = __builtin_amdgcn_mfma_f32_16x16x32_bf16(a[mi], bfr[ni], acc[mi][ni], 0, 0, 0);
        }
        __syncthreads();
    }
#pragma unroll
    for (int ni = 0; ni < 4; ++ni) {
        const int cg = n0 + wn * 64 + ni * 16 + ln16;
        const float bv = bias[cg];
#pragma unroll
        for (int mi = 0; mi < 4; ++mi)
#pragma unroll
            for (int r = 0; r < 4; ++r) {
                const int tok = m0 + wm * 64 + mi * 16 + lg * 4 + r;
                Pout[(size_t)tok * 512 + cg] = acc[mi][ni][r] + bv + Xq[(size_t)tok * 512 + cg];
            }
    }
}

// ---------------- final LayerNorm over D=512
__global__ __launch_bounds__(256) void k_ln(
    const float* __restrict__ P, const float* __restrict__ g,
    const float* __restrict__ be, float* __restrict__ out)
{
    const int row = blockIdx.x * 4 + (threadIdx.x >> 6);
    const int lane = threadIdx.x & 63;
    const float* p = P + (size_t)row * 512;
    float4 v0 = reinterpret_cast<const float4*>(p)[lane];
    float4 v1 = reinterpret_cast<const float4*>(p)[64 + lane];
    float s = v0.x + v0.y + v0.z + v0.w + v1.x + v1.y + v1.z + v1.w;
#pragma unroll
    for (int o = 32; o; o >>= 1) s += __shfl_xor(s, o);
    const float mean = s * (1.0f / 512.0f);
    float d[8] = {v0.x - mean, v0.y - mean, v0.z - mean, v0.w - mean,
                  v1.x - mean, v1.y - mean, v1.z - mean, v1.w - mean};
    float s2 = 0.f;
#pragma unroll
    for (int j = 0; j < 8; ++j) s2 += d[j] * d[j];
#pragma unroll
    for (int o = 32; o; o >>= 1) s2 += __shfl_xor(s2, o);
    const float rstd = rsqrtf(s2 * (1.0f / 512.0f) + 1e-7f);
    float4 g0 = reinterpret_cast<const float4*>(g)[lane];
    float4 g1 = reinterpret_cast<const float4*>(g)[64 + lane];
    float4 b0 = reinterpret_cast<const float4*>(be)[lane];
    float4 b1 = reinterpret_cast<const float4*>(be)[64 + lane];
    float* op = out + (size_t)row * 512;
    reinterpret_cast<float4*>(op)[lane] =
        make_float4(d[0] * rstd * g0.x + b0.x, d[1] * rstd * g0.y + b0.y,
                    d[2] * rstd * g0.z + b0.z, d[3] * rstd * g0.w + b0.w);
    reinterpret_cast<float4*>(op)[64 + lane] =
        make_float4(d[4] * rstd * g1.x + b1.x, d[5] * rstd * g1.y + b1.y,
                    d[6] * rstd * g1.z + b1.z, d[7] * rstd * g1.w + b1.w);
}

extern "C" void kernel_launch(void* const* d_in, const int* in_sizes, int n_in,
                              void* d_out, int out_size, void* d_ws, size_t ws_size,
                              hipStream_t stream)
{
    const float* query = (const float*)d_in[0];
    const int*   VL    = (const int*)d_in[1];
    const float* Wq = (const float*)d_in[2];  const float* bq = (const float*)d_in[3];
    const float* Wk = (const float*)d_in[4];  const float* bk = (const float*)d_in[5];
    const float* Wv = (const float*)d_in[6];  const float* bv = (const float*)d_in[7];
    const float* Wh = (const float*)d_in[8];  const float* bh = (const float*)d_in[9];
    const float* pos_k = (const float*)d_in[10];
    const float* c1w = (const float*)d_in[11]; const float* c1b = (const float*)d_in[12];
    const float* n1g = (const float*)d_in[13]; const float* n1b = (const float*)d_in[14];
    const float* c2w = (const float*)d_in[15]; const float* c2b = (const float*)d_in[16];
    const float* lng = (const float*)d_in[17]; const float* lnb = (const float*)d_in[18];

    float* ws = (float*)d_ws;
    const size_t M1 = (size_t)1 << 20;
    // f32-unit layout (peak ~31M f32 = 124 MB):
    //  [0,8M)    S1 scores / conv2-logits bf16 (16M u16)
    //  [8M,24M)  Y1 bf16 ch-last (32M u16)
    //  [24M,25M) Xb bf16 -> later X2
    //  [25M,26M) Qb ; [26M,27M) Kb ; [27M,28M) Vt
    //  [28M,30M) QPb bf16 -> later Pout f32
    //  [30M,30.5M) WT x4 ; then pos_kb/Wf1/Wf2
    //  [31M,..)  ST
    u16* S1  = (u16*)ws;
    u16* Y1  = (u16*)(ws + 8 * M1);
    u16* Xb  = (u16*)(ws + 24 * M1);
    u16* Qb  = (u16*)(ws + 25 * M1);
    u16* Kb  = (u16*)(ws + 26 * M1);
    u16* Vt  = (u16*)(ws + 27 * M1);
    u16* QPb = (u16*)(ws + 28 * M1);
    u16* WqT = (u16*)(ws + 30 * M1);
    u16* WkT = WqT + 262144;
    u16* WvT = WkT + 262144;
    u16* WhT = WvT + 262144;
    u16* pos_kb = (u16*)(ws + 30 * M1 + 524288);
    u16* Wf1 = pos_kb + 8192;
    u16* Wf2 = Wf1 + 3584;
    float* ST  = ws + 31 * M1;
    u16* X2 = Xb;
    float* Pout = ws + 28 * M1;

    hipMemsetAsync(ST, 0, 256 * sizeof(float), stream);

    k_prept<<<dim3(8, 8, 6), 256, 0, stream>>>(Wq, Wk, Wv, Wh, WqT, WkT, WvT, WhT,
                                               c1w, c2w, pos_k, Wf1, Wf2, pos_kb,
                                               query, Xb);
    k_qkvm<<<dim3(32, 4, 3), 256, 0, stream>>>(Xb, WqT, WkT, WvT, bq, bk, bv, Qb, Kb, Vt);
    k_qposm<<<dim3(4, 64), 256, 0, stream>>>(Qb, pos_kb, QPb);
    k_scoresm<<<dim3(4, 4, 64), 256, 0, stream>>>(Qb, Kb, QPb, S1);
    k_conv1m<<<dim3(16, 16, 8), 256, 0, stream>>>(S1, Wf1, c1b, Y1, VL, ST);
    k_conv2m<<<dim3(16, 16, 8), 256, 0, stream>>>(Y1, ST, VL, n1g, n1b, Wf2, c2b, S1);
    k_softav<<<dim3(4, 64), 256, 0, stream>>>(S1, Vt, VL, X2);
    k_outm<<<dim3(32, 4), 256, 0, stream>>>(X2, WhT, bh, query, Pout);
    k_ln<<<1024, 256, 0, stream>>>(Pout, lng, lnb, (float*)d_out);
}

// Round 7
// 287.877 us; speedup vs baseline: 1.1328x; 1.0838x over previous
//
#include <hip/hip_runtime.h>

#define PC_ 60

typedef unsigned short u16;
typedef __attribute__((ext_vector_type(8))) short short8v;   // 8 bf16 (4 VGPR)
typedef __attribute__((ext_vector_type(4))) float f32x4;

__device__ inline float bf2f(u16 u) {
    union { unsigned int i; float f; } x; x.i = ((unsigned)u) << 16; return x.f;
}
__device__ inline u16 f2bf(float f) {
    union { float f; unsigned int i; } x; x.f = f;
    unsigned int r = x.i + 0x7fff + ((x.i >> 16) & 1);   // RNE
    return (u16)(r >> 16);
}
__device__ inline unsigned pk2(float a, float b) {
    return (unsigned)f2bf(a) | ((unsigned)f2bf(b) << 16);
}

// ---------------- prep: W transposes (z<4) + conv-frag/pos (z==4) + query->bf16 (z==5)
__global__ __launch_bounds__(256) void k_prept(
    const float* __restrict__ W0, const float* __restrict__ W1,
    const float* __restrict__ W2, const float* __restrict__ W3,
    u16* __restrict__ T0, u16* __restrict__ T1, u16* __restrict__ T2, u16* __restrict__ T3,
    const float* __restrict__ c1w, const float* __restrict__ c2w,
    const float* __restrict__ pos_k,
    u16* __restrict__ Wf1, u16* __restrict__ Wf2, u16* __restrict__ pos_kb,
    const float* __restrict__ X, u16* __restrict__ Xb)
{
    const int z = blockIdx.z;
    const int t = threadIdx.x;
    if (z == 5) {
        const int blk = blockIdx.y * 8 + blockIdx.x;
#pragma unroll
        for (int k2 = 0; k2 < 16; ++k2) {
            const int i = ((blk * 16 + k2) * 256 + t) * 8;
            float4 a = *reinterpret_cast<const float4*>(X + i);
            float4 b = *reinterpret_cast<const float4*>(X + i + 4);
            *reinterpret_cast<uint4*>(Xb + i) =
                make_uint4(pk2(a.x, a.y), pk2(a.z, a.w), pk2(b.x, b.y), pk2(b.z, b.w));
        }
        return;
    }
    if (z == 4) {
        if (blockIdx.x != 0 || blockIdx.y != 0) return;
        for (int s = t; s < 448; s += 256) {
            const int q = s >> 6, l = s & 63, lg = l >> 4, n = l & 15;
            const int G = q * 4 + lg;
            unsigned o[4];
#pragma unroll
            for (int u2 = 0; u2 < 4; ++u2) {
                float v0 = 0.f, v1 = 0.f;
                if (G < 25) {
                    const int dn = G / 5, dm = G - dn * 5;
                    v0 = c1w[((dn * 5 + dm) * 8 + u2 * 2 + 0) * 16 + n];
                    v1 = c1w[((dn * 5 + dm) * 8 + u2 * 2 + 1) * 16 + n];
                }
                o[u2] = pk2(v0, v1);
            }
            *reinterpret_cast<uint4*>(&Wf1[s * 8]) = make_uint4(o[0], o[1], o[2], o[3]);
        }
        for (int s = t; s < 832; s += 256) {
            const int q = s >> 6, l = s & 63, lg = l >> 4, n = l & 15;
            const int G = q * 4 + lg;
            unsigned o[4];
#pragma unroll
            for (int u2 = 0; u2 < 4; ++u2) {
                float v0 = 0.f, v1 = 0.f;
                if (G < 50 && n < 8) {
                    const int pos = G >> 1, h = G & 1;
                    const int dn = pos / 5, dm = pos - dn * 5;
                    v0 = c2w[((dn * 5 + dm) * 16 + h * 8 + u2 * 2 + 0) * 8 + n];
                    v1 = c2w[((dn * 5 + dm) * 16 + h * 8 + u2 * 2 + 1) * 8 + n];
                }
                o[u2] = pk2(v0, v1);
            }
            *reinterpret_cast<uint4*>(&Wf2[s * 8]) = make_uint4(o[0], o[1], o[2], o[3]);
        }
        for (int s = t; s < 128 * 64; s += 256) {
            const int r = s >> 6;
            pos_kb[s] = (r < 121) ? f2bf(pos_k[s]) : (u16)0;
        }
        return;
    }
    const float* W = (z == 0) ? W0 : (z == 1) ? W1 : (z == 2) ? W2 : W3;
    u16* T        = (z == 0) ? T0 : (z == 1) ? T1 : (z == 2) ? T2 : T3;
    __shared__ float ls[64 * 65];
    const int k0 = blockIdx.x * 64, n0 = blockIdx.y * 64;
#pragma unroll
    for (int i = 0; i < 16; ++i) {
        const int idx = t + i * 256, r = idx >> 6, c = idx & 63;
        ls[c * 65 + r] = W[(size_t)(k0 + r) * 512 + n0 + c];
    }
    __syncthreads();
#pragma unroll
    for (int i = 0; i < 16; ++i) {
        const int idx = t + i * 256, r = idx >> 6, c = idx & 63;
        T[(size_t)(n0 + r) * 512 + k0 + c] = f2bf(ls[r * 65 + c]);
    }
}

// ---------------- QKV (MFMA): Xb @ WT -> Q/K bf16 (B,H,N,DH), V^T bf16 (B,H,DH,N)
__global__ __launch_bounds__(256) void k_qkvm(
    const u16* __restrict__ Xb,
    const u16* __restrict__ WT0, const u16* __restrict__ WT1, const u16* __restrict__ WT2,
    const float* __restrict__ b0, const float* __restrict__ b1, const float* __restrict__ b2,
    u16* __restrict__ Qb, u16* __restrict__ Kb, u16* __restrict__ Vt)
{
    const int z = blockIdx.z;
    const u16* WT    = (z == 0) ? WT0 : (z == 1) ? WT1 : WT2;
    const float* bias = (z == 0) ? b0 : (z == 1) ? b1 : b2;
    __shared__ __align__(16) u16 sh[18432];          // As 128x72, Bs 128x72
    u16* As = sh; u16* Bs = sh + 9216;
    const int t = threadIdx.x, lane = t & 63, wave = t >> 6;
    const int wm = wave >> 1, wn = wave & 1;
    const int lg = lane >> 4, ln16 = lane & 15;
    const int m0 = blockIdx.x * 128, n0 = blockIdx.y * 128;
    f32x4 acc[4][4] = {};
    for (int k0 = 0; k0 < 512; k0 += 64) {
#pragma unroll
        for (int u = 0; u < 4; ++u) {
            const int chunk = u * 256 + t, row = chunk >> 3, ko = (chunk & 7) * 8;
            *reinterpret_cast<uint4*>(As + row * 72 + ko) =
                *reinterpret_cast<const uint4*>(Xb + (size_t)(m0 + row) * 512 + k0 + ko);
            *reinterpret_cast<uint4*>(Bs + row * 72 + ko) =
                *reinterpret_cast<const uint4*>(WT + (size_t)(n0 + row) * 512 + k0 + ko);
        }
        __syncthreads();
#pragma unroll
        for (int kk = 0; kk < 64; kk += 32) {
            short8v a[4], bfr[4];
#pragma unroll
            for (int mi = 0; mi < 4; ++mi)
                a[mi] = *reinterpret_cast<const short8v*>(As + (wm * 64 + mi * 16 + ln16) * 72 + kk + lg * 8);
#pragma unroll
            for (int ni = 0; ni < 4; ++ni)
                bfr[ni] = *reinterpret_cast<const short8v*>(Bs + (wn * 64 + ni * 16 + ln16) * 72 + kk + lg * 8);
#pragma unroll
            for (int mi = 0; mi < 4; ++mi)
#pragma unroll
                for (int ni = 0; ni < 4; ++ni)
                    acc[mi][ni] = __builtin_amdgcn_mfma_f32_16x16x32_bf16(a[mi], bfr[ni], acc[mi][ni], 0, 0, 0);
        }
        __syncthreads();
    }
    u16* Cs = sh + wave * 4608;                       // 64x72 per wave
#pragma unroll
    for (int ni = 0; ni < 4; ++ni) {
        const float bv = bias[n0 + wn * 64 + ni * 16 + ln16];
#pragma unroll
        for (int mi = 0; mi < 4; ++mi)
#pragma unroll
            for (int r = 0; r < 4; ++r)
                Cs[(mi * 16 + lg * 4 + r) * 72 + ni * 16 + ln16] = f2bf(acc[mi][ni][r] + bv);
    }
    if (z < 2) {
        u16* O = (z == 0) ? Qb : Kb;
#pragma unroll
        for (int j = 0; j < 8; ++j) {
            const int chunk = j * 64 + lane, row = chunk >> 3, co = (chunk & 7) * 8;
            const int tok = m0 + wm * 64 + row;
            const int b = tok >> 9, n = tok & 511;
            const int cg = n0 + wn * 64 + co;
            const int h = cg >> 6, dh = cg & 63;
            *reinterpret_cast<uint4*>(O + ((size_t)((b * 8 + h) * 512 + n)) * 64 + dh) =
                *reinterpret_cast<const uint4*>(Cs + row * 72 + co);
        }
    } else {
#pragma unroll
        for (int j = 0; j < 8; ++j) {
            const int chunk = j * 64 + lane, dr = chunk >> 3, no8 = (chunk & 7) * 8;
            const int cg = n0 + wn * 64 + dr;
            const int h = cg >> 6, dh = cg & 63;
            const int tok = m0 + wm * 64 + no8;
            const int b = tok >> 9, n = tok & 511;
            u16 v[8];
#pragma unroll
            for (int e = 0; e < 8; ++e) v[e] = Cs[(no8 + e) * 72 + dr];
            uint4 o = make_uint4((unsigned)v[0] | ((unsigned)v[1] << 16),
                                 (unsigned)v[2] | ((unsigned)v[3] << 16),
                                 (unsigned)v[4] | ((unsigned)v[5] << 16),
                                 (unsigned)v[6] | ((unsigned)v[7] << 16));
            *reinterpret_cast<uint4*>(Vt + ((size_t)((b * 8 + h) * 64 + dh)) * 512 + n) = o;
        }
    }
}

// ---------------- qp (MFMA): Q(bh,n,64) @ pos_k^T -> QP bf16 (bh,n,128pad)
__global__ __launch_bounds__(256) void k_qposm(
    const u16* __restrict__ Qb, const u16* __restrict__ pos_kb, u16* __restrict__ QP)
{
    __shared__ __align__(16) u16 sh[18432];
    u16* As = sh; u16* Bs = sh + 9216;
    const int t = threadIdx.x, lane = t & 63, wave = t >> 6;
    const int lg = lane >> 4, ln16 = lane & 15;
    const int n0 = blockIdx.x * 128, bh = blockIdx.y;
#pragma unroll
    for (int u = 0; u < 4; ++u) {
        const int chunk = u * 256 + t, row = chunk >> 3, ko = (chunk & 7) * 8;
        *reinterpret_cast<uint4*>(As + row * 72 + ko) =
            *reinterpret_cast<const uint4*>(Qb + ((size_t)(bh * 512 + n0 + row)) * 64 + ko);
        *reinterpret_cast<uint4*>(Bs + row * 72 + ko) =
            *reinterpret_cast<const uint4*>(pos_kb + (size_t)row * 64 + ko);
    }
    __syncthreads();
    f32x4 acc[2][8] = {};
#pragma unroll
    for (int kk = 0; kk < 64; kk += 32) {
        short8v a[2], bfr[8];
#pragma unroll
        for (int mi = 0; mi < 2; ++mi)
            a[mi] = *reinterpret_cast<const short8v*>(As + (wave * 32 + mi * 16 + ln16) * 72 + kk + lg * 8);
#pragma unroll
        for (int ni = 0; ni < 8; ++ni)
            bfr[ni] = *reinterpret_cast<const short8v*>(Bs + (ni * 16 + ln16) * 72 + kk + lg * 8);
#pragma unroll
        for (int mi = 0; mi < 2; ++mi)
#pragma unroll
            for (int ni = 0; ni < 8; ++ni)
                acc[mi][ni] = __builtin_amdgcn_mfma_f32_16x16x32_bf16(a[mi], bfr[ni], acc[mi][ni], 0, 0, 0);
    }
    __syncthreads();
    u16* Cs = sh + wave * 4352;                      // 32x136 per wave
#pragma unroll
    for (int mi = 0; mi < 2; ++mi)
#pragma unroll
        for (int ni = 0; ni < 8; ++ni)
#pragma unroll
            for (int r = 0; r < 4; ++r)
                Cs[(mi * 16 + lg * 4 + r) * 136 + ni * 16 + ln16] = f2bf(acc[mi][ni][r]);
#pragma unroll
    for (int j = 0; j < 8; ++j) {
        const int chunk = j * 64 + lane, row = chunk >> 4, co = (chunk & 15) * 8;
        *reinterpret_cast<uint4*>(QP + ((size_t)(bh * 512 + n0 + wave * 32 + row)) * 128 + co) =
            *reinterpret_cast<const uint4*>(Cs + row * 136 + co);
    }
}

// ---------------- scores (MFMA): (Q@K^T + QP[rel]) / 8 -> S bf16 (bh,n,m)
__global__ __launch_bounds__(256) void k_scoresm(
    const u16* __restrict__ Qb, const u16* __restrict__ Kb, const u16* __restrict__ QP,
    u16* __restrict__ S)
{
    __shared__ __align__(16) u16 sh[18432];
    u16* As = sh; u16* Bs = sh + 9216;
    const int t = threadIdx.x, lane = t & 63, wave = t >> 6;
    const int wm = wave >> 1, wn = wave & 1;
    const int lg = lane >> 4, ln16 = lane & 15;
    const int m0 = blockIdx.x * 128, n0 = blockIdx.y * 128, bh = blockIdx.z;
#pragma unroll
    for (int u = 0; u < 4; ++u) {
        const int chunk = u * 256 + t, row = chunk >> 3, ko = (chunk & 7) * 8;
        *reinterpret_cast<uint4*>(As + row * 72 + ko) =
            *reinterpret_cast<const uint4*>(Qb + ((size_t)(bh * 512 + n0 + row)) * 64 + ko);
        *reinterpret_cast<uint4*>(Bs + row * 72 + ko) =
            *reinterpret_cast<const uint4*>(Kb + ((size_t)(bh * 512 + m0 + row)) * 64 + ko);
    }
    __syncthreads();
    f32x4 acc[4][4] = {};
#pragma unroll
    for (int kk = 0; kk < 64; kk += 32) {
        short8v a[4], bfr[4];
#pragma unroll
        for (int mi = 0; mi < 4; ++mi)
            a[mi] = *reinterpret_cast<const short8v*>(As + (wm * 64 + mi * 16 + ln16) * 72 + kk + lg * 8);
#pragma unroll
        for (int ni = 0; ni < 4; ++ni)
            bfr[ni] = *reinterpret_cast<const short8v*>(Bs + (wn * 64 + ni * 16 + ln16) * 72 + kk + lg * 8);
#pragma unroll
        for (int mi = 0; mi < 4; ++mi)
#pragma unroll
            for (int ni = 0; ni < 4; ++ni)
                acc[mi][ni] = __builtin_amdgcn_mfma_f32_16x16x32_bf16(a[mi], bfr[ni], acc[mi][ni], 0, 0, 0);
    }
    __syncthreads();
    u16* QPs = sh;                                   // 128x128 bf16
#pragma unroll
    for (int u = 0; u < 8; ++u) {
        const int chunk = u * 256 + t, row = chunk >> 4, co = (chunk & 15) * 8;
        *reinterpret_cast<uint4*>(QPs + row * 128 + co) =
            *reinterpret_cast<const uint4*>(QP + ((size_t)(bh * 512 + n0 + row)) * 128 + co);
    }
    __syncthreads();
#pragma unroll
    for (int mi = 0; mi < 4; ++mi)
#pragma unroll
        for (int ni = 0; ni < 4; ++ni) {
            const int m_g = m0 + wn * 64 + ni * 16 + ln16;
#pragma unroll
            for (int r = 0; r < 4; ++r) {
                const int n_loc = wm * 64 + mi * 16 + lg * 4 + r;
                const int n_g = n0 + n_loc;
                int rel = m_g - n_g;
                rel = rel < -PC_ ? -PC_ : (rel > PC_ ? PC_ : rel);
                const float v = (acc[mi][ni][r] + bf2f(QPs[n_loc * 128 + rel + PC_])) * 0.125f;
                S[(size_t)bh * 262144 + (size_t)n_g * 512 + m_g] = f2bf(v);
            }
        }
}

// ---------------- conv1 (MFMA, swapped operands): S bf16 planar -> Y ch-last + fused stats
__global__ __launch_bounds__(256) void k_conv1m(
    const u16* __restrict__ S, const u16* __restrict__ Wf,
    const float* __restrict__ bias, u16* __restrict__ Y,
    const int* __restrict__ VL, float* __restrict__ ST)
{
    __shared__ __align__(16) u16 xs[10368];
    __shared__ float wred[4][4][8];     // [wave][lg][s:0..3, s2:4..7]
    const int t = threadIdx.x;
    const int b = blockIdx.z;
    const int n0 = blockIdx.y * 32;
    const int m0 = blockIdx.x * 32;
    const u16* sp0 = S + (size_t)(b * 8) * 262144;
    // paired-pixel staging: 648 pairs; width 36 even + m0 even => pair shares validity/alignment
    for (int p = t; p < 648; p += 256) {
        const int idx2 = p * 2;
        const int r = idx2 / 36, c = idx2 - r * 36;
        const int gn = n0 - 2 + r, gm = m0 - 2 + c;
        uint4 o0 = make_uint4(0, 0, 0, 0), o1 = o0;
        if ((unsigned)gn < 512u && (unsigned)gm < 512u) {
            const u16* pp = sp0 + (size_t)gn * 512 + gm;
            unsigned u[8];
#pragma unroll
            for (int e = 0; e < 8; ++e)
                u[e] = *reinterpret_cast<const unsigned*>(pp + (size_t)e * 262144);
            o0 = make_uint4((u[0] & 0xffffu) | ((u[1] & 0xffffu) << 16),
                            (u[2] & 0xffffu) | ((u[3] & 0xffffu) << 16),
                            (u[4] & 0xffffu) | ((u[5] & 0xffffu) << 16),
                            (u[6] & 0xffffu) | ((u[7] & 0xffffu) << 16));
            o1 = make_uint4((u[0] >> 16) | (u[1] & 0xffff0000u),
                            (u[2] >> 16) | (u[3] & 0xffff0000u),
                            (u[4] >> 16) | (u[5] & 0xffff0000u),
                            (u[6] >> 16) | (u[7] & 0xffff0000u));
        }
        *reinterpret_cast<uint4*>(&xs[idx2 * 8]) = o0;
        *reinterpret_cast<uint4*>(&xs[(idx2 + 1) * 8]) = o1;
    }
    const int lane = t & 63, wave = t >> 6;
    const int lg = lane >> 4, ln16 = lane & 15;
    short8v bq[7];
#pragma unroll
    for (int q = 0; q < 7; ++q)
        bq[q] = *reinterpret_cast<const short8v*>(&Wf[(q * 64 + lane) * 8]);
    int aoff[7];
#pragma unroll
    for (int q = 0; q < 7; ++q) {
        const int G = q * 4 + lg; const int p = (G < 25) ? G : 0;
        const int dn = p / 5, dm = p - dn * 5;
        aoff[q] = (dn * 36 + dm) * 8;
    }
    const float4 b4 = *reinterpret_cast<const float4*>(&bias[lg * 4]);   // channels lg*4..+3
    const int vl = VL[b];
    f32x4 sstv = {0.f, 0.f, 0.f, 0.f}, sst2v = {0.f, 0.f, 0.f, 0.f};
    __syncthreads();
    for (int i = 0; i < 16; ++i) {
        const int j = wave * 16 + i;
        const int tr = j >> 1, c0 = (j & 1) << 4;
        const int pb = (tr * 36 + c0 + ln16) * 8;
        f32x4 acc = {b4.x, b4.y, b4.z, b4.w};
#pragma unroll
        for (int q = 0; q < 7; ++q) {
            short8v a = *reinterpret_cast<const short8v*>(&xs[pb + aoff[q]]);
            // swapped: A=weights(channels as M), B=pixels(as N) -> lane=pixel, regs=4 channels
            acc = __builtin_amdgcn_mfma_f32_16x16x32_bf16(bq[q], a, acc, 0, 0, 0);
        }
        // lane = pixel (c0+ln16), regs = channels lg*4+r -> coalesced uint2 store (512B/wave)
        u16* yb = Y + (((size_t)(b * 512 + n0 + tr)) * 512 + (m0 + c0 + ln16)) * 16 + lg * 4;
        *reinterpret_cast<uint2*>(yb) = make_uint2(pk2(acc[0], acc[1]), pk2(acc[2], acc[3]));
        if (n0 + tr < vl) {
            sstv += acc;
            sst2v += acc * acc;
        }
    }
#pragma unroll
    for (int o = 1; o < 16; o <<= 1) {
#pragma unroll
        for (int r = 0; r < 4; ++r) {
            sstv[r]  += __shfl_xor(sstv[r], o);
            sst2v[r] += __shfl_xor(sst2v[r], o);
        }
    }
    if (ln16 == 0) {
#pragma unroll
        for (int r = 0; r < 4; ++r) {
            wred[wave][lg][r]     = sstv[r];
            wred[wave][lg][4 + r] = sst2v[r];
        }
    }
    __syncthreads();
    if (t < 16) {
        const int lgg = t >> 2, r = t & 3;
        const float a  = wred[0][lgg][r] + wred[1][lgg][r] + wred[2][lgg][r] + wred[3][lgg][r];
        const float b2 = wred[0][lgg][4 + r] + wred[1][lgg][4 + r] + wred[2][lgg][4 + r] + wred[3][lgg][4 + r];
        atomicAdd(&ST[(b * 16 + t) * 2 + 0], a);
        atomicAdd(&ST[(b * 16 + t) * 2 + 1], b2);
    }
}

// ---------------- conv2 (MFMA): Y ch-last bf16, statfin + norm+relu fused -> S2 bf16 planar
__global__ __launch_bounds__(256) void k_conv2m(
    const u16* __restrict__ Y, const float* __restrict__ ST,
    const int* __restrict__ VL, const float* __restrict__ n1g, const float* __restrict__ n1b,
    const u16* __restrict__ Wf, const float* __restrict__ bias,
    u16* __restrict__ S2)
{
    __shared__ __align__(16) u16 xs[20736];
    __shared__ float ssh[16][2];
    const int t = threadIdx.x;
    const int b = blockIdx.z;
    const int n0 = blockIdx.y * 32, m0 = blockIdx.x * 32;
    if (t < 16) {                       // folded statfin (redundant per block, trivial)
        const float sw = (float)VL[b] * 512.f;
        const float mean = ST[(b * 16 + t) * 2 + 0] / sw;
        const float var  = ST[(b * 16 + t) * 2 + 1] / sw - mean * mean;
        const float sc = n1g[t] * rsqrtf(var + 1e-7f);
        ssh[t][0] = sc;
        ssh[t][1] = n1b[t] - mean * sc;
    }
    __syncthreads();
    float sc[16], shv[16];
#pragma unroll
    for (int ch = 0; ch < 16; ++ch) { sc[ch] = ssh[ch][0]; shv[ch] = ssh[ch][1]; }
    for (int idx = t; idx < 1296; idx += 256) {
        const int r = idx / 36; const int c = idx - r * 36;
        const int gn = n0 - 2 + r, gm = m0 - 2 + c;
        uint4 p0 = make_uint4(0, 0, 0, 0), p1 = p0;
        if ((unsigned)gn < 512u && (unsigned)gm < 512u) {
            const u16* yp = Y + (((size_t)(b * 512 + gn)) * 512 + gm) * 16;
            const uint4 r0 = *reinterpret_cast<const uint4*>(yp);
            const uint4 r1 = *reinterpret_cast<const uint4*>(yp + 8);
            const unsigned w0[4] = {r0.x, r0.y, r0.z, r0.w};
            const unsigned w1[4] = {r1.x, r1.y, r1.z, r1.w};
            unsigned o0[4], o1[4];
#pragma unroll
            for (int u2 = 0; u2 < 4; ++u2) {
                const int ch = u2 * 2;
                float a0 = bf2f((u16)(w0[u2] & 0xffff));
                float a1 = bf2f((u16)(w0[u2] >> 16));
                a0 = fmaf(a0, sc[ch], shv[ch]);          a0 = a0 > 0.f ? a0 : 0.f;
                a1 = fmaf(a1, sc[ch + 1], shv[ch + 1]);  a1 = a1 > 0.f ? a1 : 0.f;
                o0[u2] = pk2(a0, a1);
                const int ch2 = 8 + u2 * 2;
                float b0 = bf2f((u16)(w1[u2] & 0xffff));
                float b1 = bf2f((u16)(w1[u2] >> 16));
                b0 = fmaf(b0, sc[ch2], shv[ch2]);          b0 = b0 > 0.f ? b0 : 0.f;
                b1 = fmaf(b1, sc[ch2 + 1], shv[ch2 + 1]);  b1 = b1 > 0.f ? b1 : 0.f;
                o1[u2] = pk2(b0, b1);
            }
            p0 = make_uint4(o0[0], o0[1], o0[2], o0[3]);
            p1 = make_uint4(o1[0], o1[1], o1[2], o1[3]);
        }
        *reinterpret_cast<uint4*>(&xs[idx * 8]) = p0;
        *reinterpret_cast<uint4*>(&xs[10368 + idx * 8]) = p1;
    }
    const int lane = t & 63, wave = t >> 6;
    const int lg = lane >> 4, ln16 = lane & 15;
    short8v bq[13];
#pragma unroll
    for (int q = 0; q < 13; ++q)
        bq[q] = *reinterpret_cast<const short8v*>(&Wf[(q * 64 + lane) * 8]);
    int aoff[13];
#pragma unroll
    for (int q = 0; q < 13; ++q) {
        const int G = q * 4 + lg; const int p = (G < 50) ? G : 0;
        const int pos = p >> 1, h = p & 1;
        const int dn = pos / 5, dm = pos - dn * 5;
        aoff[q] = h * 10368 + (dn * 36 + dm) * 8;
    }
    const float bs = (ln16 < 8) ? bias[ln16] : 0.f;
    __syncthreads();
    for (int i = 0; i < 16; ++i) {
        const int j = wave * 16 + i;
        const int tr = j >> 1, c0 = (j & 1) << 4;
        const int pb = (tr * 36 + c0 + ln16) * 8;
        f32x4 acc = {bs, bs, bs, bs};
#pragma unroll
        for (int q = 0; q < 13; ++q) {
            short8v a = *reinterpret_cast<const short8v*>(&xs[pb + aoff[q]]);
            acc = __builtin_amdgcn_mfma_f32_16x16x32_bf16(a, bq[q], acc, 0, 0, 0);
        }
        if (ln16 < 8) {
            uint2 o = make_uint2(pk2(acc[0], acc[1]), pk2(acc[2], acc[3]));
            *reinterpret_cast<uint2*>(
                &S2[(((size_t)(b * 8 + ln16)) * 512 + n0 + tr) * 512 + m0 + c0 + lg * 4]) = o;
        }
    }
}

// ---------------- fused masked softmax + A@V (64-row tile): logits bf16 -> X2(B,N,512) bf16
__global__ __launch_bounds__(256) void k_softav(
    const u16* __restrict__ SL, const u16* __restrict__ Vt,
    const int* __restrict__ VL, u16* __restrict__ X2)
{
    __shared__ __align__(16) u16 As[4608];   // 64x72
    __shared__ __align__(16) u16 Bs[4608];   // 64x72
    __shared__ float smx[64], siv[64];
    const int t = threadIdx.x, lane = t & 63, wave = t >> 6;
    const int lg = lane >> 4, ln16 = lane & 15;
    const int n0 = blockIdx.x * 64, bh = blockIdx.y;
    const int b = bh >> 3, h = bh & 7;
    const int vl = VL[b];
    const u16* Sp = SL + (size_t)bh * 262144;
    for (int rr = 0; rr < 16; ++rr) {
        const int row = wave * 16 + rr;
        uint4 v = *reinterpret_cast<const uint4*>(Sp + (size_t)(n0 + row) * 512 + lane * 8);
        const unsigned w[4] = {v.x, v.y, v.z, v.w};
        float x[8];
#pragma unroll
        for (int j = 0; j < 4; ++j) {
            x[2 * j]     = bf2f((u16)(w[j] & 0xffff));
            x[2 * j + 1] = bf2f((u16)(w[j] >> 16));
        }
        const int mb = lane * 8;
        float mx = -3.0e38f;
#pragma unroll
        for (int j = 0; j < 8; ++j) {
            if (mb + j >= vl) x[j] = -3.0e38f;
            mx = fmaxf(mx, x[j]);
        }
#pragma unroll
        for (int o = 32; o; o >>= 1) mx = fmaxf(mx, __shfl_xor(mx, o));
        float sm = 0.f;
#pragma unroll
        for (int j = 0; j < 8; ++j) sm += __expf(x[j] - mx);
#pragma unroll
        for (int o = 32; o; o >>= 1) sm += __shfl_xor(sm, o);
        if (lane == 0) { smx[row] = mx; siv[row] = 1.0f / sm; }
    }
    __syncthreads();
    f32x4 acc[4] = {};
    for (int k0 = 0; k0 < 512; k0 += 64) {
#pragma unroll
        for (int u = 0; u < 2; ++u) {
            const int chunk = u * 256 + t, row = chunk >> 3, ko = (chunk & 7) * 8;
            uint4 raw = *reinterpret_cast<const uint4*>(Sp + (size_t)(n0 + row) * 512 + k0 + ko);
            const unsigned w[4] = {raw.x, raw.y, raw.z, raw.w};
            const float mxr = smx[row], ivr = siv[row];
            unsigned o[4];
#pragma unroll
            for (int jj = 0; jj < 4; ++jj) {
                const int m0i = k0 + ko + 2 * jj;
                float a0 = (m0i     < vl) ? __expf(bf2f((u16)(w[jj] & 0xffff)) - mxr) * ivr : 0.f;
                float a1 = (m0i + 1 < vl) ? __expf(bf2f((u16)(w[jj] >> 16))   - mxr) * ivr : 0.f;
                o[jj] = pk2(a0, a1);
            }
            *reinterpret_cast<uint4*>(As + row * 72 + ko) = make_uint4(o[0], o[1], o[2], o[3]);
            *reinterpret_cast<uint4*>(Bs + row * 72 + ko) =
                *reinterpret_cast<const uint4*>(Vt + ((size_t)(bh * 64 + row)) * 512 + k0 + ko);
        }
        __syncthreads();
#pragma unroll
        for (int kk = 0; kk < 64; kk += 32) {
            short8v a = *reinterpret_cast<const short8v*>(As + (wave * 16 + ln16) * 72 + kk + lg * 8);
#pragma unroll
            for (int ni = 0; ni < 4; ++ni) {
                short8v bfr = *reinterpret_cast<const short8v*>(Bs + (ni * 16 + ln16) * 72 + kk + lg * 8);
                acc[ni] = __builtin_amdgcn_mfma_f32_16x16x32_bf16(a, bfr, acc[ni], 0, 0, 0);
            }
        }
        __syncthreads();
    }
    u16* Cs = As + wave * 1152;                      // 16x72 per wave
#pragma unroll
    for (int ni = 0; ni < 4; ++ni)
#pragma unroll
        for (int r = 0; r < 4; ++r)
            Cs[(lg * 4 + r) * 72 + ni * 16 + ln16] = f2bf(acc[ni][r]);
#pragma unroll
    for (int j = 0; j < 2; ++j) {
        const int chunk = j * 64 + lane, row = chunk >> 3, co = (chunk & 7) * 8;
        const int tn = n0 + wave * 16 + row;
        *reinterpret_cast<uint4*>(X2 + ((size_t)(b * 512 + tn)) * 512 + h * 64 + co) =
            *reinterpret_cast<const uint4*>(Cs + row * 72 + co);
    }
}

// ---------------- out-proj (MFMA): X2 @ WhT + bh + query -> P f32
__global__ __launch_bounds__(256) void k_outm(
    const u16* __restrict__ X2, const u16* __restrict__ WT, const float* __restrict__ bias,
    const float* __restrict__ Xq, float* __restrict__ Pout)
{
    __shared__ __align__(16) u16 sh[18432];
    u16* As = sh; u16* Bs = sh + 9216;
    const int t = threadIdx.x, lane = t & 63, wave = t >> 6;
    const int wm = wave >> 1, wn = wave & 1;
    const int lg = lane >> 4, ln16 = lane & 15;
    const int m0 = blockIdx.x * 128, n0 = blockIdx.y * 128;
    f32x4 acc[4][4] = {};
    for (int k0 = 0; k0 < 512; k0 += 64) {
#pragma unroll
        for (int u = 0; u < 4; ++u) {
            const int chunk = u * 256 + t, row = chunk >> 3, ko = (chunk & 7) * 8;
            *reinterpret_cast<uint4*>(As + row * 72 + ko) =
                *reinterpret_cast<const uint4*>(X2 + (size_t)(m0 + row) * 512 + k0 + ko);
            *reinterpret_cast<uint4*>(Bs + row * 72 + ko) =
                *reinterpret_cast<const uint4*>(WT + (size_t)(n0 + row) * 512 + k0 + ko);
        }
        __syncthreads();
#pragma unroll
        for (int kk = 0; kk < 64; kk += 32) {
            short8v a[4], bfr[4];
#pragma unroll
            for (int mi = 0; mi < 4; ++mi)
                a[mi] = *reinterpret_cast<const short8v*>(As + (wm * 64 + mi * 16 + ln16) * 72 + kk + lg * 8);
#pragma unroll
            for (int ni = 0; ni < 4; ++ni)
                bfr[ni] = *reinterpret_cast<const short8v*>(Bs + (wn * 64 + ni * 16 + ln16) * 72 + kk + lg * 8);
#pragma unroll
            for (int mi = 0; mi < 4; ++mi)
#pragma unroll
                for (int ni = 0; ni < 4; ++ni)
                    acc[mi][ni] = __builtin_amdgcn_mfma_f32_16x16x32_bf16(a[mi], bfr[ni], acc[mi][ni], 0, 0, 0);
        }
        __syncthreads();
    }
#pragma unroll
    for (int ni = 0; ni < 4; ++ni) {
        const int cg = n0 + wn * 64 + ni * 16 + ln16;
        const float bv = bias[cg];
#pragma unroll
        for (int mi = 0; mi < 4; ++mi)
#pragma unroll
            for (int r = 0; r < 4; ++r) {
                const int tok = m0 + wm * 64 + mi * 16 + lg * 4 + r;
                Pout[(size_t)tok * 512 + cg] = acc[mi][ni][r] + bv + Xq[(size_t)tok * 512 + cg];
            }
    }
}

// ---------------- final LayerNorm over D=512
__global__ __launch_bounds__(256) void k_ln(
    const float* __restrict__ P, const float* __restrict__ g,
    const float* __restrict__ be, float* __restrict__ out)
{
    const int row = blockIdx.x * 4 + (threadIdx.x >> 6);
    const int lane = threadIdx.x & 63;
    const float* p = P + (size_t)row * 512;
    float4 v0 = reinterpret_cast<const float4*>(p)[lane];
    float4 v1 = reinterpret_cast<const float4*>(p)[64 + lane];
    float s = v0.x + v0.y + v0.z + v0.w + v1.x + v1.y + v1.z + v1.w;
#pragma unroll
    for (int o = 32; o; o >>= 1) s += __shfl_xor(s, o);
    const float mean = s * (1.0f / 512.0f);
    float d[8] = {v0.x - mean, v0.y - mean, v0.z - mean, v0.w - mean,
                  v1.x - mean, v1.y - mean, v1.z - mean, v1.w - mean};
    float s2 = 0.f;
#pragma unroll
    for (int j = 0; j < 8; ++j) s2 += d[j] * d[j];
#pragma unroll
    for (int o = 32; o; o >>= 1) s2 += __shfl_xor(s2, o);
    const float rstd = rsqrtf(s2 * (1.0f / 512.0f) + 1e-7f);
    float4 g0 = reinterpret_cast<const float4*>(g)[lane];
    float4 g1 = reinterpret_cast<const float4*>(g)[64 + lane];
    float4 b0 = reinterpret_cast<const float4*>(be)[lane];
    float4 b1 = reinterpret_cast<const float4*>(be)[64 + lane];
    float* op = out + (size_t)row * 512;
    reinterpret_cast<float4*>(op)[lane] =
        make_float4(d[0] * rstd * g0.x + b0.x, d[1] * rstd * g0.y + b0.y,
                    d[2] * rstd * g0.z + b0.z, d[3] * rstd * g0.w + b0.w);
    reinterpret_cast<float4*>(op)[64 + lane] =
        make_float4(d[4] * rstd * g1.x + b1.x, d[5] * rstd * g1.y + b1.y,
                    d[6] * rstd * g1.z + b1.z, d[7] * rstd * g1.w + b1.w);
}

extern "C" void kernel_launch(void* const* d_in, const int* in_sizes, int n_in,
                              void* d_out, int out_size, void* d_ws, size_t ws_size,
                              hipStream_t stream)
{
    const float* query = (const float*)d_in[0];
    const int*   VL    = (const int*)d_in[1];
    const float* Wq = (const float*)d_in[2];  const float* bq = (const float*)d_in[3];
    const float* Wk = (const float*)d_in[4];  const float* bk = (const float*)d_in[5];
    const float* Wv = (const float*)d_in[6];  const float* bv = (const float*)d_in[7];
    const float* Wh = (const float*)d_in[8];  const float* bh = (const float*)d_in[9];
    const float* pos_k = (const float*)d_in[10];
    const float* c1w = (const float*)d_in[11]; const float* c1b = (const float*)d_in[12];
    const float* n1g = (const float*)d_in[13]; const float* n1b = (const float*)d_in[14];
    const float* c2w = (const float*)d_in[15]; const float* c2b = (const float*)d_in[16];
    const float* lng = (const float*)d_in[17]; const float* lnb = (const float*)d_in[18];

    float* ws = (float*)d_ws;
    const size_t M1 = (size_t)1 << 20;
    u16* S1  = (u16*)ws;
    u16* Y1  = (u16*)(ws + 8 * M1);
    u16* Xb  = (u16*)(ws + 24 * M1);
    u16* Qb  = (u16*)(ws + 25 * M1);
    u16* Kb  = (u16*)(ws + 26 * M1);
    u16* Vt  = (u16*)(ws + 27 * M1);
    u16* QPb = (u16*)(ws + 28 * M1);
    u16* WqT = (u16*)(ws + 30 * M1);
    u16* WkT = WqT + 262144;
    u16* WvT = WkT + 262144;
    u16* WhT = WvT + 262144;
    u16* pos_kb = (u16*)(ws + 30 * M1 + 524288);
    u16* Wf1 = pos_kb + 8192;
    u16* Wf2 = Wf1 + 3584;
    float* ST  = ws + 31 * M1;
    u16* X2 = Xb;
    float* Pout = ws + 28 * M1;

    hipMemsetAsync(ST, 0, 256 * sizeof(float), stream);

    k_prept<<<dim3(8, 8, 6), 256, 0, stream>>>(Wq, Wk, Wv, Wh, WqT, WkT, WvT, WhT,
                                               c1w, c2w, pos_k, Wf1, Wf2, pos_kb,
                                               query, Xb);
    k_qkvm<<<dim3(32, 4, 3), 256, 0, stream>>>(Xb, WqT, WkT, WvT, bq, bk, bv, Qb, Kb, Vt);
    k_qposm<<<dim3(4, 64), 256, 0, stream>>>(Qb, pos_kb, QPb);
    k_scoresm<<<dim3(4, 4, 64), 256, 0, stream>>>(Qb, Kb, QPb, S1);
    k_conv1m<<<dim3(16, 16, 8), 256, 0, stream>>>(S1, Wf1, c1b, Y1, VL, ST);
    k_conv2m<<<dim3(16, 16, 8), 256, 0, stream>>>(Y1, ST, VL, n1g, n1b, Wf2, c2b, S1);
    k_softav<<<dim3(8, 64), 256, 0, stream>>>(S1, Vt, VL, X2);
    k_outm<<<dim3(32, 4), 256, 0, stream>>>(X2, WhT, bh, query, Pout);
    k_ln<<<1024, 256, 0, stream>>>(Pout, lng, lnb, (float*)d_out);
}

// Round 8
// 256.336 us; speedup vs baseline: 1.2721x; 1.1230x over previous
//
#include <hip/hip_runtime.h>

#define PC_ 60

typedef unsigned short u16;
typedef __attribute__((ext_vector_type(8))) short short8v;   // 8 bf16 (4 VGPR)
typedef __attribute__((ext_vector_type(4))) float f32x4;

__device__ inline float bf2f(u16 u) {
    union { unsigned int i; float f; } x; x.i = ((unsigned)u) << 16; return x.f;
}
__device__ inline u16 f2bf(float f) {
    union { float f; unsigned int i; } x; x.f = f;
    unsigned int r = x.i + 0x7fff + ((x.i >> 16) & 1);   // RNE
    return (u16)(r >> 16);
}
__device__ inline unsigned pk2(float a, float b) {
    return (unsigned)f2bf(a) | ((unsigned)f2bf(b) << 16);
}

// ---------------- prep: W transposes (z<4) + conv-frag/pos (z==4) + query->bf16 (z==5)
__global__ __launch_bounds__(256) void k_prept(
    const float* __restrict__ W0, const float* __restrict__ W1,
    const float* __restrict__ W2, const float* __restrict__ W3,
    u16* __restrict__ T0, u16* __restrict__ T1, u16* __restrict__ T2, u16* __restrict__ T3,
    const float* __restrict__ c1w, const float* __restrict__ c2w,
    const float* __restrict__ pos_k,
    u16* __restrict__ Wf1, u16* __restrict__ Wf2, u16* __restrict__ pos_kb,
    const float* __restrict__ X, u16* __restrict__ Xb)
{
    const int z = blockIdx.z;
    const int t = threadIdx.x;
    if (z == 5) {
        const int blk = blockIdx.y * 8 + blockIdx.x;
#pragma unroll
        for (int k2 = 0; k2 < 16; ++k2) {
            const int i = ((blk * 16 + k2) * 256 + t) * 8;
            float4 a = *reinterpret_cast<const float4*>(X + i);
            float4 b = *reinterpret_cast<const float4*>(X + i + 4);
            *reinterpret_cast<uint4*>(Xb + i) =
                make_uint4(pk2(a.x, a.y), pk2(a.z, a.w), pk2(b.x, b.y), pk2(b.z, b.w));
        }
        return;
    }
    if (z == 4) {
        if (blockIdx.x != 0 || blockIdx.y != 0) return;
        for (int s = t; s < 448; s += 256) {
            const int q = s >> 6, l = s & 63, lg = l >> 4, n = l & 15;
            const int G = q * 4 + lg;
            unsigned o[4];
#pragma unroll
            for (int u2 = 0; u2 < 4; ++u2) {
                float v0 = 0.f, v1 = 0.f;
                if (G < 25) {
                    const int dn = G / 5, dm = G - dn * 5;
                    v0 = c1w[((dn * 5 + dm) * 8 + u2 * 2 + 0) * 16 + n];
                    v1 = c1w[((dn * 5 + dm) * 8 + u2 * 2 + 1) * 16 + n];
                }
                o[u2] = pk2(v0, v1);
            }
            *reinterpret_cast<uint4*>(&Wf1[s * 8]) = make_uint4(o[0], o[1], o[2], o[3]);
        }
        for (int s = t; s < 832; s += 256) {
            const int q = s >> 6, l = s & 63, lg = l >> 4, n = l & 15;
            const int G = q * 4 + lg;
            unsigned o[4];
#pragma unroll
            for (int u2 = 0; u2 < 4; ++u2) {
                float v0 = 0.f, v1 = 0.f;
                if (G < 50 && n < 8) {
                    const int pos = G >> 1, h = G & 1;
                    const int dn = pos / 5, dm = pos - dn * 5;
                    v0 = c2w[((dn * 5 + dm) * 16 + h * 8 + u2 * 2 + 0) * 8 + n];
                    v1 = c2w[((dn * 5 + dm) * 16 + h * 8 + u2 * 2 + 1) * 8 + n];
                }
                o[u2] = pk2(v0, v1);
            }
            *reinterpret_cast<uint4*>(&Wf2[s * 8]) = make_uint4(o[0], o[1], o[2], o[3]);
        }
        for (int s = t; s < 128 * 64; s += 256) {
            const int r = s >> 6;
            pos_kb[s] = (r < 121) ? f2bf(pos_k[s]) : (u16)0;
        }
        return;
    }
    const float* W = (z == 0) ? W0 : (z == 1) ? W1 : (z == 2) ? W2 : W3;
    u16* T        = (z == 0) ? T0 : (z == 1) ? T1 : (z == 2) ? T2 : T3;
    __shared__ float ls[64 * 65];
    const int k0 = blockIdx.x * 64, n0 = blockIdx.y * 64;
#pragma unroll
    for (int i = 0; i < 16; ++i) {
        const int idx = t + i * 256, r = idx >> 6, c = idx & 63;
        ls[c * 65 + r] = W[(size_t)(k0 + r) * 512 + n0 + c];
    }
    __syncthreads();
#pragma unroll
    for (int i = 0; i < 16; ++i) {
        const int idx = t + i * 256, r = idx >> 6, c = idx & 63;
        T[(size_t)(n0 + r) * 512 + k0 + c] = f2bf(ls[r * 65 + c]);
    }
}

// ---------------- QKV (MFMA): Xb @ WT -> Q/K bf16 (B,H,N,DH), V^T bf16 (B,H,DH,N)
__global__ __launch_bounds__(256) void k_qkvm(
    const u16* __restrict__ Xb,
    const u16* __restrict__ WT0, const u16* __restrict__ WT1, const u16* __restrict__ WT2,
    const float* __restrict__ b0, const float* __restrict__ b1, const float* __restrict__ b2,
    u16* __restrict__ Qb, u16* __restrict__ Kb, u16* __restrict__ Vt)
{
    const int z = blockIdx.z;
    const u16* WT    = (z == 0) ? WT0 : (z == 1) ? WT1 : WT2;
    const float* bias = (z == 0) ? b0 : (z == 1) ? b1 : b2;
    __shared__ __align__(16) u16 sh[18432];          // As 128x72, Bs 128x72
    u16* As = sh; u16* Bs = sh + 9216;
    const int t = threadIdx.x, lane = t & 63, wave = t >> 6;
    const int wm = wave >> 1, wn = wave & 1;
    const int lg = lane >> 4, ln16 = lane & 15;
    const int m0 = blockIdx.x * 128, n0 = blockIdx.y * 128;
    f32x4 acc[4][4] = {};
    for (int k0 = 0; k0 < 512; k0 += 64) {
#pragma unroll
        for (int u = 0; u < 4; ++u) {
            const int chunk = u * 256 + t, row = chunk >> 3, ko = (chunk & 7) * 8;
            *reinterpret_cast<uint4*>(As + row * 72 + ko) =
                *reinterpret_cast<const uint4*>(Xb + (size_t)(m0 + row) * 512 + k0 + ko);
            *reinterpret_cast<uint4*>(Bs + row * 72 + ko) =
                *reinterpret_cast<const uint4*>(WT + (size_t)(n0 + row) * 512 + k0 + ko);
        }
        __syncthreads();
#pragma unroll
        for (int kk = 0; kk < 64; kk += 32) {
            short8v a[4], bfr[4];
#pragma unroll
            for (int mi = 0; mi < 4; ++mi)
                a[mi] = *reinterpret_cast<const short8v*>(As + (wm * 64 + mi * 16 + ln16) * 72 + kk + lg * 8);
#pragma unroll
            for (int ni = 0; ni < 4; ++ni)
                bfr[ni] = *reinterpret_cast<const short8v*>(Bs + (wn * 64 + ni * 16 + ln16) * 72 + kk + lg * 8);
#pragma unroll
            for (int mi = 0; mi < 4; ++mi)
#pragma unroll
                for (int ni = 0; ni < 4; ++ni)
                    acc[mi][ni] = __builtin_amdgcn_mfma_f32_16x16x32_bf16(a[mi], bfr[ni], acc[mi][ni], 0, 0, 0);
        }
        __syncthreads();
    }
    u16* Cs = sh + wave * 4608;                       // 64x72 per wave
#pragma unroll
    for (int ni = 0; ni < 4; ++ni) {
        const float bv = bias[n0 + wn * 64 + ni * 16 + ln16];
#pragma unroll
        for (int mi = 0; mi < 4; ++mi)
#pragma unroll
            for (int r = 0; r < 4; ++r)
                Cs[(mi * 16 + lg * 4 + r) * 72 + ni * 16 + ln16] = f2bf(acc[mi][ni][r] + bv);
    }
    if (z < 2) {
        u16* O = (z == 0) ? Qb : Kb;
#pragma unroll
        for (int j = 0; j < 8; ++j) {
            const int chunk = j * 64 + lane, row = chunk >> 3, co = (chunk & 7) * 8;
            const int tok = m0 + wm * 64 + row;
            const int b = tok >> 9, n = tok & 511;
            const int cg = n0 + wn * 64 + co;
            const int h = cg >> 6, dh = cg & 63;
            *reinterpret_cast<uint4*>(O + ((size_t)((b * 8 + h) * 512 + n)) * 64 + dh) =
                *reinterpret_cast<const uint4*>(Cs + row * 72 + co);
        }
    } else {
#pragma unroll
        for (int j = 0; j < 8; ++j) {
            const int chunk = j * 64 + lane, dr = chunk >> 3, no8 = (chunk & 7) * 8;
            const int cg = n0 + wn * 64 + dr;
            const int h = cg >> 6, dh = cg & 63;
            const int tok = m0 + wm * 64 + no8;
            const int b = tok >> 9, n = tok & 511;
            u16 v[8];
#pragma unroll
            for (int e = 0; e < 8; ++e) v[e] = Cs[(no8 + e) * 72 + dr];
            uint4 o = make_uint4((unsigned)v[0] | ((unsigned)v[1] << 16),
                                 (unsigned)v[2] | ((unsigned)v[3] << 16),
                                 (unsigned)v[4] | ((unsigned)v[5] << 16),
                                 (unsigned)v[6] | ((unsigned)v[7] << 16));
            *reinterpret_cast<uint4*>(Vt + ((size_t)((b * 8 + h) * 64 + dh)) * 512 + n) = o;
        }
    }
}

// ---------------- qp (MFMA): Q(bh,n,64) @ pos_k^T -> QP bf16 (bh,n,128pad)
__global__ __launch_bounds__(256) void k_qposm(
    const u16* __restrict__ Qb, const u16* __restrict__ pos_kb, u16* __restrict__ QP)
{
    __shared__ __align__(16) u16 sh[18432];
    u16* As = sh; u16* Bs = sh + 9216;
    const int t = threadIdx.x, lane = t & 63, wave = t >> 6;
    const int lg = lane >> 4, ln16 = lane & 15;
    const int n0 = blockIdx.x * 128, bh = blockIdx.y;
#pragma unroll
    for (int u = 0; u < 4; ++u) {
        const int chunk = u * 256 + t, row = chunk >> 3, ko = (chunk & 7) * 8;
        *reinterpret_cast<uint4*>(As + row * 72 + ko) =
            *reinterpret_cast<const uint4*>(Qb + ((size_t)(bh * 512 + n0 + row)) * 64 + ko);
        *reinterpret_cast<uint4*>(Bs + row * 72 + ko) =
            *reinterpret_cast<const uint4*>(pos_kb + (size_t)row * 64 + ko);
    }
    __syncthreads();
    f32x4 acc[2][8] = {};
#pragma unroll
    for (int kk = 0; kk < 64; kk += 32) {
        short8v a[2], bfr[8];
#pragma unroll
        for (int mi = 0; mi < 2; ++mi)
            a[mi] = *reinterpret_cast<const short8v*>(As + (wave * 32 + mi * 16 + ln16) * 72 + kk + lg * 8);
#pragma unroll
        for (int ni = 0; ni < 8; ++ni)
            bfr[ni] = *reinterpret_cast<const short8v*>(Bs + (ni * 16 + ln16) * 72 + kk + lg * 8);
#pragma unroll
        for (int mi = 0; mi < 2; ++mi)
#pragma unroll
            for (int ni = 0; ni < 8; ++ni)
                acc[mi][ni] = __builtin_amdgcn_mfma_f32_16x16x32_bf16(a[mi], bfr[ni], acc[mi][ni], 0, 0, 0);
    }
    __syncthreads();
    u16* Cs = sh + wave * 4352;                      // 32x136 per wave
#pragma unroll
    for (int mi = 0; mi < 2; ++mi)
#pragma unroll
        for (int ni = 0; ni < 8; ++ni)
#pragma unroll
            for (int r = 0; r < 4; ++r)
                Cs[(mi * 16 + lg * 4 + r) * 136 + ni * 16 + ln16] = f2bf(acc[mi][ni][r]);
#pragma unroll
    for (int j = 0; j < 8; ++j) {
        const int chunk = j * 64 + lane, row = chunk >> 4, co = (chunk & 15) * 8;
        *reinterpret_cast<uint4*>(QP + ((size_t)(bh * 512 + n0 + wave * 32 + row)) * 128 + co) =
            *reinterpret_cast<const uint4*>(Cs + row * 136 + co);
    }
}

// ---------------- scores (MFMA): (Q@K^T + QP[rel]) / 8 -> S bf16 (bh,n,m)
// 1-D grid 1024, batch->XCD affine: bid = b + 8*(h + 8*(mx + 4*my))
__global__ __launch_bounds__(256) void k_scoresm(
    const u16* __restrict__ Qb, const u16* __restrict__ Kb, const u16* __restrict__ QP,
    u16* __restrict__ S)
{
    __shared__ __align__(16) u16 sh[18432];
    u16* As = sh; u16* Bs = sh + 9216;
    const int t = threadIdx.x, lane = t & 63, wave = t >> 6;
    const int wm = wave >> 1, wn = wave & 1;
    const int lg = lane >> 4, ln16 = lane & 15;
    const int bid = blockIdx.x;
    const int bb = bid & 7;
    const int rest = bid >> 3;
    const int h = rest & 7;
    const int tile = rest >> 3;
    const int mx = tile & 3, my = tile >> 2;
    const int bh = bb * 8 + h;
    const int m0 = mx * 128, n0 = my * 128;
#pragma unroll
    for (int u = 0; u < 4; ++u) {
        const int chunk = u * 256 + t, row = chunk >> 3, ko = (chunk & 7) * 8;
        *reinterpret_cast<uint4*>(As + row * 72 + ko) =
            *reinterpret_cast<const uint4*>(Qb + ((size_t)(bh * 512 + n0 + row)) * 64 + ko);
        *reinterpret_cast<uint4*>(Bs + row * 72 + ko) =
            *reinterpret_cast<const uint4*>(Kb + ((size_t)(bh * 512 + m0 + row)) * 64 + ko);
    }
    __syncthreads();
    f32x4 acc[4][4] = {};
#pragma unroll
    for (int kk = 0; kk < 64; kk += 32) {
        short8v a[4], bfr[4];
#pragma unroll
        for (int mi = 0; mi < 4; ++mi)
            a[mi] = *reinterpret_cast<const short8v*>(As + (wm * 64 + mi * 16 + ln16) * 72 + kk + lg * 8);
#pragma unroll
        for (int ni = 0; ni < 4; ++ni)
            bfr[ni] = *reinterpret_cast<const short8v*>(Bs + (wn * 64 + ni * 16 + ln16) * 72 + kk + lg * 8);
#pragma unroll
        for (int mi = 0; mi < 4; ++mi)
#pragma unroll
            for (int ni = 0; ni < 4; ++ni)
                acc[mi][ni] = __builtin_amdgcn_mfma_f32_16x16x32_bf16(a[mi], bfr[ni], acc[mi][ni], 0, 0, 0);
    }
    __syncthreads();
    u16* QPs = sh;                                   // 128x128 bf16
#pragma unroll
    for (int u = 0; u < 8; ++u) {
        const int chunk = u * 256 + t, row = chunk >> 4, co = (chunk & 15) * 8;
        *reinterpret_cast<uint4*>(QPs + row * 128 + co) =
            *reinterpret_cast<const uint4*>(QP + ((size_t)(bh * 512 + n0 + row)) * 128 + co);
    }
    __syncthreads();
#pragma unroll
    for (int mi = 0; mi < 4; ++mi)
#pragma unroll
        for (int ni = 0; ni < 4; ++ni) {
            const int m_g = m0 + wn * 64 + ni * 16 + ln16;
#pragma unroll
            for (int r = 0; r < 4; ++r) {
                const int n_loc = wm * 64 + mi * 16 + lg * 4 + r;
                const int n_g = n0 + n_loc;
                int rel = m_g - n_g;
                rel = rel < -PC_ ? -PC_ : (rel > PC_ ? PC_ : rel);
                const float v = (acc[mi][ni][r] + bf2f(QPs[n_loc * 128 + rel + PC_])) * 0.125f;
                S[(size_t)bh * 262144 + (size_t)n_g * 512 + m_g] = f2bf(v);
            }
        }
}

// ---------------- conv1 (MFMA, swapped operands): S bf16 planar -> Y ch-last + fused stats
// 1-D grid 2048, batch->XCD affine, x-fastest band sweep: bid = b + 8*(mx + 16*my)
__global__ __launch_bounds__(256) void k_conv1m(
    const u16* __restrict__ S, const u16* __restrict__ Wf,
    const float* __restrict__ bias, u16* __restrict__ Y,
    const int* __restrict__ VL, float* __restrict__ ST)
{
    __shared__ __align__(16) u16 xs[10368];
    __shared__ float wred[4][4][8];     // [wave][lg][s:0..3, s2:4..7]
    const int t = threadIdx.x;
    const int bid = blockIdx.x;
    const int b = bid & 7;
    const int rest = bid >> 3;
    const int m0 = (rest & 15) * 32;
    const int n0 = (rest >> 4) * 32;
    const u16* sp0 = S + (size_t)(b * 8) * 262144;
    // paired-pixel staging: 648 pairs; width 36 even + m0 even => pair shares validity/alignment
    for (int p = t; p < 648; p += 256) {
        const int idx2 = p * 2;
        const int r = idx2 / 36, c = idx2 - r * 36;
        const int gn = n0 - 2 + r, gm = m0 - 2 + c;
        uint4 o0 = make_uint4(0, 0, 0, 0), o1 = o0;
        if ((unsigned)gn < 512u && (unsigned)gm < 512u) {
            const u16* pp = sp0 + (size_t)gn * 512 + gm;
            unsigned u[8];
#pragma unroll
            for (int e = 0; e < 8; ++e)
                u[e] = *reinterpret_cast<const unsigned*>(pp + (size_t)e * 262144);
            o0 = make_uint4((u[0] & 0xffffu) | ((u[1] & 0xffffu) << 16),
                            (u[2] & 0xffffu) | ((u[3] & 0xffffu) << 16),
                            (u[4] & 0xffffu) | ((u[5] & 0xffffu) << 16),
                            (u[6] & 0xffffu) | ((u[7] & 0xffffu) << 16));
            o1 = make_uint4((u[0] >> 16) | (u[1] & 0xffff0000u),
                            (u[2] >> 16) | (u[3] & 0xffff0000u),
                            (u[4] >> 16) | (u[5] & 0xffff0000u),
                            (u[6] >> 16) | (u[7] & 0xffff0000u));
        }
        *reinterpret_cast<uint4*>(&xs[idx2 * 8]) = o0;
        *reinterpret_cast<uint4*>(&xs[(idx2 + 1) * 8]) = o1;
    }
    const int lane = t & 63, wave = t >> 6;
    const int lg = lane >> 4, ln16 = lane & 15;
    short8v bq[7];
#pragma unroll
    for (int q = 0; q < 7; ++q)
        bq[q] = *reinterpret_cast<const short8v*>(&Wf[(q * 64 + lane) * 8]);
    int aoff[7];
#pragma unroll
    for (int q = 0; q < 7; ++q) {
        const int G = q * 4 + lg; const int p = (G < 25) ? G : 0;
        const int dn = p / 5, dm = p - dn * 5;
        aoff[q] = (dn * 36 + dm) * 8;
    }
    const float4 b4 = *reinterpret_cast<const float4*>(&bias[lg * 4]);   // channels lg*4..+3
    const int vl = VL[b];
    f32x4 sstv = {0.f, 0.f, 0.f, 0.f}, sst2v = {0.f, 0.f, 0.f, 0.f};
    __syncthreads();
    for (int i = 0; i < 16; ++i) {
        const int j = wave * 16 + i;
        const int tr = j >> 1, c0 = (j & 1) << 4;
        const int pb = (tr * 36 + c0 + ln16) * 8;
        f32x4 acc = {b4.x, b4.y, b4.z, b4.w};
#pragma unroll
        for (int q = 0; q < 7; ++q) {
            short8v a = *reinterpret_cast<const short8v*>(&xs[pb + aoff[q]]);
            // swapped: A=weights(channels as M), B=pixels(as N) -> lane=pixel, regs=4 channels
            acc = __builtin_amdgcn_mfma_f32_16x16x32_bf16(bq[q], a, acc, 0, 0, 0);
        }
        // lane = pixel (c0+ln16), regs = channels lg*4+r -> coalesced uint2 store (512B/wave)
        u16* yb = Y + (((size_t)(b * 512 + n0 + tr)) * 512 + (m0 + c0 + ln16)) * 16 + lg * 4;
        *reinterpret_cast<uint2*>(yb) = make_uint2(pk2(acc[0], acc[1]), pk2(acc[2], acc[3]));
        if (n0 + tr < vl) {
            sstv += acc;
            sst2v += acc * acc;
        }
    }
#pragma unroll
    for (int o = 1; o < 16; o <<= 1) {
#pragma unroll
        for (int r = 0; r < 4; ++r) {
            sstv[r]  += __shfl_xor(sstv[r], o);
            sst2v[r] += __shfl_xor(sst2v[r], o);
        }
    }
    if (ln16 == 0) {
#pragma unroll
        for (int r = 0; r < 4; ++r) {
            wred[wave][lg][r]     = sstv[r];
            wred[wave][lg][4 + r] = sst2v[r];
        }
    }
    __syncthreads();
    if (t < 16) {
        const int lgg = t >> 2, r = t & 3;
        const float a  = wred[0][lgg][r] + wred[1][lgg][r] + wred[2][lgg][r] + wred[3][lgg][r];
        const float b2 = wred[0][lgg][4 + r] + wred[1][lgg][4 + r] + wred[2][lgg][4 + r] + wred[3][lgg][4 + r];
        atomicAdd(&ST[(b * 16 + t) * 2 + 0], a);
        atomicAdd(&ST[(b * 16 + t) * 2 + 1], b2);
    }
}

// ---------------- conv2 (MFMA): Y ch-last bf16, statfin + norm+relu fused -> S2 bf16 planar
// 1-D grid 2048, batch->XCD affine, x-fastest band sweep
__global__ __launch_bounds__(256) void k_conv2m(
    const u16* __restrict__ Y, const float* __restrict__ ST,
    const int* __restrict__ VL, const float* __restrict__ n1g, const float* __restrict__ n1b,
    const u16* __restrict__ Wf, const float* __restrict__ bias,
    u16* __restrict__ S2)
{
    __shared__ __align__(16) u16 xs[20736];
    __shared__ float ssh[16][2];
    const int t = threadIdx.x;
    const int bid = blockIdx.x;
    const int b = bid & 7;
    const int rest = bid >> 3;
    const int m0 = (rest & 15) * 32;
    const int n0 = (rest >> 4) * 32;
    if (t < 16) {                       // folded statfin (redundant per block, trivial)
        const float sw = (float)VL[b] * 512.f;
        const float mean = ST[(b * 16 + t) * 2 + 0] / sw;
        const float var  = ST[(b * 16 + t) * 2 + 1] / sw - mean * mean;
        const float sc = n1g[t] * rsqrtf(var + 1e-7f);
        ssh[t][0] = sc;
        ssh[t][1] = n1b[t] - mean * sc;
    }
    __syncthreads();
    float sc[16], shv[16];
#pragma unroll
    for (int ch = 0; ch < 16; ++ch) { sc[ch] = ssh[ch][0]; shv[ch] = ssh[ch][1]; }
    for (int idx = t; idx < 1296; idx += 256) {
        const int r = idx / 36; const int c = idx - r * 36;
        const int gn = n0 - 2 + r, gm = m0 - 2 + c;
        uint4 p0 = make_uint4(0, 0, 0, 0), p1 = p0;
        if ((unsigned)gn < 512u && (unsigned)gm < 512u) {
            const u16* yp = Y + (((size_t)(b * 512 + gn)) * 512 + gm) * 16;
            const uint4 r0 = *reinterpret_cast<const uint4*>(yp);
            const uint4 r1 = *reinterpret_cast<const uint4*>(yp + 8);
            const unsigned w0[4] = {r0.x, r0.y, r0.z, r0.w};
            const unsigned w1[4] = {r1.x, r1.y, r1.z, r1.w};
            unsigned o0[4], o1[4];
#pragma unroll
            for (int u2 = 0; u2 < 4; ++u2) {
                const int ch = u2 * 2;
                float a0 = bf2f((u16)(w0[u2] & 0xffff));
                float a1 = bf2f((u16)(w0[u2] >> 16));
                a0 = fmaf(a0, sc[ch], shv[ch]);          a0 = a0 > 0.f ? a0 : 0.f;
                a1 = fmaf(a1, sc[ch + 1], shv[ch + 1]);  a1 = a1 > 0.f ? a1 : 0.f;
                o0[u2] = pk2(a0, a1);
                const int ch2 = 8 + u2 * 2;
                float b0 = bf2f((u16)(w1[u2] & 0xffff));
                float b1 = bf2f((u16)(w1[u2] >> 16));
                b0 = fmaf(b0, sc[ch2], shv[ch2]);          b0 = b0 > 0.f ? b0 : 0.f;
                b1 = fmaf(b1, sc[ch2 + 1], shv[ch2 + 1]);  b1 = b1 > 0.f ? b1 : 0.f;
                o1[u2] = pk2(b0, b1);
            }
            p0 = make_uint4(o0[0], o0[1], o0[2], o0[3]);
            p1 = make_uint4(o1[0], o1[1], o1[2], o1[3]);
        }
        *reinterpret_cast<uint4*>(&xs[idx * 8]) = p0;
        *reinterpret_cast<uint4*>(&xs[10368 + idx * 8]) = p1;
    }
    const int lane = t & 63, wave = t >> 6;
    const int lg = lane >> 4, ln16 = lane & 15;
    short8v bq[13];
#pragma unroll
    for (int q = 0; q < 13; ++q)
        bq[q] = *reinterpret_cast<const short8v*>(&Wf[(q * 64 + lane) * 8]);
    int aoff[13];
#pragma unroll
    for (int q = 0; q < 13; ++q) {
        const int G = q * 4 + lg; const int p = (G < 50) ? G : 0;
        const int pos = p >> 1, h = p & 1;
        const int dn = pos / 5, dm = pos - dn * 5;
        aoff[q] = h * 10368 + (dn * 36 + dm) * 8;
    }
    const float bs = (ln16 < 8) ? bias[ln16] : 0.f;
    __syncthreads();
    for (int i = 0; i < 16; ++i) {
        const int j = wave * 16 + i;
        const int tr = j >> 1, c0 = (j & 1) << 4;
        const int pb = (tr * 36 + c0 + ln16) * 8;
        f32x4 acc = {bs, bs, bs, bs};
#pragma unroll
        for (int q = 0; q < 13; ++q) {
            short8v a = *reinterpret_cast<const short8v*>(&xs[pb + aoff[q]]);
            acc = __builtin_amdgcn_mfma_f32_16x16x32_bf16(a, bq[q], acc, 0, 0, 0);
        }
        if (ln16 < 8) {
            uint2 o = make_uint2(pk2(acc[0], acc[1]), pk2(acc[2], acc[3]));
            *reinterpret_cast<uint2*>(
                &S2[(((size_t)(b * 8 + ln16)) * 512 + n0 + tr) * 512 + m0 + c0 + lg * 4]) = o;
        }
    }
}

// ---------------- fused masked softmax + A@V (64-row tile): logits bf16 -> X2(B,N,512) bf16
// 1-D grid 512, batch->XCD affine: bid = b + 8*(nx + 8*h)
__global__ __launch_bounds__(256) void k_softav(
    const u16* __restrict__ SL, const u16* __restrict__ Vt,
    const int* __restrict__ VL, u16* __restrict__ X2)
{
    __shared__ __align__(16) u16 As[4608];   // 64x72
    __shared__ __align__(16) u16 Bs[4608];   // 64x72
    __shared__ float smx[64], siv[64];
    const int t = threadIdx.x, lane = t & 63, wave = t >> 6;
    const int lg = lane >> 4, ln16 = lane & 15;
    const int bid = blockIdx.x;
    const int b = bid & 7;
    const int rest = bid >> 3;
    const int nx = rest & 7;
    const int h = rest >> 3;
    const int n0 = nx * 64;
    const int bh = b * 8 + h;
    const int vl = VL[b];
    const u16* Sp = SL + (size_t)bh * 262144;
    for (int rr = 0; rr < 16; ++rr) {
        const int row = wave * 16 + rr;
        uint4 v = *reinterpret_cast<const uint4*>(Sp + (size_t)(n0 + row) * 512 + lane * 8);
        const unsigned w[4] = {v.x, v.y, v.z, v.w};
        float x[8];
#pragma unroll
        for (int j = 0; j < 4; ++j) {
            x[2 * j]     = bf2f((u16)(w[j] & 0xffff));
            x[2 * j + 1] = bf2f((u16)(w[j] >> 16));
        }
        const int mb = lane * 8;
        float mx = -3.0e38f;
#pragma unroll
        for (int j = 0; j < 8; ++j) {
            if (mb + j >= vl) x[j] = -3.0e38f;
            mx = fmaxf(mx, x[j]);
        }
#pragma unroll
        for (int o = 32; o; o >>= 1) mx = fmaxf(mx, __shfl_xor(mx, o));
        float sm = 0.f;
#pragma unroll
        for (int j = 0; j < 8; ++j) sm += __expf(x[j] - mx);
#pragma unroll
        for (int o = 32; o; o >>= 1) sm += __shfl_xor(sm, o);
        if (lane == 0) { smx[row] = mx; siv[row] = 1.0f / sm; }
    }
    __syncthreads();
    f32x4 acc[4] = {};
    for (int k0 = 0; k0 < 512; k0 += 64) {
#pragma unroll
        for (int u = 0; u < 2; ++u) {
            const int chunk = u * 256 + t, row = chunk >> 3, ko = (chunk & 7) * 8;
            uint4 raw = *reinterpret_cast<const uint4*>(Sp + (size_t)(n0 + row) * 512 + k0 + ko);
            const unsigned w[4] = {raw.x, raw.y, raw.z, raw.w};
            const float mxr = smx[row], ivr = siv[row];
            unsigned o[4];
#pragma unroll
            for (int jj = 0; jj < 4; ++jj) {
                const int m0i = k0 + ko + 2 * jj;
                float a0 = (m0i     < vl) ? __expf(bf2f((u16)(w[jj] & 0xffff)) - mxr) * ivr : 0.f;
                float a1 = (m0i + 1 < vl) ? __expf(bf2f((u16)(w[jj] >> 16))   - mxr) * ivr : 0.f;
                o[jj] = pk2(a0, a1);
            }
            *reinterpret_cast<uint4*>(As + row * 72 + ko) = make_uint4(o[0], o[1], o[2], o[3]);
            *reinterpret_cast<uint4*>(Bs + row * 72 + ko) =
                *reinterpret_cast<const uint4*>(Vt + ((size_t)(bh * 64 + row)) * 512 + k0 + ko);
        }
        __syncthreads();
#pragma unroll
        for (int kk = 0; kk < 64; kk += 32) {
            short8v a = *reinterpret_cast<const short8v*>(As + (wave * 16 + ln16) * 72 + kk + lg * 8);
#pragma unroll
            for (int ni = 0; ni < 4; ++ni) {
                short8v bfr = *reinterpret_cast<const short8v*>(Bs + (ni * 16 + ln16) * 72 + kk + lg * 8);
                acc[ni] = __builtin_amdgcn_mfma_f32_16x16x32_bf16(a, bfr, acc[ni], 0, 0, 0);
            }
        }
        __syncthreads();
    }
    u16* Cs = As + wave * 1152;                      // 16x72 per wave
#pragma unroll
    for (int ni = 0; ni < 4; ++ni)
#pragma unroll
        for (int r = 0; r < 4; ++r)
            Cs[(lg * 4 + r) * 72 + ni * 16 + ln16] = f2bf(acc[ni][r]);
#pragma unroll
    for (int j = 0; j < 2; ++j) {
        const int chunk = j * 64 + lane, row = chunk >> 3, co = (chunk & 7) * 8;
        const int tn = n0 + wave * 16 + row;
        *reinterpret_cast<uint4*>(X2 + ((size_t)(b * 512 + tn)) * 512 + h * 64 + co) =
            *reinterpret_cast<const uint4*>(Cs + row * 72 + co);
    }
}

// ---------------- out-proj (MFMA): X2 @ WhT + bh + query -> P f32
__global__ __launch_bounds__(256) void k_outm(
    const u16* __restrict__ X2, const u16* __restrict__ WT, const float* __restrict__ bias,
    const float* __restrict__ Xq, float* __restrict__ Pout)
{
    __shared__ __align__(16) u16 sh[18432];
    u16* As = sh; u16* Bs = sh + 9216;
    const int t = threadIdx.x, lane = t & 63, wave = t >> 6;
    const int wm = wave >> 1, wn = wave & 1;
    const int lg = lane >> 4, ln16 = lane & 15;
    const int m0 = blockIdx.x * 128, n0 = blockIdx.y * 128;
    f32x4 acc[4][4] = {};
    for (int k0 = 0; k0 < 512; k0 += 64) {
#pragma unroll
        for (int u = 0; u < 4; ++u) {
            const int chunk = u * 256 + t, row = chunk >> 3, ko = (chunk & 7) * 8;
            *reinterpret_cast<uint4*>(As + row * 72 + ko) =
                *reinterpret_cast<const uint4*>(X2 + (size_t)(m0 + row) * 512 + k0 + ko);
            *reinterpret_cast<uint4*>(Bs + row * 72 + ko) =
                *reinterpret_cast<const uint4*>(WT + (size_t)(n0 + row) * 512 + k0 + ko);
        }
        __syncthreads();
#pragma unroll
        for (int kk = 0; kk < 64; kk += 32) {
            short8v a[4], bfr[4];
#pragma unroll
            for (int mi = 0; mi < 4; ++mi)
                a[mi] = *reinterpret_cast<const short8v*>(As + (wm * 64 + mi * 16 + ln16) * 72 + kk + lg * 8);
#pragma unroll
            for (int ni = 0; ni < 4; ++ni)
                bfr[ni] = *reinterpret_cast<const short8v*>(Bs + (wn * 64 + ni * 16 + ln16) * 72 + kk + lg * 8);
#pragma unroll
            for (int mi = 0; mi < 4; ++mi)
#pragma unroll
                for (int ni = 0; ni < 4; ++ni)
                    acc[mi][ni] = __builtin_amdgcn_mfma_f32_16x16x32_bf16(a[mi], bfr[ni], acc[mi][ni], 0, 0, 0);
        }
        __syncthreads();
    }
#pragma unroll
    for (int ni = 0; ni < 4; ++ni) {
        const int cg = n0 + wn * 64 + ni * 16 + ln16;
        const float bv = bias[cg];
#pragma unroll
        for (int mi = 0; mi < 4; ++mi)
#pragma unroll
            for (int r = 0; r < 4; ++r) {
                const int tok = m0 + wm * 64 + mi * 16 + lg * 4 + r;
                Pout[(size_t)tok * 512 + cg] = acc[mi][ni][r] + bv + Xq[(size_t)tok * 512 + cg];
            }
    }
}

// ---------------- final LayerNorm over D=512
__global__ __launch_bounds__(256) void k_ln(
    const float* __restrict__ P, const float* __restrict__ g,
    const float* __restrict__ be, float* __restrict__ out)
{
    const int row = blockIdx.x * 4 + (threadIdx.x >> 6);
    const int lane = threadIdx.x & 63;
    const float* p = P + (size_t)row * 512;
    float4 v0 = reinterpret_cast<const float4*>(p)[lane];
    float4 v1 = reinterpret_cast<const float4*>(p)[64 + lane];
    float s = v0.x + v0.y + v0.z + v0.w + v1.x + v1.y + v1.z + v1.w;
#pragma unroll
    for (int o = 32; o; o >>= 1) s += __shfl_xor(s, o);
    const float mean = s * (1.0f / 512.0f);
    float d[8] = {v0.x - mean, v0.y - mean, v0.z - mean, v0.w - mean,
                  v1.x - mean, v1.y - mean, v1.z - mean, v1.w - mean};
    float s2 = 0.f;
#pragma unroll
    for (int j = 0; j < 8; ++j) s2 += d[j] * d[j];
#pragma unroll
    for (int o = 32; o; o >>= 1) s2 += __shfl_xor(s2, o);
    const float rstd = rsqrtf(s2 * (1.0f / 512.0f) + 1e-7f);
    float4 g0 = reinterpret_cast<const float4*>(g)[lane];
    float4 g1 = reinterpret_cast<const float4*>(g)[64 + lane];
    float4 b0 = reinterpret_cast<const float4*>(be)[lane];
    float4 b1 = reinterpret_cast<const float4*>(be)[64 + lane];
    float* op = out + (size_t)row * 512;
    reinterpret_cast<float4*>(op)[lane] =
        make_float4(d[0] * rstd * g0.x + b0.x, d[1] * rstd * g0.y + b0.y,
                    d[2] * rstd * g0.z + b0.z, d[3] * rstd * g0.w + b0.w);
    reinterpret_cast<float4*>(op)[64 + lane] =
        make_float4(d[4] * rstd * g1.x + b1.x, d[5] * rstd * g1.y + b1.y,
                    d[6] * rstd * g1.z + b1.z, d[7] * rstd * g1.w + b1.w);
}

extern "C" void kernel_launch(void* const* d_in, const int* in_sizes, int n_in,
                              void* d_out, int out_size, void* d_ws, size_t ws_size,
                              hipStream_t stream)
{
    const float* query = (const float*)d_in[0];
    const int*   VL    = (const int*)d_in[1];
    const float* Wq = (const float*)d_in[2];  const float* bq = (const float*)d_in[3];
    const float* Wk = (const float*)d_in[4];  const float* bk = (const float*)d_in[5];
    const float* Wv = (const float*)d_in[6];  const float* bv = (const float*)d_in[7];
    const float* Wh = (const float*)d_in[8];  const float* bh = (const float*)d_in[9];
    const float* pos_k = (const float*)d_in[10];
    const float* c1w = (const float*)d_in[11]; const float* c1b = (const float*)d_in[12];
    const float* n1g = (const float*)d_in[13]; const float* n1b = (const float*)d_in[14];
    const float* c2w = (const float*)d_in[15]; const float* c2b = (const float*)d_in[16];
    const float* lng = (const float*)d_in[17]; const float* lnb = (const float*)d_in[18];

    float* ws = (float*)d_ws;
    const size_t M1 = (size_t)1 << 20;
    u16* S1  = (u16*)ws;
    u16* Y1  = (u16*)(ws + 8 * M1);
    u16* Xb  = (u16*)(ws + 24 * M1);
    u16* Qb  = (u16*)(ws + 25 * M1);
    u16* Kb  = (u16*)(ws + 26 * M1);
    u16* Vt  = (u16*)(ws + 27 * M1);
    u16* QPb = (u16*)(ws + 28 * M1);
    u16* WqT = (u16*)(ws + 30 * M1);
    u16* WkT = WqT + 262144;
    u16* WvT = WkT + 262144;
    u16* WhT = WvT + 262144;
    u16* pos_kb = (u16*)(ws + 30 * M1 + 524288);
    u16* Wf1 = pos_kb + 8192;
    u16* Wf2 = Wf1 + 3584;
    float* ST  = ws + 31 * M1;
    u16* X2 = Xb;
    float* Pout = ws + 28 * M1;

    hipMemsetAsync(ST, 0, 256 * sizeof(float), stream);

    k_prept<<<dim3(8, 8, 6), 256, 0, stream>>>(Wq, Wk, Wv, Wh, WqT, WkT, WvT, WhT,
                                               c1w, c2w, pos_k, Wf1, Wf2, pos_kb,
                                               query, Xb);
    k_qkvm<<<dim3(32, 4, 3), 256, 0, stream>>>(Xb, WqT, WkT, WvT, bq, bk, bv, Qb, Kb, Vt);
    k_qposm<<<dim3(4, 64), 256, 0, stream>>>(Qb, pos_kb, QPb);
    k_scoresm<<<1024, 256, 0, stream>>>(Qb, Kb, QPb, S1);
    k_conv1m<<<2048, 256, 0, stream>>>(S1, Wf1, c1b, Y1, VL, ST);
    k_conv2m<<<2048, 256, 0, stream>>>(Y1, ST, VL, n1g, n1b, Wf2, c2b, S1);
    k_softav<<<512, 256, 0, stream>>>(S1, Vt, VL, X2);
    k_outm<<<dim3(32, 4), 256, 0, stream>>>(X2, WhT, bh, query, Pout);
    k_ln<<<1024, 256, 0, stream>>>(Pout, lng, lnb, (float*)d_out);
}

// Round 9
// 255.260 us; speedup vs baseline: 1.2775x; 1.0042x over previous
//
#include <hip/hip_runtime.h>

#define PC_ 60

typedef unsigned short u16;
typedef __attribute__((ext_vector_type(8))) short short8v;   // 8 bf16 (4 VGPR)
typedef __attribute__((ext_vector_type(4))) float f32x4;

__device__ inline float bf2f(u16 u) {
    union { unsigned int i; float f; } x; x.i = ((unsigned)u) << 16; return x.f;
}
__device__ inline u16 f2bf(float f) {
    union { float f; unsigned int i; } x; x.f = f;
    unsigned int r = x.i + 0x7fff + ((x.i >> 16) & 1);   // RNE
    return (u16)(r >> 16);
}
__device__ inline unsigned pk2(float a, float b) {
    return (unsigned)f2bf(a) | ((unsigned)f2bf(b) << 16);
}

// ---------------- prep: W transposes (z<4) + conv-frag/pos (z==4) + query->bf16 (z==5)
__global__ __launch_bounds__(256) void k_prept(
    const float* __restrict__ W0, const float* __restrict__ W1,
    const float* __restrict__ W2, const float* __restrict__ W3,
    u16* __restrict__ T0, u16* __restrict__ T1, u16* __restrict__ T2, u16* __restrict__ T3,
    const float* __restrict__ c1w, const float* __restrict__ c2w,
    const float* __restrict__ pos_k,
    u16* __restrict__ Wf1, u16* __restrict__ Wf2, u16* __restrict__ pos_kb,
    const float* __restrict__ X, u16* __restrict__ Xb)
{
    const int z = blockIdx.z;
    const int t = threadIdx.x;
    if (z == 5) {
        const int blk = blockIdx.y * 8 + blockIdx.x;
#pragma unroll
        for (int k2 = 0; k2 < 16; ++k2) {
            const int i = ((blk * 16 + k2) * 256 + t) * 8;
            float4 a = *reinterpret_cast<const float4*>(X + i);
            float4 b = *reinterpret_cast<const float4*>(X + i + 4);
            *reinterpret_cast<uint4*>(Xb + i) =
                make_uint4(pk2(a.x, a.y), pk2(a.z, a.w), pk2(b.x, b.y), pk2(b.z, b.w));
        }
        return;
    }
    if (z == 4) {
        if (blockIdx.x != 0 || blockIdx.y != 0) return;
        for (int s = t; s < 448; s += 256) {
            const int q = s >> 6, l = s & 63, lg = l >> 4, n = l & 15;
            const int G = q * 4 + lg;
            unsigned o[4];
#pragma unroll
            for (int u2 = 0; u2 < 4; ++u2) {
                float v0 = 0.f, v1 = 0.f;
                if (G < 25) {
                    const int dn = G / 5, dm = G - dn * 5;
                    v0 = c1w[((dn * 5 + dm) * 8 + u2 * 2 + 0) * 16 + n];
                    v1 = c1w[((dn * 5 + dm) * 8 + u2 * 2 + 1) * 16 + n];
                }
                o[u2] = pk2(v0, v1);
            }
            *reinterpret_cast<uint4*>(&Wf1[s * 8]) = make_uint4(o[0], o[1], o[2], o[3]);
        }
        for (int s = t; s < 832; s += 256) {
            const int q = s >> 6, l = s & 63, lg = l >> 4, n = l & 15;
            const int G = q * 4 + lg;
            unsigned o[4];
#pragma unroll
            for (int u2 = 0; u2 < 4; ++u2) {
                float v0 = 0.f, v1 = 0.f;
                if (G < 50 && n < 8) {
                    const int pos = G >> 1, h = G & 1;
                    const int dn = pos / 5, dm = pos - dn * 5;
                    v0 = c2w[((dn * 5 + dm) * 16 + h * 8 + u2 * 2 + 0) * 8 + n];
                    v1 = c2w[((dn * 5 + dm) * 16 + h * 8 + u2 * 2 + 1) * 8 + n];
                }
                o[u2] = pk2(v0, v1);
            }
            *reinterpret_cast<uint4*>(&Wf2[s * 8]) = make_uint4(o[0], o[1], o[2], o[3]);
        }
        for (int s = t; s < 128 * 64; s += 256) {
            const int r = s >> 6;
            pos_kb[s] = (r < 121) ? f2bf(pos_k[s]) : (u16)0;
        }
        return;
    }
    const float* W = (z == 0) ? W0 : (z == 1) ? W1 : (z == 2) ? W2 : W3;
    u16* T        = (z == 0) ? T0 : (z == 1) ? T1 : (z == 2) ? T2 : T3;
    __shared__ float ls[64 * 65];
    const int k0 = blockIdx.x * 64, n0 = blockIdx.y * 64;
#pragma unroll
    for (int i = 0; i < 16; ++i) {
        const int idx = t + i * 256, r = idx >> 6, c = idx & 63;
        ls[c * 65 + r] = W[(size_t)(k0 + r) * 512 + n0 + c];
    }
    __syncthreads();
#pragma unroll
    for (int i = 0; i < 16; ++i) {
        const int idx = t + i * 256, r = idx >> 6, c = idx & 63;
        T[(size_t)(n0 + r) * 512 + k0 + c] = f2bf(ls[r * 65 + c]);
    }
}

// ---------------- QKV (MFMA): Xb @ WT -> Q/K bf16 (B,H,N,DH), V^T bf16 (B,H,DH,N)
__global__ __launch_bounds__(256) void k_qkvm(
    const u16* __restrict__ Xb,
    const u16* __restrict__ WT0, const u16* __restrict__ WT1, const u16* __restrict__ WT2,
    const float* __restrict__ b0, const float* __restrict__ b1, const float* __restrict__ b2,
    u16* __restrict__ Qb, u16* __restrict__ Kb, u16* __restrict__ Vt)
{
    const int z = blockIdx.z;
    const u16* WT    = (z == 0) ? WT0 : (z == 1) ? WT1 : WT2;
    const float* bias = (z == 0) ? b0 : (z == 1) ? b1 : b2;
    __shared__ __align__(16) u16 sh[18432];          // As 128x72, Bs 128x72
    u16* As = sh; u16* Bs = sh + 9216;
    const int t = threadIdx.x, lane = t & 63, wave = t >> 6;
    const int wm = wave >> 1, wn = wave & 1;
    const int lg = lane >> 4, ln16 = lane & 15;
    const int m0 = blockIdx.x * 128, n0 = blockIdx.y * 128;
    f32x4 acc[4][4] = {};
    for (int k0 = 0; k0 < 512; k0 += 64) {
#pragma unroll
        for (int u = 0; u < 4; ++u) {
            const int chunk = u * 256 + t, row = chunk >> 3, ko = (chunk & 7) * 8;
            *reinterpret_cast<uint4*>(As + row * 72 + ko) =
                *reinterpret_cast<const uint4*>(Xb + (size_t)(m0 + row) * 512 + k0 + ko);
            *reinterpret_cast<uint4*>(Bs + row * 72 + ko) =
                *reinterpret_cast<const uint4*>(WT + (size_t)(n0 + row) * 512 + k0 + ko);
        }
        __syncthreads();
#pragma unroll
        for (int kk = 0; kk < 64; kk += 32) {
            short8v a[4], bfr[4];
#pragma unroll
            for (int mi = 0; mi < 4; ++mi)
                a[mi] = *reinterpret_cast<const short8v*>(As + (wm * 64 + mi * 16 + ln16) * 72 + kk + lg * 8);
#pragma unroll
            for (int ni = 0; ni < 4; ++ni)
                bfr[ni] = *reinterpret_cast<const short8v*>(Bs + (wn * 64 + ni * 16 + ln16) * 72 + kk + lg * 8);
#pragma unroll
            for (int mi = 0; mi < 4; ++mi)
#pragma unroll
                for (int ni = 0; ni < 4; ++ni)
                    acc[mi][ni] = __builtin_amdgcn_mfma_f32_16x16x32_bf16(a[mi], bfr[ni], acc[mi][ni], 0, 0, 0);
        }
        __syncthreads();
    }
    u16* Cs = sh + wave * 4608;                       // 64x72 per wave
#pragma unroll
    for (int ni = 0; ni < 4; ++ni) {
        const float bv = bias[n0 + wn * 64 + ni * 16 + ln16];
#pragma unroll
        for (int mi = 0; mi < 4; ++mi)
#pragma unroll
            for (int r = 0; r < 4; ++r)
                Cs[(mi * 16 + lg * 4 + r) * 72 + ni * 16 + ln16] = f2bf(acc[mi][ni][r] + bv);
    }
    if (z < 2) {
        u16* O = (z == 0) ? Qb : Kb;
#pragma unroll
        for (int j = 0; j < 8; ++j) {
            const int chunk = j * 64 + lane, row = chunk >> 3, co = (chunk & 7) * 8;
            const int tok = m0 + wm * 64 + row;
            const int b = tok >> 9, n = tok & 511;
            const int cg = n0 + wn * 64 + co;
            const int h = cg >> 6, dh = cg & 63;
            *reinterpret_cast<uint4*>(O + ((size_t)((b * 8 + h) * 512 + n)) * 64 + dh) =
                *reinterpret_cast<const uint4*>(Cs + row * 72 + co);
        }
    } else {
#pragma unroll
        for (int j = 0; j < 8; ++j) {
            const int chunk = j * 64 + lane, dr = chunk >> 3, no8 = (chunk & 7) * 8;
            const int cg = n0 + wn * 64 + dr;
            const int h = cg >> 6, dh = cg & 63;
            const int tok = m0 + wm * 64 + no8;
            const int b = tok >> 9, n = tok & 511;
            u16 v[8];
#pragma unroll
            for (int e = 0; e < 8; ++e) v[e] = Cs[(no8 + e) * 72 + dr];
            uint4 o = make_uint4((unsigned)v[0] | ((unsigned)v[1] << 16),
                                 (unsigned)v[2] | ((unsigned)v[3] << 16),
                                 (unsigned)v[4] | ((unsigned)v[5] << 16),
                                 (unsigned)v[6] | ((unsigned)v[7] << 16));
            *reinterpret_cast<uint4*>(Vt + ((size_t)((b * 8 + h) * 64 + dh)) * 512 + n) = o;
        }
    }
}

// ---------------- qp (MFMA): Q(bh,n,64) @ pos_k^T -> QP bf16 (bh,n,128pad)
__global__ __launch_bounds__(256) void k_qposm(
    const u16* __restrict__ Qb, const u16* __restrict__ pos_kb, u16* __restrict__ QP)
{
    __shared__ __align__(16) u16 sh[18432];
    u16* As = sh; u16* Bs = sh + 9216;
    const int t = threadIdx.x, lane = t & 63, wave = t >> 6;
    const int lg = lane >> 4, ln16 = lane & 15;
    const int n0 = blockIdx.x * 128, bh = blockIdx.y;
#pragma unroll
    for (int u = 0; u < 4; ++u) {
        const int chunk = u * 256 + t, row = chunk >> 3, ko = (chunk & 7) * 8;
        *reinterpret_cast<uint4*>(As + row * 72 + ko) =
            *reinterpret_cast<const uint4*>(Qb + ((size_t)(bh * 512 + n0 + row)) * 64 + ko);
        *reinterpret_cast<uint4*>(Bs + row * 72 + ko) =
            *reinterpret_cast<const uint4*>(pos_kb + (size_t)row * 64 + ko);
    }
    __syncthreads();
    f32x4 acc[2][8] = {};
#pragma unroll
    for (int kk = 0; kk < 64; kk += 32) {
        short8v a[2], bfr[8];
#pragma unroll
        for (int mi = 0; mi < 2; ++mi)
            a[mi] = *reinterpret_cast<const short8v*>(As + (wave * 32 + mi * 16 + ln16) * 72 + kk + lg * 8);
#pragma unroll
        for (int ni = 0; ni < 8; ++ni)
            bfr[ni] = *reinterpret_cast<const short8v*>(Bs + (ni * 16 + ln16) * 72 + kk + lg * 8);
#pragma unroll
        for (int mi = 0; mi < 2; ++mi)
#pragma unroll
            for (int ni = 0; ni < 8; ++ni)
                acc[mi][ni] = __builtin_amdgcn_mfma_f32_16x16x32_bf16(a[mi], bfr[ni], acc[mi][ni], 0, 0, 0);
    }
    __syncthreads();
    u16* Cs = sh + wave * 4352;                      // 32x136 per wave
#pragma unroll
    for (int mi = 0; mi < 2; ++mi)
#pragma unroll
        for (int ni = 0; ni < 8; ++ni)
#pragma unroll
            for (int r = 0; r < 4; ++r)
                Cs[(mi * 16 + lg * 4 + r) * 136 + ni * 16 + ln16] = f2bf(acc[mi][ni][r]);
#pragma unroll
    for (int j = 0; j < 8; ++j) {
        const int chunk = j * 64 + lane, row = chunk >> 4, co = (chunk & 15) * 8;
        *reinterpret_cast<uint4*>(QP + ((size_t)(bh * 512 + n0 + wave * 32 + row)) * 128 + co) =
            *reinterpret_cast<const uint4*>(Cs + row * 136 + co);
    }
}

// ---------------- scores (MFMA, swapped operands): (Q@K^T + QP[rel]) / 8 -> S bf16 (bh,n,m)
// 1-D grid 1024, batch->XCD affine: bid = b + 8*(h + 8*(mx + 4*my))
__global__ __launch_bounds__(256) void k_scoresm(
    const u16* __restrict__ Qb, const u16* __restrict__ Kb, const u16* __restrict__ QP,
    u16* __restrict__ S)
{
    __shared__ __align__(16) u16 sh[18432];
    u16* As = sh; u16* Bs = sh + 9216;
    const int t = threadIdx.x, lane = t & 63, wave = t >> 6;
    const int wm = wave >> 1, wn = wave & 1;
    const int lg = lane >> 4, ln16 = lane & 15;
    const int bid = blockIdx.x;
    const int bb = bid & 7;
    const int rest = bid >> 3;
    const int h = rest & 7;
    const int tile = rest >> 3;
    const int mx = tile & 3, my = tile >> 2;
    const int bh = bb * 8 + h;
    const int m0 = mx * 128, n0 = my * 128;
#pragma unroll
    for (int u = 0; u < 4; ++u) {
        const int chunk = u * 256 + t, row = chunk >> 3, ko = (chunk & 7) * 8;
        *reinterpret_cast<uint4*>(As + row * 72 + ko) =
            *reinterpret_cast<const uint4*>(Qb + ((size_t)(bh * 512 + n0 + row)) * 64 + ko);
        *reinterpret_cast<uint4*>(Bs + row * 72 + ko) =
            *reinterpret_cast<const uint4*>(Kb + ((size_t)(bh * 512 + m0 + row)) * 64 + ko);
    }
    __syncthreads();
    f32x4 acc[4][4] = {};
#pragma unroll
    for (int kk = 0; kk < 64; kk += 32) {
        short8v a[4], bfr[4];
#pragma unroll
        for (int mi = 0; mi < 4; ++mi)
            a[mi] = *reinterpret_cast<const short8v*>(As + (wm * 64 + mi * 16 + ln16) * 72 + kk + lg * 8);
#pragma unroll
        for (int ni = 0; ni < 4; ++ni)
            bfr[ni] = *reinterpret_cast<const short8v*>(Bs + (wn * 64 + ni * 16 + ln16) * 72 + kk + lg * 8);
        // swapped: A=K (rows=m), B=Q (cols=n) -> lane holds fixed n, 4 consecutive m per reg
#pragma unroll
        for (int mi = 0; mi < 4; ++mi)
#pragma unroll
            for (int ni = 0; ni < 4; ++ni)
                acc[mi][ni] = __builtin_amdgcn_mfma_f32_16x16x32_bf16(bfr[ni], a[mi], acc[mi][ni], 0, 0, 0);
    }
    __syncthreads();
    u16* QPs = sh;                                   // 128 rows x 136 stride bf16
#pragma unroll
    for (int u = 0; u < 8; ++u) {
        const int chunk = u * 256 + t, row = chunk >> 4, co = (chunk & 15) * 8;
        *reinterpret_cast<uint4*>(QPs + row * 136 + co) =
            *reinterpret_cast<const uint4*>(QP + ((size_t)(bh * 512 + n0 + row)) * 128 + co);
    }
    __syncthreads();
#pragma unroll
    for (int mi = 0; mi < 4; ++mi) {
        const int n_loc = wm * 64 + mi * 16 + ln16;
        const int n_g = n0 + n_loc;
#pragma unroll
        for (int ni = 0; ni < 4; ++ni) {
            const int mb = m0 + wn * 64 + ni * 16 + lg * 4;
            float v[4];
#pragma unroll
            for (int r = 0; r < 4; ++r) {
                int rel = (mb + r) - n_g;
                rel = rel < -PC_ ? -PC_ : (rel > PC_ ? PC_ : rel);
                v[r] = (acc[mi][ni][r] + bf2f(QPs[n_loc * 136 + rel + PC_])) * 0.125f;
            }
            *reinterpret_cast<uint2*>(&S[(size_t)bh * 262144 + (size_t)n_g * 512 + mb]) =
                make_uint2(pk2(v[0], v[1]), pk2(v[2], v[3]));
        }
    }
}

// ---------------- conv1 (MFMA, swapped operands): S bf16 planar -> Y ch-last + fused stats
// 1-D grid 2048, batch->XCD affine, x-fastest band sweep: bid = b + 8*(mx + 16*my)
__global__ __launch_bounds__(256) void k_conv1m(
    const u16* __restrict__ S, const u16* __restrict__ Wf,
    const float* __restrict__ bias, u16* __restrict__ Y,
    const int* __restrict__ VL, float* __restrict__ ST)
{
    __shared__ __align__(16) u16 xs[10368];
    __shared__ float wred[4][4][8];     // [wave][lg][s:0..3, s2:4..7]
    const int t = threadIdx.x;
    const int bid = blockIdx.x;
    const int b = bid & 7;
    const int rest = bid >> 3;
    const int m0 = (rest & 15) * 32;
    const int n0 = (rest >> 4) * 32;
    const u16* sp0 = S + (size_t)(b * 8) * 262144;
    // paired-pixel staging: 648 pairs; width 36 even + m0 even => pair shares validity/alignment
    for (int p = t; p < 648; p += 256) {
        const int idx2 = p * 2;
        const int r = idx2 / 36, c = idx2 - r * 36;
        const int gn = n0 - 2 + r, gm = m0 - 2 + c;
        uint4 o0 = make_uint4(0, 0, 0, 0), o1 = o0;
        if ((unsigned)gn < 512u && (unsigned)gm < 512u) {
            const u16* pp = sp0 + (size_t)gn * 512 + gm;
            unsigned u[8];
#pragma unroll
            for (int e = 0; e < 8; ++e)
                u[e] = *reinterpret_cast<const unsigned*>(pp + (size_t)e * 262144);
            o0 = make_uint4((u[0] & 0xffffu) | ((u[1] & 0xffffu) << 16),
                            (u[2] & 0xffffu) | ((u[3] & 0xffffu) << 16),
                            (u[4] & 0xffffu) | ((u[5] & 0xffffu) << 16),
                            (u[6] & 0xffffu) | ((u[7] & 0xffffu) << 16));
            o1 = make_uint4((u[0] >> 16) | (u[1] & 0xffff0000u),
                            (u[2] >> 16) | (u[3] & 0xffff0000u),
                            (u[4] >> 16) | (u[5] & 0xffff0000u),
                            (u[6] >> 16) | (u[7] & 0xffff0000u));
        }
        *reinterpret_cast<uint4*>(&xs[idx2 * 8]) = o0;
        *reinterpret_cast<uint4*>(&xs[(idx2 + 1) * 8]) = o1;
    }
    const int lane = t & 63, wave = t >> 6;
    const int lg = lane >> 4, ln16 = lane & 15;
    short8v bq[7];
#pragma unroll
    for (int q = 0; q < 7; ++q)
        bq[q] = *reinterpret_cast<const short8v*>(&Wf[(q * 64 + lane) * 8]);
    int aoff[7];
#pragma unroll
    for (int q = 0; q < 7; ++q) {
        const int G = q * 4 + lg; const int p = (G < 25) ? G : 0;
        const int dn = p / 5, dm = p - dn * 5;
        aoff[q] = (dn * 36 + dm) * 8;
    }
    const float4 b4 = *reinterpret_cast<const float4*>(&bias[lg * 4]);   // channels lg*4..+3
    const int vl = VL[b];
    f32x4 sstv = {0.f, 0.f, 0.f, 0.f}, sst2v = {0.f, 0.f, 0.f, 0.f};
    __syncthreads();
    for (int i = 0; i < 16; ++i) {
        const int j = wave * 16 + i;
        const int tr = j >> 1, c0 = (j & 1) << 4;
        const int pb = (tr * 36 + c0 + ln16) * 8;
        f32x4 acc = {b4.x, b4.y, b4.z, b4.w};
#pragma unroll
        for (int q = 0; q < 7; ++q) {
            short8v a = *reinterpret_cast<const short8v*>(&xs[pb + aoff[q]]);
            // swapped: A=weights(channels as M), B=pixels(as N) -> lane=pixel, regs=4 channels
            acc = __builtin_amdgcn_mfma_f32_16x16x32_bf16(bq[q], a, acc, 0, 0, 0);
        }
        // lane = pixel (c0+ln16), regs = channels lg*4+r -> coalesced uint2 store (512B/wave)
        u16* yb = Y + (((size_t)(b * 512 + n0 + tr)) * 512 + (m0 + c0 + ln16)) * 16 + lg * 4;
        *reinterpret_cast<uint2*>(yb) = make_uint2(pk2(acc[0], acc[1]), pk2(acc[2], acc[3]));
        if (n0 + tr < vl) {
            sstv += acc;
            sst2v += acc * acc;
        }
    }
#pragma unroll
    for (int o = 1; o < 16; o <<= 1) {
#pragma unroll
        for (int r = 0; r < 4; ++r) {
            sstv[r]  += __shfl_xor(sstv[r], o);
            sst2v[r] += __shfl_xor(sst2v[r], o);
        }
    }
    if (ln16 == 0) {
#pragma unroll
        for (int r = 0; r < 4; ++r) {
            wred[wave][lg][r]     = sstv[r];
            wred[wave][lg][4 + r] = sst2v[r];
        }
    }
    __syncthreads();
    if (t < 16) {
        const int lgg = t >> 2, r = t & 3;
        const float a  = wred[0][lgg][r] + wred[1][lgg][r] + wred[2][lgg][r] + wred[3][lgg][r];
        const float b2 = wred[0][lgg][4 + r] + wred[1][lgg][4 + r] + wred[2][lgg][4 + r] + wred[3][lgg][4 + r];
        atomicAdd(&ST[(b * 16 + t) * 2 + 0], a);
        atomicAdd(&ST[(b * 16 + t) * 2 + 1], b2);
    }
}

// ---------------- conv2 (MFMA): Y ch-last bf16, statfin + norm+relu fused -> S2 bf16 planar
// + online-softmax partials (max, sumexp) per (b,h,row,32-m-tile) into PS
// 1-D grid 2048, batch->XCD affine, x-fastest band sweep
__global__ __launch_bounds__(256) void k_conv2m(
    const u16* __restrict__ Y, const float* __restrict__ ST,
    const int* __restrict__ VL, const float* __restrict__ n1g, const float* __restrict__ n1b,
    const u16* __restrict__ Wf, const float* __restrict__ bias,
    u16* __restrict__ S2, float2* __restrict__ PS)
{
    __shared__ __align__(16) u16 xs[20736];
    __shared__ float ssh[16][2];
    const int t = threadIdx.x;
    const int bid = blockIdx.x;
    const int b = bid & 7;
    const int rest = bid >> 3;
    const int m0 = (rest & 15) * 32;
    const int n0 = (rest >> 4) * 32;
    const int vl = VL[b];
    if (t < 16) {                       // folded statfin (redundant per block, trivial)
        const float sw = (float)vl * 512.f;
        const float mean = ST[(b * 16 + t) * 2 + 0] / sw;
        const float var  = ST[(b * 16 + t) * 2 + 1] / sw - mean * mean;
        const float sc = n1g[t] * rsqrtf(var + 1e-7f);
        ssh[t][0] = sc;
        ssh[t][1] = n1b[t] - mean * sc;
    }
    __syncthreads();
    float sc[16], shv[16];
#pragma unroll
    for (int ch = 0; ch < 16; ++ch) { sc[ch] = ssh[ch][0]; shv[ch] = ssh[ch][1]; }
    for (int idx = t; idx < 1296; idx += 256) {
        const int r = idx / 36; const int c = idx - r * 36;
        const int gn = n0 - 2 + r, gm = m0 - 2 + c;
        uint4 p0 = make_uint4(0, 0, 0, 0), p1 = p0;
        if ((unsigned)gn < 512u && (unsigned)gm < 512u) {
            const u16* yp = Y + (((size_t)(b * 512 + gn)) * 512 + gm) * 16;
            const uint4 r0 = *reinterpret_cast<const uint4*>(yp);
            const uint4 r1 = *reinterpret_cast<const uint4*>(yp + 8);
            const unsigned w0[4] = {r0.x, r0.y, r0.z, r0.w};
            const unsigned w1[4] = {r1.x, r1.y, r1.z, r1.w};
            unsigned o0[4], o1[4];
#pragma unroll
            for (int u2 = 0; u2 < 4; ++u2) {
                const int ch = u2 * 2;
                float a0 = bf2f((u16)(w0[u2] & 0xffff));
                float a1 = bf2f((u16)(w0[u2] >> 16));
                a0 = fmaf(a0, sc[ch], shv[ch]);          a0 = a0 > 0.f ? a0 : 0.f;
                a1 = fmaf(a1, sc[ch + 1], shv[ch + 1]);  a1 = a1 > 0.f ? a1 : 0.f;
                o0[u2] = pk2(a0, a1);
                const int ch2 = 8 + u2 * 2;
                float b0 = bf2f((u16)(w1[u2] & 0xffff));
                float b1 = bf2f((u16)(w1[u2] >> 16));
                b0 = fmaf(b0, sc[ch2], shv[ch2]);          b0 = b0 > 0.f ? b0 : 0.f;
                b1 = fmaf(b1, sc[ch2 + 1], shv[ch2 + 1]);  b1 = b1 > 0.f ? b1 : 0.f;
                o1[u2] = pk2(b0, b1);
            }
            p0 = make_uint4(o0[0], o0[1], o0[2], o0[3]);
            p1 = make_uint4(o1[0], o1[1], o1[2], o1[3]);
        }
        *reinterpret_cast<uint4*>(&xs[idx * 8]) = p0;
        *reinterpret_cast<uint4*>(&xs[10368 + idx * 8]) = p1;
    }
    const int lane = t & 63, wave = t >> 6;
    const int lg = lane >> 4, ln16 = lane & 15;
    short8v bq[13];
#pragma unroll
    for (int q = 0; q < 13; ++q)
        bq[q] = *reinterpret_cast<const short8v*>(&Wf[(q * 64 + lane) * 8]);
    int aoff[13];
#pragma unroll
    for (int q = 0; q < 13; ++q) {
        const int G = q * 4 + lg; const int p = (G < 50) ? G : 0;
        const int pos = p >> 1, h = p & 1;
        const int dn = pos / 5, dm = pos - dn * 5;
        aoff[q] = h * 10368 + (dn * 36 + dm) * 8;
    }
    const float bs = (ln16 < 8) ? bias[ln16] : 0.f;
    __syncthreads();
    for (int ip = 0; ip < 8; ++ip) {
        const int tr = wave * 8 + ip;
        float xv[8];
#pragma unroll
        for (int half = 0; half < 2; ++half) {
            const int c0 = half << 4;
            const int pb = (tr * 36 + c0 + ln16) * 8;
            f32x4 acc = {bs, bs, bs, bs};
#pragma unroll
            for (int q = 0; q < 13; ++q) {
                short8v a = *reinterpret_cast<const short8v*>(&xs[pb + aoff[q]]);
                acc = __builtin_amdgcn_mfma_f32_16x16x32_bf16(a, bq[q], acc, 0, 0, 0);
            }
            if (ln16 < 8) {
                uint2 o = make_uint2(pk2(acc[0], acc[1]), pk2(acc[2], acc[3]));
                *reinterpret_cast<uint2*>(
                    &S2[(((size_t)(b * 8 + ln16)) * 512 + n0 + tr) * 512 + m0 + c0 + lg * 4]) = o;
            }
#pragma unroll
            for (int r = 0; r < 4; ++r) {
                const int m = m0 + c0 + lg * 4 + r;
                xv[half * 4 + r] = (m < vl) ? acc[r] : -3.0e38f;
            }
        }
        // per-(ch,row) online partial over this block's 32 m values
        float mxr = xv[0];
#pragma unroll
        for (int r8 = 1; r8 < 8; ++r8) mxr = fmaxf(mxr, xv[r8]);
        mxr = fmaxf(mxr, __shfl_xor(mxr, 16));
        mxr = fmaxf(mxr, __shfl_xor(mxr, 32));
        float smr = 0.f;
#pragma unroll
        for (int r8 = 0; r8 < 8; ++r8) {
            const int m = m0 + ((r8 >> 2) << 4) + lg * 4 + (r8 & 3);
            smr += (m < vl) ? __expf(xv[r8] - mxr) : 0.f;
        }
        smr += __shfl_xor(smr, 16);
        smr += __shfl_xor(smr, 32);
        if (lg == 0 && ln16 < 8)
            PS[((size_t)(b * 8 + ln16) * 512 + n0 + tr) * 16 + (m0 >> 5)] = make_float2(mxr, smr);
    }
}

// ---------------- fused masked softmax (from PS partials) + A@V: logits bf16 -> X2 bf16
// 1-D grid 512, batch->XCD affine: bid = b + 8*(nx + 8*h)
__global__ __launch_bounds__(256) void k_softav(
    const u16* __restrict__ SL, const u16* __restrict__ Vt,
    const int* __restrict__ VL, const float2* __restrict__ PS, u16* __restrict__ X2)
{
    __shared__ __align__(16) u16 As[4608];   // 64x72
    __shared__ __align__(16) u16 Bs[4608];   // 64x72
    __shared__ float smx[64], siv[64];
    const int t = threadIdx.x, lane = t & 63, wave = t >> 6;
    const int lg = lane >> 4, ln16 = lane & 15;
    const int bid = blockIdx.x;
    const int b = bid & 7;
    const int rest = bid >> 3;
    const int nx = rest & 7;
    const int h = rest >> 3;
    const int n0 = nx * 64;
    const int bh = b * 8 + h;
    const int vl = VL[b];
    const u16* Sp = SL + (size_t)bh * 262144;
    if (t < 64) {
        const float* pp = reinterpret_cast<const float*>(PS) + ((size_t)bh * 512 + n0 + t) * 32;
        float mxv[16], smv[16];
#pragma unroll
        for (int i = 0; i < 8; ++i) {
            float4 v = *reinterpret_cast<const float4*>(pp + i * 4);
            mxv[i * 2]     = v.x; smv[i * 2]     = v.y;
            mxv[i * 2 + 1] = v.z; smv[i * 2 + 1] = v.w;
        }
        float M = mxv[0];
#pragma unroll
        for (int i = 1; i < 16; ++i) M = fmaxf(M, mxv[i]);
        float Ssum = 0.f;
#pragma unroll
        for (int i = 0; i < 16; ++i) Ssum += smv[i] * __expf(mxv[i] - M);
        smx[t] = M; siv[t] = 1.0f / Ssum;
    }
    __syncthreads();
    f32x4 acc[4] = {};
    for (int k0 = 0; k0 < 512; k0 += 64) {
#pragma unroll
        for (int u = 0; u < 2; ++u) {
            const int chunk = u * 256 + t, row = chunk >> 3, ko = (chunk & 7) * 8;
            uint4 raw = *reinterpret_cast<const uint4*>(Sp + (size_t)(n0 + row) * 512 + k0 + ko);
            const unsigned w[4] = {raw.x, raw.y, raw.z, raw.w};
            const float mxr = smx[row], ivr = siv[row];
            unsigned o[4];
#pragma unroll
            for (int jj = 0; jj < 4; ++jj) {
                const int m0i = k0 + ko + 2 * jj;
                float a0 = (m0i     < vl) ? __expf(bf2f((u16)(w[jj] & 0xffff)) - mxr) * ivr : 0.f;
                float a1 = (m0i + 1 < vl) ? __expf(bf2f((u16)(w[jj] >> 16))   - mxr) * ivr : 0.f;
                o[jj] = pk2(a0, a1);
            }
            *reinterpret_cast<uint4*>(As + row * 72 + ko) = make_uint4(o[0], o[1], o[2], o[3]);
            *reinterpret_cast<uint4*>(Bs + row * 72 + ko) =
                *reinterpret_cast<const uint4*>(Vt + ((size_t)(bh * 64 + row)) * 512 + k0 + ko);
        }
        __syncthreads();
#pragma unroll
        for (int kk = 0; kk < 64; kk += 32) {
            short8v a = *reinterpret_cast<const short8v*>(As + (wave * 16 + ln16) * 72 + kk + lg * 8);
#pragma unroll
            for (int ni = 0; ni < 4; ++ni) {
                short8v bfr = *reinterpret_cast<const short8v*>(Bs + (ni * 16 + ln16) * 72 + kk + lg * 8);
                acc[ni] = __builtin_amdgcn_mfma_f32_16x16x32_bf16(a, bfr, acc[ni], 0, 0, 0);
            }
        }
        __syncthreads();
    }
    u16* Cs = As + wave * 1152;                      // 16x72 per wave
#pragma unroll
    for (int ni = 0; ni < 4; ++ni)
#pragma unroll
        for (int r = 0; r < 4; ++r)
            Cs[(lg * 4 + r) * 72 + ni * 16 + ln16] = f2bf(acc[ni][r]);
#pragma unroll
    for (int j = 0; j < 2; ++j) {
        const int chunk = j * 64 + lane, row = chunk >> 3, co = (chunk & 7) * 8;
        const int tn = n0 + wave * 16 + row;
        *reinterpret_cast<uint4*>(X2 + ((size_t)(b * 512 + tn)) * 512 + h * 64 + co) =
            *reinterpret_cast<const uint4*>(Cs + row * 72 + co);
    }
}

// ---------------- out-proj (MFMA): X2 @ WhT + bh + query -> P f32
__global__ __launch_bounds__(256) void k_outm(
    const u16* __restrict__ X2, const u16* __restrict__ WT, const float* __restrict__ bias,
    const float* __restrict__ Xq, float* __restrict__ Pout)
{
    __shared__ __align__(16) u16 sh[18432];
    u16* As = sh; u16* Bs = sh + 9216;
    const int t = threadIdx.x, lane = t & 63, wave = t >> 6;
    const int wm = wave >> 1, wn = wave & 1;
    const int lg = lane >> 4, ln16 = lane & 15;
    const int m0 = blockIdx.x * 128, n0 = blockIdx.y * 128;
    f32x4 acc[4][4] = {};
    for (int k0 = 0; k0 < 512; k0 += 64) {
#pragma unroll
        for (int u = 0; u < 4; ++u) {
            const int chunk = u * 256 + t, row = chunk >> 3, ko = (chunk & 7) * 8;
            *reinterpret_cast<uint4*>(As + row * 72 + ko) =
                *reinterpret_cast<const uint4*>(X2 + (size_t)(m0 + row) * 512 + k0 + ko);
            *reinterpret_cast<uint4*>(Bs + row * 72 + ko) =
                *reinterpret_cast<const uint4*>(WT + (size_t)(n0 + row) * 512 + k0 + ko);
        }
        __syncthreads();
#pragma unroll
        for (int kk = 0; kk < 64; kk += 32) {
            short8v a[4], bfr[4];
#pragma unroll
            for (int mi = 0; mi < 4; ++mi)
                a[mi] = *reinterpret_cast<const short8v*>(As + (wm * 64 + mi * 16 + ln16) * 72 + kk + lg * 8);
#pragma unroll
            for (int ni = 0; ni < 4; ++ni)
                bfr[ni] = *reinterpret_cast<const short8v*>(Bs + (wn * 64 + ni * 16 + ln16) * 72 + kk + lg * 8);
#pragma unroll
            for (int mi = 0; mi < 4; ++mi)
#pragma unroll
                for (int ni = 0; ni < 4; ++ni)
                    acc[mi][ni] = __builtin_amdgcn_mfma_f32_16x16x32_bf16(a[mi], bfr[ni], acc[mi][ni], 0, 0, 0);
        }
        __syncthreads();
    }
#pragma unroll
    for (int ni = 0; ni < 4; ++ni) {
        const int cg = n0 + wn * 64 + ni * 16 + ln16;
        const float bv = bias[cg];
#pragma unroll
        for (int mi = 0; mi < 4; ++mi)
#pragma unroll
            for (int r = 0; r < 4; ++r) {
                const int tok = m0 + wm * 64 + mi * 16 + lg * 4 + r;
                Pout[(size_t)tok * 512 + cg] = acc[mi][ni][r] + bv + Xq[(size_t)tok * 512 + cg];
            }
    }
}

// ---------------- final LayerNorm over D=512
__global__ __launch_bounds__(256) void k_ln(
    const float* __restrict__ P, const float* __restrict__ g,
    const float* __restrict__ be, float* __restrict__ out)
{
    const int row = blockIdx.x * 4 + (threadIdx.x >> 6);
    const int lane = threadIdx.x & 63;
    const float* p = P + (size_t)row * 512;
    float4 v0 = reinterpret_cast<const float4*>(p)[lane];
    float4 v1 = reinterpret_cast<const float4*>(p)[64 + lane];
    float s = v0.x + v0.y + v0.z + v0.w + v1.x + v1.y + v1.z + v1.w;
#pragma unroll
    for (int o = 32; o; o >>= 1) s += __shfl_xor(s, o);
    const float mean = s * (1.0f / 512.0f);
    float d[8] = {v0.x - mean, v0.y - mean, v0.z - mean, v0.w - mean,
                  v1.x - mean, v1.y - mean, v1.z - mean, v1.w - mean};
    float s2 = 0.f;
#pragma unroll
    for (int j = 0; j < 8; ++j) s2 += d[j] * d[j];
#pragma unroll
    for (int o = 32; o; o >>= 1) s2 += __shfl_xor(s2, o);
    const float rstd = rsqrtf(s2 * (1.0f / 512.0f) + 1e-7f);
    float4 g0 = reinterpret_cast<const float4*>(g)[lane];
    float4 g1 = reinterpret_cast<const float4*>(g)[64 + lane];
    float4 b0 = reinterpret_cast<const float4*>(be)[lane];
    float4 b1 = reinterpret_cast<const float4*>(be)[64 + lane];
    float* op = out + (size_t)row * 512;
    reinterpret_cast<float4*>(op)[lane] =
        make_float4(d[0] * rstd * g0.x + b0.x, d[1] * rstd * g0.y + b0.y,
                    d[2] * rstd * g0.z + b0.z, d[3] * rstd * g0.w + b0.w);
    reinterpret_cast<float4*>(op)[64 + lane] =
        make_float4(d[4] * rstd * g1.x + b1.x, d[5] * rstd * g1.y + b1.y,
                    d[6] * rstd * g1.z + b1.z, d[7] * rstd * g1.w + b1.w);
}

extern "C" void kernel_launch(void* const* d_in, const int* in_sizes, int n_in,
                              void* d_out, int out_size, void* d_ws, size_t ws_size,
                              hipStream_t stream)
{
    const float* query = (const float*)d_in[0];
    const int*   VL    = (const int*)d_in[1];
    const float* Wq = (const float*)d_in[2];  const float* bq = (const float*)d_in[3];
    const float* Wk = (const float*)d_in[4];  const float* bk = (const float*)d_in[5];
    const float* Wv = (const float*)d_in[6];  const float* bv = (const float*)d_in[7];
    const float* Wh = (const float*)d_in[8];  const float* bh = (const float*)d_in[9];
    const float* pos_k = (const float*)d_in[10];
    const float* c1w = (const float*)d_in[11]; const float* c1b = (const float*)d_in[12];
    const float* n1g = (const float*)d_in[13]; const float* n1b = (const float*)d_in[14];
    const float* c2w = (const float*)d_in[15]; const float* c2b = (const float*)d_in[16];
    const float* lng = (const float*)d_in[17]; const float* lnb = (const float*)d_in[18];

    float* ws = (float*)d_ws;
    const size_t M1 = (size_t)1 << 20;
    u16* S1  = (u16*)ws;
    u16* Y1  = (u16*)(ws + 8 * M1);
    u16* Xb  = (u16*)(ws + 24 * M1);
    u16* Qb  = (u16*)(ws + 25 * M1);
    u16* Kb  = (u16*)(ws + 26 * M1);
    u16* Vt  = (u16*)(ws + 27 * M1);
    u16* QPb = (u16*)(ws + 28 * M1);
    u16* WqT = (u16*)(ws + 30 * M1);
    u16* WkT = WqT + 262144;
    u16* WvT = WkT + 262144;
    u16* WhT = WvT + 262144;
    u16* pos_kb = (u16*)(ws + 30 * M1 + 524288);
    u16* Wf1 = pos_kb + 8192;
    u16* Wf2 = Wf1 + 3584;
    float* ST  = ws + 31 * M1;
    float2* PS = (float2*)(ws + 31 * M1 + 512);      // (B,H,512,16) x (max,sumexp) = 4 MB
    u16* X2 = Xb;
    float* Pout = ws + 28 * M1;

    hipMemsetAsync(ST, 0, 256 * sizeof(float), stream);

    k_prept<<<dim3(8, 8, 6), 256, 0, stream>>>(Wq, Wk, Wv, Wh, WqT, WkT, WvT, WhT,
                                               c1w, c2w, pos_k, Wf1, Wf2, pos_kb,
                                               query, Xb);
    k_qkvm<<<dim3(32, 4, 3), 256, 0, stream>>>(Xb, WqT, WkT, WvT, bq, bk, bv, Qb, Kb, Vt);
    k_qposm<<<dim3(4, 64), 256, 0, stream>>>(Qb, pos_kb, QPb);
    k_scoresm<<<1024, 256, 0, stream>>>(Qb, Kb, QPb, S1);
    k_conv1m<<<2048, 256, 0, stream>>>(S1, Wf1, c1b, Y1, VL, ST);
    k_conv2m<<<2048, 256, 0, stream>>>(Y1, ST, VL, n1g, n1b, Wf2, c2b, S1, PS);
    k_softav<<<512, 256, 0, stream>>>(S1, Vt, VL, PS, X2);
    k_outm<<<dim3(32, 4), 256, 0, stream>>>(X2, WhT, bh, query, Pout);
    k_ln<<<1024, 256, 0, stream>>>(Pout, lng, lnb, (float*)d_out);
}

// Round 10
// 248.331 us; speedup vs baseline: 1.3132x; 1.0279x over previous
//
#include <hip/hip_runtime.h>

#define PC_ 60

typedef unsigned short u16;
typedef unsigned char u8;
typedef __attribute__((ext_vector_type(8))) short short8v;   // 8 bf16 (4 VGPR)
typedef __attribute__((ext_vector_type(4))) float f32x4;
typedef __attribute__((ext_vector_type(2))) float f32x2;

__device__ inline float bf2f(u16 u) {
    union { unsigned int i; float f; } x; x.i = ((unsigned)u) << 16; return x.f;
}
__device__ inline u16 f2bf(float f) {
    union { float f; unsigned int i; } x; x.f = f;
    unsigned int r = x.i + 0x7fff + ((x.i >> 16) & 1);   // RNE
    return (u16)(r >> 16);
}
__device__ inline unsigned pk2(float a, float b) {       // RNE pack (prep only)
    return (unsigned)f2bf(a) | ((unsigned)f2bf(b) << 16);
}
__device__ inline unsigned pkt2(float a, float b) {      // truncating pack (2 VALU)
    union { float f; unsigned u; } x, y; x.f = a; y.f = b;
    return (x.u >> 16) | (y.u & 0xffff0000u);
}
__device__ inline u16 f2bft(float f) {
    union { float f; unsigned u; } x; x.f = f; return (u16)(x.u >> 16);
}
__device__ inline unsigned pk4fp8(f32x4 a) {             // 4 f32 -> 4 fp8 e4m3 (2 VALU)
    int w = __builtin_amdgcn_cvt_pk_fp8_f32(a[0], a[1], 0, false);
    w = __builtin_amdgcn_cvt_pk_fp8_f32(a[2], a[3], w, true);
    return (unsigned)w;
}

// ---------------- prep: W transposes (z<4) + conv-frag/pos (z==4) + query->bf16 (z==5)
__global__ __launch_bounds__(256) void k_prept(
    const float* __restrict__ W0, const float* __restrict__ W1,
    const float* __restrict__ W2, const float* __restrict__ W3,
    u16* __restrict__ T0, u16* __restrict__ T1, u16* __restrict__ T2, u16* __restrict__ T3,
    const float* __restrict__ c1w, const float* __restrict__ c2w,
    const float* __restrict__ pos_k,
    u16* __restrict__ Wf1, u16* __restrict__ Wf2, u16* __restrict__ pos_kb,
    const float* __restrict__ X, u16* __restrict__ Xb)
{
    const int z = blockIdx.z;
    const int t = threadIdx.x;
    if (z == 5) {
        const int blk = blockIdx.y * 8 + blockIdx.x;
#pragma unroll
        for (int k2 = 0; k2 < 16; ++k2) {
            const int i = ((blk * 16 + k2) * 256 + t) * 8;
            float4 a = *reinterpret_cast<const float4*>(X + i);
            float4 b = *reinterpret_cast<const float4*>(X + i + 4);
            *reinterpret_cast<uint4*>(Xb + i) =
                make_uint4(pk2(a.x, a.y), pk2(a.z, a.w), pk2(b.x, b.y), pk2(b.z, b.w));
        }
        return;
    }
    if (z == 4) {
        if (blockIdx.x != 0 || blockIdx.y != 0) return;
        for (int s = t; s < 448; s += 256) {
            const int q = s >> 6, l = s & 63, lg = l >> 4, n = l & 15;
            const int G = q * 4 + lg;
            unsigned o[4];
#pragma unroll
            for (int u2 = 0; u2 < 4; ++u2) {
                float v0 = 0.f, v1 = 0.f;
                if (G < 25) {
                    const int dn = G / 5, dm = G - dn * 5;
                    v0 = c1w[((dn * 5 + dm) * 8 + u2 * 2 + 0) * 16 + n];
                    v1 = c1w[((dn * 5 + dm) * 8 + u2 * 2 + 1) * 16 + n];
                }
                o[u2] = pk2(v0, v1);
            }
            *reinterpret_cast<uint4*>(&Wf1[s * 8]) = make_uint4(o[0], o[1], o[2], o[3]);
        }
        for (int s = t; s < 832; s += 256) {
            const int q = s >> 6, l = s & 63, lg = l >> 4, n = l & 15;
            const int G = q * 4 + lg;
            unsigned o[4];
#pragma unroll
            for (int u2 = 0; u2 < 4; ++u2) {
                float v0 = 0.f, v1 = 0.f;
                if (G < 50 && n < 8) {
                    const int pos = G >> 1, h = G & 1;
                    const int dn = pos / 5, dm = pos - dn * 5;
                    v0 = c2w[((dn * 5 + dm) * 16 + h * 8 + u2 * 2 + 0) * 8 + n];
                    v1 = c2w[((dn * 5 + dm) * 16 + h * 8 + u2 * 2 + 1) * 8 + n];
                }
                o[u2] = pk2(v0, v1);
            }
            *reinterpret_cast<uint4*>(&Wf2[s * 8]) = make_uint4(o[0], o[1], o[2], o[3]);
        }
        for (int s = t; s < 128 * 64; s += 256) {
            const int r = s >> 6;
            pos_kb[s] = (r < 121) ? f2bf(pos_k[s]) : (u16)0;
        }
        return;
    }
    const float* W = (z == 0) ? W0 : (z == 1) ? W1 : (z == 2) ? W2 : W3;
    u16* T        = (z == 0) ? T0 : (z == 1) ? T1 : (z == 2) ? T2 : T3;
    __shared__ float ls[64 * 65];
    const int k0 = blockIdx.x * 64, n0 = blockIdx.y * 64;
#pragma unroll
    for (int i = 0; i < 16; ++i) {
        const int idx = t + i * 256, r = idx >> 6, c = idx & 63;
        ls[c * 65 + r] = W[(size_t)(k0 + r) * 512 + n0 + c];
    }
    __syncthreads();
#pragma unroll
    for (int i = 0; i < 16; ++i) {
        const int idx = t + i * 256, r = idx >> 6, c = idx & 63;
        T[(size_t)(n0 + r) * 512 + k0 + c] = f2bf(ls[r * 65 + c]);
    }
}

// ---------------- QKV (MFMA): Xb @ WT -> Q/K bf16 (B,H,N,DH), V^T bf16 (B,H,DH,N)
__global__ __launch_bounds__(256) void k_qkvm(
    const u16* __restrict__ Xb,
    const u16* __restrict__ WT0, const u16* __restrict__ WT1, const u16* __restrict__ WT2,
    const float* __restrict__ b0, const float* __restrict__ b1, const float* __restrict__ b2,
    u16* __restrict__ Qb, u16* __restrict__ Kb, u16* __restrict__ Vt)
{
    const int z = blockIdx.z;
    const u16* WT    = (z == 0) ? WT0 : (z == 1) ? WT1 : WT2;
    const float* bias = (z == 0) ? b0 : (z == 1) ? b1 : b2;
    __shared__ __align__(16) u16 sh[18432];          // As 128x72, Bs 128x72
    u16* As = sh; u16* Bs = sh + 9216;
    const int t = threadIdx.x, lane = t & 63, wave = t >> 6;
    const int wm = wave >> 1, wn = wave & 1;
    const int lg = lane >> 4, ln16 = lane & 15;
    const int m0 = blockIdx.x * 128, n0 = blockIdx.y * 128;
    f32x4 acc[4][4] = {};
    for (int k0 = 0; k0 < 512; k0 += 64) {
#pragma unroll
        for (int u = 0; u < 4; ++u) {
            const int chunk = u * 256 + t, row = chunk >> 3, ko = (chunk & 7) * 8;
            *reinterpret_cast<uint4*>(As + row * 72 + ko) =
                *reinterpret_cast<const uint4*>(Xb + (size_t)(m0 + row) * 512 + k0 + ko);
            *reinterpret_cast<uint4*>(Bs + row * 72 + ko) =
                *reinterpret_cast<const uint4*>(WT + (size_t)(n0 + row) * 512 + k0 + ko);
        }
        __syncthreads();
#pragma unroll
        for (int kk = 0; kk < 64; kk += 32) {
            short8v a[4], bfr[4];
#pragma unroll
            for (int mi = 0; mi < 4; ++mi)
                a[mi] = *reinterpret_cast<const short8v*>(As + (wm * 64 + mi * 16 + ln16) * 72 + kk + lg * 8);
#pragma unroll
            for (int ni = 0; ni < 4; ++ni)
                bfr[ni] = *reinterpret_cast<const short8v*>(Bs + (wn * 64 + ni * 16 + ln16) * 72 + kk + lg * 8);
#pragma unroll
            for (int mi = 0; mi < 4; ++mi)
#pragma unroll
                for (int ni = 0; ni < 4; ++ni)
                    acc[mi][ni] = __builtin_amdgcn_mfma_f32_16x16x32_bf16(a[mi], bfr[ni], acc[mi][ni], 0, 0, 0);
        }
        __syncthreads();
    }
    u16* Cs = sh + wave * 4608;                       // 64x72 per wave
#pragma unroll
    for (int ni = 0; ni < 4; ++ni) {
        const float bv = bias[n0 + wn * 64 + ni * 16 + ln16];
#pragma unroll
        for (int mi = 0; mi < 4; ++mi)
#pragma unroll
            for (int r = 0; r < 4; ++r)
                Cs[(mi * 16 + lg * 4 + r) * 72 + ni * 16 + ln16] = f2bft(acc[mi][ni][r] + bv);
    }
    if (z < 2) {
        u16* O = (z == 0) ? Qb : Kb;
#pragma unroll
        for (int j = 0; j < 8; ++j) {
            const int chunk = j * 64 + lane, row = chunk >> 3, co = (chunk & 7) * 8;
            const int tok = m0 + wm * 64 + row;
            const int b = tok >> 9, n = tok & 511;
            const int cg = n0 + wn * 64 + co;
            const int h = cg >> 6, dh = cg & 63;
            *reinterpret_cast<uint4*>(O + ((size_t)((b * 8 + h) * 512 + n)) * 64 + dh) =
                *reinterpret_cast<const uint4*>(Cs + row * 72 + co);
        }
    } else {
#pragma unroll
        for (int j = 0; j < 8; ++j) {
            const int chunk = j * 64 + lane, dr = chunk >> 3, no8 = (chunk & 7) * 8;
            const int cg = n0 + wn * 64 + dr;
            const int h = cg >> 6, dh = cg & 63;
            const int tok = m0 + wm * 64 + no8;
            const int b = tok >> 9, n = tok & 511;
            u16 v[8];
#pragma unroll
            for (int e = 0; e < 8; ++e) v[e] = Cs[(no8 + e) * 72 + dr];
            uint4 o = make_uint4((unsigned)v[0] | ((unsigned)v[1] << 16),
                                 (unsigned)v[2] | ((unsigned)v[3] << 16),
                                 (unsigned)v[4] | ((unsigned)v[5] << 16),
                                 (unsigned)v[6] | ((unsigned)v[7] << 16));
            *reinterpret_cast<uint4*>(Vt + ((size_t)((b * 8 + h) * 64 + dh)) * 512 + n) = o;
        }
    }
}

// ---------------- qp (MFMA): Q(bh,n,64) @ pos_k^T -> QP bf16 (bh,n,128pad)
__global__ __launch_bounds__(256) void k_qposm(
    const u16* __restrict__ Qb, const u16* __restrict__ pos_kb, u16* __restrict__ QP)
{
    __shared__ __align__(16) u16 sh[18432];
    u16* As = sh; u16* Bs = sh + 9216;
    const int t = threadIdx.x, lane = t & 63, wave = t >> 6;
    const int lg = lane >> 4, ln16 = lane & 15;
    const int n0 = blockIdx.x * 128, bh = blockIdx.y;
#pragma unroll
    for (int u = 0; u < 4; ++u) {
        const int chunk = u * 256 + t, row = chunk >> 3, ko = (chunk & 7) * 8;
        *reinterpret_cast<uint4*>(As + row * 72 + ko) =
            *reinterpret_cast<const uint4*>(Qb + ((size_t)(bh * 512 + n0 + row)) * 64 + ko);
        *reinterpret_cast<uint4*>(Bs + row * 72 + ko) =
            *reinterpret_cast<const uint4*>(pos_kb + (size_t)row * 64 + ko);
    }
    __syncthreads();
    f32x4 acc[2][8] = {};
#pragma unroll
    for (int kk = 0; kk < 64; kk += 32) {
        short8v a[2], bfr[8];
#pragma unroll
        for (int mi = 0; mi < 2; ++mi)
            a[mi] = *reinterpret_cast<const short8v*>(As + (wave * 32 + mi * 16 + ln16) * 72 + kk + lg * 8);
#pragma unroll
        for (int ni = 0; ni < 8; ++ni)
            bfr[ni] = *reinterpret_cast<const short8v*>(Bs + (ni * 16 + ln16) * 72 + kk + lg * 8);
#pragma unroll
        for (int mi = 0; mi < 2; ++mi)
#pragma unroll
            for (int ni = 0; ni < 8; ++ni)
                acc[mi][ni] = __builtin_amdgcn_mfma_f32_16x16x32_bf16(a[mi], bfr[ni], acc[mi][ni], 0, 0, 0);
    }
    __syncthreads();
    u16* Cs = sh + wave * 4352;                      // 32x136 per wave
#pragma unroll
    for (int mi = 0; mi < 2; ++mi)
#pragma unroll
        for (int ni = 0; ni < 8; ++ni)
#pragma unroll
            for (int r = 0; r < 4; ++r)
                Cs[(mi * 16 + lg * 4 + r) * 136 + ni * 16 + ln16] = f2bft(acc[mi][ni][r]);
#pragma unroll
    for (int j = 0; j < 8; ++j) {
        const int chunk = j * 64 + lane, row = chunk >> 4, co = (chunk & 15) * 8;
        *reinterpret_cast<uint4*>(QP + ((size_t)(bh * 512 + n0 + wave * 32 + row)) * 128 + co) =
            *reinterpret_cast<const uint4*>(Cs + row * 136 + co);
    }
}

// ---------------- scores (MFMA, swapped operands): (Q@K^T + QP[rel]) / 8 -> S bf16 (bh,n,m)
// 1-D grid 1024, batch->XCD affine: bid = b + 8*(h + 8*(mx + 4*my))
__global__ __launch_bounds__(256) void k_scoresm(
    const u16* __restrict__ Qb, const u16* __restrict__ Kb, const u16* __restrict__ QP,
    u16* __restrict__ S)
{
    __shared__ __align__(16) u16 sh[18432];
    u16* As = sh; u16* Bs = sh + 9216;
    const int t = threadIdx.x, lane = t & 63, wave = t >> 6;
    const int wm = wave >> 1, wn = wave & 1;
    const int lg = lane >> 4, ln16 = lane & 15;
    const int bid = blockIdx.x;
    const int bb = bid & 7;
    const int rest = bid >> 3;
    const int h = rest & 7;
    const int tile = rest >> 3;
    const int mx = tile & 3, my = tile >> 2;
    const int bh = bb * 8 + h;
    const int m0 = mx * 128, n0 = my * 128;
#pragma unroll
    for (int u = 0; u < 4; ++u) {
        const int chunk = u * 256 + t, row = chunk >> 3, ko = (chunk & 7) * 8;
        *reinterpret_cast<uint4*>(As + row * 72 + ko) =
            *reinterpret_cast<const uint4*>(Qb + ((size_t)(bh * 512 + n0 + row)) * 64 + ko);
        *reinterpret_cast<uint4*>(Bs + row * 72 + ko) =
            *reinterpret_cast<const uint4*>(Kb + ((size_t)(bh * 512 + m0 + row)) * 64 + ko);
    }
    __syncthreads();
    f32x4 acc[4][4] = {};
#pragma unroll
    for (int kk = 0; kk < 64; kk += 32) {
        short8v a[4], bfr[4];
#pragma unroll
        for (int mi = 0; mi < 4; ++mi)
            a[mi] = *reinterpret_cast<const short8v*>(As + (wm * 64 + mi * 16 + ln16) * 72 + kk + lg * 8);
#pragma unroll
        for (int ni = 0; ni < 4; ++ni)
            bfr[ni] = *reinterpret_cast<const short8v*>(Bs + (wn * 64 + ni * 16 + ln16) * 72 + kk + lg * 8);
        // swapped: A=K (rows=m), B=Q (cols=n) -> lane holds fixed n, 4 consecutive m per reg
#pragma unroll
        for (int mi = 0; mi < 4; ++mi)
#pragma unroll
            for (int ni = 0; ni < 4; ++ni)
                acc[mi][ni] = __builtin_amdgcn_mfma_f32_16x16x32_bf16(bfr[ni], a[mi], acc[mi][ni], 0, 0, 0);
    }
    __syncthreads();
    u16* QPs = sh;                                   // 128 rows x 136 stride bf16
#pragma unroll
    for (int u = 0; u < 8; ++u) {
        const int chunk = u * 256 + t, row = chunk >> 4, co = (chunk & 15) * 8;
        *reinterpret_cast<uint4*>(QPs + row * 136 + co) =
            *reinterpret_cast<const uint4*>(QP + ((size_t)(bh * 512 + n0 + row)) * 128 + co);
    }
    __syncthreads();
#pragma unroll
    for (int mi = 0; mi < 4; ++mi) {
        const int n_loc = wm * 64 + mi * 16 + ln16;
        const int n_g = n0 + n_loc;
#pragma unroll
        for (int ni = 0; ni < 4; ++ni) {
            const int mb = m0 + wn * 64 + ni * 16 + lg * 4;
            float v[4];
#pragma unroll
            for (int r = 0; r < 4; ++r) {
                int rel = (mb + r) - n_g;
                rel = rel < -PC_ ? -PC_ : (rel > PC_ ? PC_ : rel);
                v[r] = (acc[mi][ni][r] + bf2f(QPs[n_loc * 136 + rel + PC_])) * 0.125f;
            }
            *reinterpret_cast<uint2*>(&S[(size_t)bh * 262144 + (size_t)n_g * 512 + mb]) =
                make_uint2(pkt2(v[0], v[1]), pkt2(v[2], v[3]));
        }
    }
}

// ---------------- conv1 (MFMA, swapped operands): S bf16 planar -> Y fp8 ch-last + fused stats
// 1-D grid 2048, batch->XCD affine, x-fastest band sweep: bid = b + 8*(mx + 16*my)
__global__ __launch_bounds__(256) void k_conv1m(
    const u16* __restrict__ S, const u16* __restrict__ Wf,
    const float* __restrict__ bias, u8* __restrict__ Y,
    const int* __restrict__ VL, float* __restrict__ ST)
{
    __shared__ __align__(16) u16 xs[10368];
    __shared__ float wred[4][4][8];     // [wave][lg][s:0..3, s2:4..7]
    const int t = threadIdx.x;
    const int bid = blockIdx.x;
    const int b = bid & 7;
    const int rest = bid >> 3;
    const int m0 = (rest & 15) * 32;
    const int n0 = (rest >> 4) * 32;
    const u16* sp0 = S + (size_t)(b * 8) * 262144;
    // paired-pixel staging: 648 pairs; width 36 even + m0 even => pair shares validity/alignment
    for (int p = t; p < 648; p += 256) {
        const int idx2 = p * 2;
        const int r = idx2 / 36, c = idx2 - r * 36;
        const int gn = n0 - 2 + r, gm = m0 - 2 + c;
        uint4 o0 = make_uint4(0, 0, 0, 0), o1 = o0;
        if ((unsigned)gn < 512u && (unsigned)gm < 512u) {
            const u16* pp = sp0 + (size_t)gn * 512 + gm;
            unsigned u[8];
#pragma unroll
            for (int e = 0; e < 8; ++e)
                u[e] = *reinterpret_cast<const unsigned*>(pp + (size_t)e * 262144);
            o0 = make_uint4((u[0] & 0xffffu) | ((u[1] & 0xffffu) << 16),
                            (u[2] & 0xffffu) | ((u[3] & 0xffffu) << 16),
                            (u[4] & 0xffffu) | ((u[5] & 0xffffu) << 16),
                            (u[6] & 0xffffu) | ((u[7] & 0xffffu) << 16));
            o1 = make_uint4((u[0] >> 16) | (u[1] & 0xffff0000u),
                            (u[2] >> 16) | (u[3] & 0xffff0000u),
                            (u[4] >> 16) | (u[5] & 0xffff0000u),
                            (u[6] >> 16) | (u[7] & 0xffff0000u));
        }
        *reinterpret_cast<uint4*>(&xs[idx2 * 8]) = o0;
        *reinterpret_cast<uint4*>(&xs[(idx2 + 1) * 8]) = o1;
    }
    const int lane = t & 63, wave = t >> 6;
    const int lg = lane >> 4, ln16 = lane & 15;
    short8v bq[7];
#pragma unroll
    for (int q = 0; q < 7; ++q)
        bq[q] = *reinterpret_cast<const short8v*>(&Wf[(q * 64 + lane) * 8]);
    int aoff[7];
#pragma unroll
    for (int q = 0; q < 7; ++q) {
        const int G = q * 4 + lg; const int p = (G < 25) ? G : 0;
        const int dn = p / 5, dm = p - dn * 5;
        aoff[q] = (dn * 36 + dm) * 8;
    }
    const float4 b4 = *reinterpret_cast<const float4*>(&bias[lg * 4]);   // channels lg*4..+3
    const int vl = VL[b];
    f32x4 sstv = {0.f, 0.f, 0.f, 0.f}, sst2v = {0.f, 0.f, 0.f, 0.f};
    __syncthreads();
    for (int i = 0; i < 16; ++i) {
        const int j = wave * 16 + i;
        const int tr = j >> 1, c0 = (j & 1) << 4;
        const int pb = (tr * 36 + c0 + ln16) * 8;
        f32x4 acc = {b4.x, b4.y, b4.z, b4.w};
#pragma unroll
        for (int q = 0; q < 7; ++q) {
            short8v a = *reinterpret_cast<const short8v*>(&xs[pb + aoff[q]]);
            // swapped: A=weights(channels as M), B=pixels(as N) -> lane=pixel, regs=4 channels
            acc = __builtin_amdgcn_mfma_f32_16x16x32_bf16(bq[q], a, acc, 0, 0, 0);
        }
        // lane = pixel (c0+ln16), regs = channels lg*4..+3 -> 4 fp8 = one u32 store
        u8* yb = Y + (((size_t)(b * 512 + n0 + tr)) * 512 + (m0 + c0 + ln16)) * 16 + lg * 4;
        *reinterpret_cast<unsigned*>(yb) = pk4fp8(acc);
        if (n0 + tr < vl) {
            sstv += acc;
            sst2v += acc * acc;
        }
    }
#pragma unroll
    for (int o = 1; o < 16; o <<= 1) {
#pragma unroll
        for (int r = 0; r < 4; ++r) {
            sstv[r]  += __shfl_xor(sstv[r], o);
            sst2v[r] += __shfl_xor(sst2v[r], o);
        }
    }
    if (ln16 == 0) {
#pragma unroll
        for (int r = 0; r < 4; ++r) {
            wred[wave][lg][r]     = sstv[r];
            wred[wave][lg][4 + r] = sst2v[r];
        }
    }
    __syncthreads();
    if (t < 16) {
        const int lgg = t >> 2, r = t & 3;
        const float a  = wred[0][lgg][r] + wred[1][lgg][r] + wred[2][lgg][r] + wred[3][lgg][r];
        const float b2 = wred[0][lgg][4 + r] + wred[1][lgg][4 + r] + wred[2][lgg][4 + r] + wred[3][lgg][4 + r];
        atomicAdd(&ST[(b * 16 + t) * 2 + 0], a);
        atomicAdd(&ST[(b * 16 + t) * 2 + 1], b2);
    }
}

// ---------------- conv2 (MFMA): Y fp8 ch-last, statfin + norm+relu fused -> S2 bf16 planar
// + online-softmax partials (max, sumexp) per (b,h,row,32-m-tile) into PS
// 1-D grid 2048, batch->XCD affine, x-fastest band sweep
__global__ __launch_bounds__(256) void k_conv2m(
    const u8* __restrict__ Y, const float* __restrict__ ST,
    const int* __restrict__ VL, const float* __restrict__ n1g, const float* __restrict__ n1b,
    const u16* __restrict__ Wf, const float* __restrict__ bias,
    u16* __restrict__ S2, float2* __restrict__ PS)
{
    __shared__ __align__(16) u16 xs[20736];
    __shared__ float ssh[16][2];
    const int t = threadIdx.x;
    const int bid = blockIdx.x;
    const int b = bid & 7;
    const int rest = bid >> 3;
    const int m0 = (rest & 15) * 32;
    const int n0 = (rest >> 4) * 32;
    const int vl = VL[b];
    if (t < 16) {                       // folded statfin (redundant per block, trivial)
        const float sw = (float)vl * 512.f;
        const float mean = ST[(b * 16 + t) * 2 + 0] / sw;
        const float var  = ST[(b * 16 + t) * 2 + 1] / sw - mean * mean;
        const float sc = n1g[t] * rsqrtf(var + 1e-7f);
        ssh[t][0] = sc;
        ssh[t][1] = n1b[t] - mean * sc;
    }
    __syncthreads();
    float sc[16], shv[16];
#pragma unroll
    for (int ch = 0; ch < 16; ++ch) { sc[ch] = ssh[ch][0]; shv[ch] = ssh[ch][1]; }
    for (int idx = t; idx < 1296; idx += 256) {
        const int r = idx / 36; const int c = idx - r * 36;
        const int gn = n0 - 2 + r, gm = m0 - 2 + c;
        uint4 p0 = make_uint4(0, 0, 0, 0), p1 = p0;
        if ((unsigned)gn < 512u && (unsigned)gm < 512u) {
            const uint4 rv = *reinterpret_cast<const uint4*>(
                Y + (((size_t)(b * 512 + gn)) * 512 + gm) * 16);
            const unsigned rr[4] = {rv.x, rv.y, rv.z, rv.w};
            unsigned o0[4], o1[4];
#pragma unroll
            for (int q2 = 0; q2 < 4; ++q2) {
                const int ch = q2 * 4;
                f32x2 lo = __builtin_amdgcn_cvt_pk_f32_fp8((int)rr[q2], false);
                f32x2 hi = __builtin_amdgcn_cvt_pk_f32_fp8((int)rr[q2], true);
                float a0 = fmaf(lo.x, sc[ch],     shv[ch]);     a0 = a0 > 0.f ? a0 : 0.f;
                float a1 = fmaf(lo.y, sc[ch + 1], shv[ch + 1]); a1 = a1 > 0.f ? a1 : 0.f;
                float a2 = fmaf(hi.x, sc[ch + 2], shv[ch + 2]); a2 = a2 > 0.f ? a2 : 0.f;
                float a3 = fmaf(hi.y, sc[ch + 3], shv[ch + 3]); a3 = a3 > 0.f ? a3 : 0.f;
                unsigned* dst = (q2 < 2) ? o0 : o1;
                dst[(q2 & 1) * 2]     = pkt2(a0, a1);
                dst[(q2 & 1) * 2 + 1] = pkt2(a2, a3);
            }
            p0 = make_uint4(o0[0], o0[1], o0[2], o0[3]);
            p1 = make_uint4(o1[0], o1[1], o1[2], o1[3]);
        }
        *reinterpret_cast<uint4*>(&xs[idx * 8]) = p0;
        *reinterpret_cast<uint4*>(&xs[10368 + idx * 8]) = p1;
    }
    const int lane = t & 63, wave = t >> 6;
    const int lg = lane >> 4, ln16 = lane & 15;
    short8v bq[13];
#pragma unroll
    for (int q = 0; q < 13; ++q)
        bq[q] = *reinterpret_cast<const short8v*>(&Wf[(q * 64 + lane) * 8]);
    int aoff[13];
#pragma unroll
    for (int q = 0; q < 13; ++q) {
        const int G = q * 4 + lg; const int p = (G < 50) ? G : 0;
        const int pos = p >> 1, h = p & 1;
        const int dn = pos / 5, dm = pos - dn * 5;
        aoff[q] = h * 10368 + (dn * 36 + dm) * 8;
    }
    const float bs = (ln16 < 8) ? bias[ln16] : 0.f;
    __syncthreads();
    for (int ip = 0; ip < 8; ++ip) {
        const int tr = wave * 8 + ip;
        float xv[8];
#pragma unroll
        for (int half = 0; half < 2; ++half) {
            const int c0 = half << 4;
            const int pb = (tr * 36 + c0 + ln16) * 8;
            f32x4 acc = {bs, bs, bs, bs};
#pragma unroll
            for (int q = 0; q < 13; ++q) {
                short8v a = *reinterpret_cast<const short8v*>(&xs[pb + aoff[q]]);
                acc = __builtin_amdgcn_mfma_f32_16x16x32_bf16(a, bq[q], acc, 0, 0, 0);
            }
            if (ln16 < 8) {
                uint2 o = make_uint2(pkt2(acc[0], acc[1]), pkt2(acc[2], acc[3]));
                *reinterpret_cast<uint2*>(
                    &S2[(((size_t)(b * 8 + ln16)) * 512 + n0 + tr) * 512 + m0 + c0 + lg * 4]) = o;
            }
#pragma unroll
            for (int r = 0; r < 4; ++r) {
                const int m = m0 + c0 + lg * 4 + r;
                xv[half * 4 + r] = (m < vl) ? acc[r] : -3.0e38f;
            }
        }
        // per-(ch,row) online partial over this block's 32 m values
        float mxr = xv[0];
#pragma unroll
        for (int r8 = 1; r8 < 8; ++r8) mxr = fmaxf(mxr, xv[r8]);
        mxr = fmaxf(mxr, __shfl_xor(mxr, 16));
        mxr = fmaxf(mxr, __shfl_xor(mxr, 32));
        float smr = 0.f;
#pragma unroll
        for (int r8 = 0; r8 < 8; ++r8) {
            const int m = m0 + ((r8 >> 2) << 4) + lg * 4 + (r8 & 3);
            smr += (m < vl) ? __expf(xv[r8] - mxr) : 0.f;
        }
        smr += __shfl_xor(smr, 16);
        smr += __shfl_xor(smr, 32);
        if (lg == 0 && ln16 < 8)
            PS[((size_t)(b * 8 + ln16) * 512 + n0 + tr) * 16 + (m0 >> 5)] = make_float2(mxr, smr);
    }
}

// ---------------- fused masked softmax (from PS partials) + A@V: logits bf16 -> X2 bf16
// 1-D grid 512, batch->XCD affine: bid = b + 8*(nx + 8*h)
__global__ __launch_bounds__(256) void k_softav(
    const u16* __restrict__ SL, const u16* __restrict__ Vt,
    const int* __restrict__ VL, const float2* __restrict__ PS, u16* __restrict__ X2)
{
    __shared__ __align__(16) u16 As[4608];   // 64x72
    __shared__ __align__(16) u16 Bs[4608];   // 64x72
    __shared__ float smx[64], siv[64];
    const int t = threadIdx.x, lane = t & 63, wave = t >> 6;
    const int lg = lane >> 4, ln16 = lane & 15;
    const int bid = blockIdx.x;
    const int b = bid & 7;
    const int rest = bid >> 3;
    const int nx = rest & 7;
    const int h = rest >> 3;
    const int n0 = nx * 64;
    const int bh = b * 8 + h;
    const int vl = VL[b];
    const u16* Sp = SL + (size_t)bh * 262144;
    if (t < 64) {
        const float* pp = reinterpret_cast<const float*>(PS) + ((size_t)bh * 512 + n0 + t) * 32;
        float mxv[16], smv[16];
#pragma unroll
        for (int i = 0; i < 8; ++i) {
            float4 v = *reinterpret_cast<const float4*>(pp + i * 4);
            mxv[i * 2]     = v.x; smv[i * 2]     = v.y;
            mxv[i * 2 + 1] = v.z; smv[i * 2 + 1] = v.w;
        }
        float M = mxv[0];
#pragma unroll
        for (int i = 1; i < 16; ++i) M = fmaxf(M, mxv[i]);
        float Ssum = 0.f;
#pragma unroll
        for (int i = 0; i < 16; ++i) Ssum += smv[i] * __expf(mxv[i] - M);
        smx[t] = M; siv[t] = 1.0f / Ssum;
    }
    __syncthreads();
    f32x4 acc[4] = {};
    for (int k0 = 0; k0 < 512; k0 += 64) {
#pragma unroll
        for (int u = 0; u < 2; ++u) {
            const int chunk = u * 256 + t, row = chunk >> 3, ko = (chunk & 7) * 8;
            uint4 raw = *reinterpret_cast<const uint4*>(Sp + (size_t)(n0 + row) * 512 + k0 + ko);
            const unsigned w[4] = {raw.x, raw.y, raw.z, raw.w};
            const float mxr = smx[row], ivr = siv[row];
            unsigned o[4];
#pragma unroll
            for (int jj = 0; jj < 4; ++jj) {
                const int m0i = k0 + ko + 2 * jj;
                float a0 = (m0i     < vl) ? __expf(bf2f((u16)(w[jj] & 0xffff)) - mxr) * ivr : 0.f;
                float a1 = (m0i + 1 < vl) ? __expf(bf2f((u16)(w[jj] >> 16))   - mxr) * ivr : 0.f;
                o[jj] = pkt2(a0, a1);
            }
            *reinterpret_cast<uint4*>(As + row * 72 + ko) = make_uint4(o[0], o[1], o[2], o[3]);
            *reinterpret_cast<uint4*>(Bs + row * 72 + ko) =
                *reinterpret_cast<const uint4*>(Vt + ((size_t)(bh * 64 + row)) * 512 + k0 + ko);
        }
        __syncthreads();
#pragma unroll
        for (int kk = 0; kk < 64; kk += 32) {
            short8v a = *reinterpret_cast<const short8v*>(As + (wave * 16 + ln16) * 72 + kk + lg * 8);
#pragma unroll
            for (int ni = 0; ni < 4; ++ni) {
                short8v bfr = *reinterpret_cast<const short8v*>(Bs + (ni * 16 + ln16) * 72 + kk + lg * 8);
                acc[ni] = __builtin_amdgcn_mfma_f32_16x16x32_bf16(a, bfr, acc[ni], 0, 0, 0);
            }
        }
        __syncthreads();
    }
    u16* Cs = As + wave * 1152;                      // 16x72 per wave
#pragma unroll
    for (int ni = 0; ni < 4; ++ni)
#pragma unroll
        for (int r = 0; r < 4; ++r)
            Cs[(lg * 4 + r) * 72 + ni * 16 + ln16] = f2bft(acc[ni][r]);
#pragma unroll
    for (int j = 0; j < 2; ++j) {
        const int chunk = j * 64 + lane, row = chunk >> 3, co = (chunk & 7) * 8;
        const int tn = n0 + wave * 16 + row;
        *reinterpret_cast<uint4*>(X2 + ((size_t)(b * 512 + tn)) * 512 + h * 64 + co) =
            *reinterpret_cast<const uint4*>(Cs + row * 72 + co);
    }
}

// ---------------- out-proj (MFMA): X2 @ WhT + bh + query -> P f32
__global__ __launch_bounds__(256) void k_outm(
    const u16* __restrict__ X2, const u16* __restrict__ WT, const float* __restrict__ bias,
    const float* __restrict__ Xq, float* __restrict__ Pout)
{
    __shared__ __align__(16) u16 sh[18432];
    u16* As = sh; u16* Bs = sh + 9216;
    const int t = threadIdx.x, lane = t & 63, wave = t >> 6;
    const int wm = wave >> 1, wn = wave & 1;
    const int lg = lane >> 4, ln16 = lane & 15;
    const int m0 = blockIdx.x * 128, n0 = blockIdx.y * 128;
    f32x4 acc[4][4] = {};
    for (int k0 = 0; k0 < 512; k0 += 64) {
#pragma unroll
        for (int u = 0; u < 4; ++u) {
            const int chunk = u * 256 + t, row = chunk >> 3, ko = (chunk & 7) * 8;
            *reinterpret_cast<uint4*>(As + row * 72 + ko) =
                *reinterpret_cast<const uint4*>(X2 + (size_t)(m0 + row) * 512 + k0 + ko);
            *reinterpret_cast<uint4*>(Bs + row * 72 + ko) =
                *reinterpret_cast<const uint4*>(WT + (size_t)(n0 + row) * 512 + k0 + ko);
        }
        __syncthreads();
#pragma unroll
        for (int kk = 0; kk < 64; kk += 32) {
            short8v a[4], bfr[4];
#pragma unroll
            for (int mi = 0; mi < 4; ++mi)
                a[mi] = *reinterpret_cast<const short8v*>(As + (wm * 64 + mi * 16 + ln16) * 72 + kk + lg * 8);
#pragma unroll
            for (int ni = 0; ni < 4; ++ni)
                bfr[ni] = *reinterpret_cast<const short8v*>(Bs + (wn * 64 + ni * 16 + ln16) * 72 + kk + lg * 8);
#pragma unroll
            for (int mi = 0; mi < 4; ++mi)
#pragma unroll
                for (int ni = 0; ni < 4; ++ni)
                    acc[mi][ni] = __builtin_amdgcn_mfma_f32_16x16x32_bf16(a[mi], bfr[ni], acc[mi][ni], 0, 0, 0);
        }
        __syncthreads();
    }
#pragma unroll
    for (int ni = 0; ni < 4; ++ni) {
        const int cg = n0 + wn * 64 + ni * 16 + ln16;
        const float bv = bias[cg];
#pragma unroll
        for (int mi = 0; mi < 4; ++mi)
#pragma unroll
            for (int r = 0; r < 4; ++r) {
                const int tok = m0 + wm * 64 + mi * 16 + lg * 4 + r;
                Pout[(size_t)tok * 512 + cg] = acc[mi][ni][r] + bv + Xq[(size_t)tok * 512 + cg];
            }
    }
}

// ---------------- final LayerNorm over D=512
__global__ __launch_bounds__(256) void k_ln(
    const float* __restrict__ P, const float* __restrict__ g,
    const float* __restrict__ be, float* __restrict__ out)
{
    const int row = blockIdx.x * 4 + (threadIdx.x >> 6);
    const int lane = threadIdx.x & 63;
    const float* p = P + (size_t)row * 512;
    float4 v0 = reinterpret_cast<const float4*>(p)[lane];
    float4 v1 = reinterpret_cast<const float4*>(p)[64 + lane];
    float s = v0.x + v0.y + v0.z + v0.w + v1.x + v1.y + v1.z + v1.w;
#pragma unroll
    for (int o = 32; o; o >>= 1) s += __shfl_xor(s, o);
    const float mean = s * (1.0f / 512.0f);
    float d[8] = {v0.x - mean, v0.y - mean, v0.z - mean, v0.w - mean,
                  v1.x - mean, v1.y - mean, v1.z - mean, v1.w - mean};
    float s2 = 0.f;
#pragma unroll
    for (int j = 0; j < 8; ++j) s2 += d[j] * d[j];
#pragma unroll
    for (int o = 32; o; o >>= 1) s2 += __shfl_xor(s2, o);
    const float rstd = rsqrtf(s2 * (1.0f / 512.0f) + 1e-7f);
    float4 g0 = reinterpret_cast<const float4*>(g)[lane];
    float4 g1 = reinterpret_cast<const float4*>(g)[64 + lane];
    float4 b0 = reinterpret_cast<const float4*>(be)[lane];
    float4 b1 = reinterpret_cast<const float4*>(be)[64 + lane];
    float* op = out + (size_t)row * 512;
    reinterpret_cast<float4*>(op)[lane] =
        make_float4(d[0] * rstd * g0.x + b0.x, d[1] * rstd * g0.y + b0.y,
                    d[2] * rstd * g0.z + b0.z, d[3] * rstd * g0.w + b0.w);
    reinterpret_cast<float4*>(op)[64 + lane] =
        make_float4(d[4] * rstd * g1.x + b1.x, d[5] * rstd * g1.y + b1.y,
                    d[6] * rstd * g1.z + b1.z, d[7] * rstd * g1.w + b1.w);
}

extern "C" void kernel_launch(void* const* d_in, const int* in_sizes, int n_in,
                              void* d_out, int out_size, void* d_ws, size_t ws_size,
                              hipStream_t stream)
{
    const float* query = (const float*)d_in[0];
    const int*   VL    = (const int*)d_in[1];
    const float* Wq = (const float*)d_in[2];  const float* bq = (const float*)d_in[3];
    const float* Wk = (const float*)d_in[4];  const float* bk = (const float*)d_in[5];
    const float* Wv = (const float*)d_in[6];  const float* bv = (const float*)d_in[7];
    const float* Wh = (const float*)d_in[8];  const float* bh = (const float*)d_in[9];
    const float* pos_k = (const float*)d_in[10];
    const float* c1w = (const float*)d_in[11]; const float* c1b = (const float*)d_in[12];
    const float* n1g = (const float*)d_in[13]; const float* n1b = (const float*)d_in[14];
    const float* c2w = (const float*)d_in[15]; const float* c2b = (const float*)d_in[16];
    const float* lng = (const float*)d_in[17]; const float* lnb = (const float*)d_in[18];

    float* ws = (float*)d_ws;
    const size_t M1 = (size_t)1 << 20;
    u16* S1  = (u16*)ws;                             // [0,8M) scores/logits bf16
    u8*  Y1  = (u8*)(ws + 8 * M1);                   // [8M,16M) Y fp8 ch-last (32 MB)
    u16* Xb  = (u16*)(ws + 24 * M1);
    u16* Qb  = (u16*)(ws + 25 * M1);
    u16* Kb  = (u16*)(ws + 26 * M1);
    u16* Vt  = (u16*)(ws + 27 * M1);
    u16* QPb = (u16*)(ws + 28 * M1);
    u16* WqT = (u16*)(ws + 30 * M1);
    u16* WkT = WqT + 262144;
    u16* WvT = WkT + 262144;
    u16* WhT = WvT + 262144;
    u16* pos_kb = (u16*)(ws + 30 * M1 + 524288);
    u16* Wf1 = pos_kb + 8192;
    u16* Wf2 = Wf1 + 3584;
    float* ST  = ws + 31 * M1;
    float2* PS = (float2*)(ws + 31 * M1 + 512);      // (B,H,512,16) x (max,sumexp) = 4 MB
    u16* X2 = Xb;
    float* Pout = ws + 28 * M1;

    hipMemsetAsync(ST, 0, 256 * sizeof(float), stream);

    k_prept<<<dim3(8, 8, 6), 256, 0, stream>>>(Wq, Wk, Wv, Wh, WqT, WkT, WvT, WhT,
                                               c1w, c2w, pos_k, Wf1, Wf2, pos_kb,
                                               query, Xb);
    k_qkvm<<<dim3(32, 4, 3), 256, 0, stream>>>(Xb, WqT, WkT, WvT, bq, bk, bv, Qb, Kb, Vt);
    k_qposm<<<dim3(4, 64), 256, 0, stream>>>(Qb, pos_kb, QPb);
    k_scoresm<<<1024, 256, 0, stream>>>(Qb, Kb, QPb, S1);
    k_conv1m<<<2048, 256, 0, stream>>>(S1, Wf1, c1b, Y1, VL, ST);
    k_conv2m<<<2048, 256, 0, stream>>>(Y1, ST, VL, n1g, n1b, Wf2, c2b, S1, PS);
    k_softav<<<512, 256, 0, stream>>>(S1, Vt, VL, PS, X2);
    k_outm<<<dim3(32, 4), 256, 0, stream>>>(X2, WhT, bh, query, Pout);
    k_ln<<<1024, 256, 0, stream>>>(Pout, lng, lnb, (float*)d_out);
}